// Round 2
// baseline (438.799 us; speedup 1.0000x reference)
//
#include <hip/hip_runtime.h>
#include <math.h>
#include <float.h>

#define BATCH 8
#define HIGH  256
#define LOWR  64
#define NN    4096          // LOWR*LOWR
#define HIDC  16
#define C1    64
#define NSL   8             // j-slices in kNN scan (512 j each)

// workspace layout (floats) — footprint identical to the validated R1/R2 layout
#define OFF_XL   0
#define OFF_H1   (OFF_XL  + BATCH*NN)            // 2.097M floats; reused for cand_i after conv2
#define OFF_H    (OFF_H1  + BATCH*C1*NN)         // node-major [B*N][16]
#define OFF_SQ   (OFF_H   + BATCH*NN*HIDC)       // 0.5*|h|^2 per node
#define OFF_XP   (OFF_SQ  + BATCH*NN)
#define OFF_ASR  (OFF_XP  + BATCH*NN*HIDC)
#define OFF_ADT  (OFF_ASR + BATCH*NN*4)
#define OFF_P    (OFF_ADT + BATCH*NN*4)
#define OFF_OL   (OFF_P   + BATCH*NN*HIDC)
// cand_i: BATCH*NSL*NN packed uint4 (8 ushort idx) = 8*8*4096*16 B = 4 MB
//         = 1,048,576 float-slots at OFF_H1 (< 2,097,152) — no footprint growth.

// identical-arithmetic dot used by BOTH k_scan and k_gat2 (bit-equal scores)
__device__ __forceinline__ float dot16m(const float ni[16], float4 a0, float4 a1,
                                        float4 a2, float4 a3, float hs) {
    return ni[0]*a0.x + ni[1]*a0.y + ni[2]*a0.z + ni[3]*a0.w
         + ni[4]*a1.x + ni[5]*a1.y + ni[6]*a1.z + ni[7]*a1.w
         + ni[8]*a2.x + ni[9]*a2.y + ni[10]*a2.z + ni[11]*a2.w
         + ni[12]*a3.x + ni[13]*a3.y + ni[14]*a3.z + ni[15]*a3.w
         - hs;
}

// ---------------- bilinear downsample 256 -> 64 (antialiased triangle) -------
__global__ void k_down(const float* __restrict__ x, float* __restrict__ xl) {
    int t = blockIdx.x * 128 + threadIdx.x;
    if (t >= BATCH * NN) return;
    int b = t >> 12, oy = (t >> 6) & 63, ox = t & 63;
    const float* xb = x + b * HIGH * HIGH;
    float cy = 4.f * oy + 1.5f, cx = 4.f * ox + 1.5f;
    float wy[8], wx[8], sy = 0.f, sx = 0.f;
#pragma unroll
    for (int k = 0; k < 8; k++) {
        int iy = 4 * oy - 2 + k;
        float w = 1.f - fabsf((float)iy - cy) * 0.25f;
        if (iy < 0 || iy >= HIGH) w = 0.f;
        wy[k] = w; sy += w;
        int ix = 4 * ox - 2 + k;
        float v = 1.f - fabsf((float)ix - cx) * 0.25f;
        if (ix < 0 || ix >= HIGH) v = 0.f;
        wx[k] = v; sx += v;
    }
    float acc = 0.f;
#pragma unroll
    for (int ky = 0; ky < 8; ky++) {
        if (wy[ky] == 0.f) continue;
        int iy = 4 * oy - 2 + ky;
        float rowacc = 0.f;
#pragma unroll
        for (int kx = 0; kx < 8; kx++) {
            if (wx[kx] == 0.f) continue;
            int ix = 4 * ox - 2 + kx;
            rowacc += wx[kx] * xb[iy * HIGH + ix];
        }
        acc += wy[ky] * rowacc;
    }
    xl[t] = acc / (sy * sx);
}

// ---------------- conv3x3 1->64 + BN + relu ---------------------------------
__global__ void k_conv1(const float* __restrict__ xl, const float* __restrict__ W1,
                        const float* __restrict__ b1, const float* __restrict__ g1,
                        const float* __restrict__ be1, const float* __restrict__ m1,
                        const float* __restrict__ v1, float* __restrict__ h1) {
    int t = blockIdx.x * 256 + threadIdx.x;
    if (t >= BATCH * C1 * NN) return;
    int b = t >> 18, co = (t >> 12) & 63, y = (t >> 6) & 63, x = t & 63;
    const float* src = xl + b * NN;
    const float* w = W1 + co * 9;
    float acc = 0.f;
#pragma unroll
    for (int dy = -1; dy <= 1; dy++) {
        int yy = y + dy; if (yy < 0 || yy >= 64) continue;
#pragma unroll
        for (int dx = -1; dx <= 1; dx++) {
            int xx = x + dx; if (xx < 0 || xx >= 64) continue;
            acc += w[(dy + 1) * 3 + (dx + 1)] * src[yy * 64 + xx];
        }
    }
    acc += b1[co];
    float sc = g1[co] / sqrtf(v1[co] + 1e-5f);
    acc = (acc - m1[co]) * sc + be1[co];
    h1[t] = fmaxf(acc, 0.f);
}

// ------- conv3x3 64->16 + BN + relu, fused: h (node-major), sq, xp, asr, adt -
__launch_bounds__(128)
__global__ void k_conv2(const float* __restrict__ h1, const float* __restrict__ W2,
                        const float* __restrict__ b2, const float* __restrict__ g2,
                        const float* __restrict__ be2, const float* __restrict__ m2,
                        const float* __restrict__ v2, const float* __restrict__ Wg,
                        const float* __restrict__ a_src, const float* __restrict__ a_dst,
                        float* __restrict__ h, float* __restrict__ sq,
                        float* __restrict__ xp, float* __restrict__ asr,
                        float* __restrict__ adt) {
    __shared__ float sW2t[576 * 16];    // [ci*9+tap][o]
    __shared__ float sWg[256];
    __shared__ float sA[32];
    int tid = threadIdx.x;
    for (int k = tid; k < 9216; k += 128) {          // coalesced global read, scatter to LDS
        int o = k / 576, ct = k - o * 576;
        sW2t[ct * 16 + o] = W2[k];
    }
    for (int k = tid; k < 256; k += 128) sWg[k] = Wg[k];
    if (tid < 16) { sA[tid] = a_src[tid]; sA[16 + tid] = a_dst[tid]; }
    __syncthreads();
    int blk = blockIdx.x;                 // 8 batches * 32 y-tiles
    int b = blk >> 5, ytile = blk & 31;
    int ty = tid >> 6, x = tid & 63, y = ytile * 2 + ty;
    float acc[16];
#pragma unroll
    for (int o = 0; o < 16; o++) acc[o] = 0.f;
    const float* hb = h1 + (long)b * C1 * NN;
    for (int ci = 0; ci < 64; ci++) {
        const float* plane = hb + ci * NN;
#pragma unroll
        for (int dy = -1; dy <= 1; dy++) {
            int yy = y + dy; bool oky = (yy >= 0 && yy < 64);
#pragma unroll
            for (int dx = -1; dx <= 1; dx++) {
                int xx = x + dx;
                float v = (oky && xx >= 0 && xx < 64) ? plane[yy * 64 + xx] : 0.f;
                int ct = ci * 9 + (dy + 1) * 3 + (dx + 1);
                const float4* wr = (const float4*)&sW2t[ct * 16];
                float4 w0 = wr[0], w1 = wr[1], w2 = wr[2], w3 = wr[3];
                acc[0] += v * w0.x; acc[1] += v * w0.y; acc[2] += v * w0.z; acc[3] += v * w0.w;
                acc[4] += v * w1.x; acc[5] += v * w1.y; acc[6] += v * w1.z; acc[7] += v * w1.w;
                acc[8] += v * w2.x; acc[9] += v * w2.y; acc[10]+= v * w2.z; acc[11]+= v * w2.w;
                acc[12]+= v * w3.x; acc[13]+= v * w3.y; acc[14]+= v * w3.z; acc[15]+= v * w3.w;
            }
        }
    }
    int n = y * 64 + x;
    long node = (long)b * NN + n;
    float nodev[16], sqv = 0.f;
#pragma unroll
    for (int o = 0; o < 16; o++) {
        float a = acc[o] + b2[o];
        float sc = g2[o] / sqrtf(v2[o] + 1e-5f);
        a = (a - m2[o]) * sc + be2[o];
        a = fmaxf(a, 0.f);
        nodev[o] = a; sqv += a * a;
        h[node * 16 + o] = a;
    }
    sq[node] = 0.5f * sqv;                // pre-scaled: scan/merge use dot - 0.5|j|^2
    float xpv[16];
#pragma unroll
    for (int o = 0; o < 16; o++) {
        float a = 0.f;
#pragma unroll
        for (int c = 0; c < 16; c++) a += sWg[o * 16 + c] * nodev[c];
        xpv[o] = a;
        xp[node * 16 + o] = a;
    }
#pragma unroll
    for (int hh = 0; hh < 4; hh++) {
        float as = 0.f, ad = 0.f;
#pragma unroll
        for (int f = 0; f < 4; f++) {
            as += xpv[hh * 4 + f] * sA[hh * 4 + f];
            ad += xpv[hh * 4 + f] * sA[16 + hh * 4 + f];
        }
        asr[node * 4 + hh] = as;
        adt[node * 4 + hh] = ad;
    }
}

// --------- kNN scan: per (row, j-slice) top-8, index-only output ------------
// block = 256 threads = 256 rows, all scanning the SAME 512-j slice in lock-step.
// j-node load is wave-uniform -> broadcast, no LDS, no barriers.
// grid = 8 batches * 16 rowgroups * 8 slices = 1024 blocks (4 waves/SIMD).
// __launch_bounds__(256, 4): 4 waves/EU is exactly what the 1024-block grid
// sustains (4 blocks/CU); raises ArchVGPR budget to 128 so ni[16]+s[8]+id[8]
// live in real VGPRs instead of AGPRs (VGPR_Count=24 + no scratch traffic
// showed the compiler was shuttling the arrays via v_accvgpr_read/write,
// ~2x VALU inflation).
__launch_bounds__(256, 4)
__global__ void k_scan(const float* __restrict__ h, const float* __restrict__ sq,
                       uint4* __restrict__ cand_i) {
    int tid = threadIdx.x;
    int blk = blockIdx.x;
    int b  = blk >> 7;
    int rg = (blk >> 3) & 15;
    int sl = blk & 7;
    int i  = rg * 256 + tid;
    long bN = (long)b * NN;
    const float4* ip = (const float4*)&h[(bN + i) * 16];
    float4 r0 = ip[0], r1 = ip[1], r2 = ip[2], r3 = ip[3];
    float ni[16] = { r0.x,r0.y,r0.z,r0.w, r1.x,r1.y,r1.z,r1.w,
                     r2.x,r2.y,r2.z,r2.w, r3.x,r3.y,r3.z,r3.w };
    float s[8]; int id[8];
#pragma unroll
    for (int k = 0; k < 8; k++) { s[k] = -FLT_MAX; id[k] = 65535; }
    int j0 = sl * 512;
    const float* __restrict__ hj  = h + (bN + j0) * 16;
    const float* __restrict__ sqp = sq + bN + j0;
#pragma unroll 4
    for (int q = 0; q < 512; q++) {
        const float4* np = (const float4*)(hj + q * 16);
        float4 a0 = np[0], a1 = np[1], a2 = np[2], a3 = np[3];
        float sc = dot16m(ni, a0, a1, a2, a3, sqp[q]);
        int j = j0 + q;
        if (sc > s[7] && j != i) {          // strict > : lowest-index kept on ties
            s[7] = sc; id[7] = j;
#pragma unroll
            for (int k = 7; k > 0; k--) {
                if (s[k] > s[k - 1]) {
                    float td = s[k]; s[k] = s[k - 1]; s[k - 1] = td;
                    int tj = id[k]; id[k] = id[k - 1]; id[k - 1] = tj;
                }
            }
        }
    }
    uint4 pk;
    pk.x = (unsigned)id[0] | ((unsigned)id[1] << 16);
    pk.y = (unsigned)id[2] | ((unsigned)id[3] << 16);
    pk.z = (unsigned)id[4] | ((unsigned)id[5] << 16);
    pk.w = (unsigned)id[6] | ((unsigned)id[7] << 16);
    cand_i[(long)(b * NSL + sl) * NN + i] = pk;
}

// --- merge 8 slice-lists (recompute scores bit-identically) + GAT -> p ------
__launch_bounds__(256)
__global__ void k_gat2(const uint4* __restrict__ cand_i, const float* __restrict__ h,
                       const float* __restrict__ sq,
                       const float* __restrict__ xp, const float* __restrict__ asr,
                       const float* __restrict__ adt, const float* __restrict__ bg,
                       float* __restrict__ p) {
    int t = blockIdx.x * 256 + threadIdx.x;       // 0..32767
    int b = t >> 12, i = t & 4095;
    long bN = (long)b * NN;
    const float4* ip = (const float4*)&h[(bN + i) * 16];
    float4 r0 = ip[0], r1 = ip[1], r2 = ip[2], r3 = ip[3];
    float ni[16] = { r0.x,r0.y,r0.z,r0.w, r1.x,r1.y,r1.z,r1.w,
                     r2.x,r2.y,r2.z,r2.w, r3.x,r3.y,r3.z,r3.w };
    float fS[8]; int fI[8];
#pragma unroll
    for (int k = 0; k < 8; k++) { fS[k] = -FLT_MAX; fI[k] = 65535; }
    for (int sl = 0; sl < NSL; sl++) {
        uint4 pk = cand_i[(long)(b * NSL + sl) * NN + i];
        unsigned idx8[8] = { pk.x & 0xFFFF, pk.x >> 16, pk.y & 0xFFFF, pk.y >> 16,
                             pk.z & 0xFFFF, pk.z >> 16, pk.w & 0xFFFF, pk.w >> 16 };
#pragma unroll
        for (int k = 0; k < 8; k++) {
            int j = (int)idx8[k];
            const float4* np = (const float4*)&h[(bN + j) * 16];
            float4 a0 = np[0], a1 = np[1], a2 = np[2], a3 = np[3];
            float d = dot16m(ni, a0, a1, a2, a3, sq[bN + j]);   // bit-identical to scan
            bool bt = (d > fS[7]) || (d == fS[7] && j < fI[7]);
            if (bt) {
                fS[7] = d; fI[7] = j;
#pragma unroll
                for (int q = 7; q > 0; q--) {
                    bool sw = (fS[q] > fS[q - 1]) || (fS[q] == fS[q - 1] && fI[q] < fI[q - 1]);
                    if (sw) {
                        float td = fS[q]; fS[q] = fS[q - 1]; fS[q - 1] = td;
                        int tj = fI[q]; fI[q] = fI[q - 1]; fI[q - 1] = tj;
                    }
                }
            }
        }
    }
    int nbrs[9];
#pragma unroll
    for (int e = 0; e < 8; e++) nbrs[e] = fI[e];
    nbrs[8] = i;                                   // self-loop
    float adtv[4];
#pragma unroll
    for (int hh = 0; hh < 4; hh++) adtv[hh] = adt[(bN + i) * 4 + hh];
    float mx[4] = { -FLT_MAX, -FLT_MAX, -FLT_MAX, -FLT_MAX };
    float lg[9][4];
#pragma unroll
    for (int e = 0; e < 9; e++) {
        long nb = bN + nbrs[e];
#pragma unroll
        for (int hh = 0; hh < 4; hh++) {
            float l = asr[nb * 4 + hh] + adtv[hh];
            l = (l > 0.f) ? l : 0.2f * l;          // leaky_relu 0.2
            lg[e][hh] = l;
            mx[hh] = fmaxf(mx[hh], l);
        }
    }
    float sum[4] = { 0, 0, 0, 0 };
    float acc[16];
#pragma unroll
    for (int c = 0; c < 16; c++) acc[c] = 0.f;
#pragma unroll
    for (int e = 0; e < 9; e++) {
        long nb = bN + nbrs[e];
        const float4* xpn = (const float4*)&xp[nb * 16];
        float4 x0 = xpn[0], x1 = xpn[1], x2 = xpn[2], x3 = xpn[3];
        float xv[16] = { x0.x,x0.y,x0.z,x0.w, x1.x,x1.y,x1.z,x1.w,
                         x2.x,x2.y,x2.z,x2.w, x3.x,x3.y,x3.z,x3.w };
        float wv[4];
#pragma unroll
        for (int hh = 0; hh < 4; hh++) {
            float w = expf(lg[e][hh] - mx[hh]);
            sum[hh] += w; wv[hh] = w;
        }
#pragma unroll
        for (int hh = 0; hh < 4; hh++)
#pragma unroll
            for (int f = 0; f < 4; f++)
                acc[hh * 4 + f] += wv[hh] * xv[hh * 4 + f];
    }
#pragma unroll
    for (int hh = 0; hh < 4; hh++) {
        float inv = 1.f / sum[hh];
#pragma unroll
        for (int f = 0; f < 4; f++) {
            float o = acc[hh * 4 + f] * inv + bg[hh * 4 + f];
            p[(bN + i) * 16 + hh * 4 + f] = fmaxf(o, 0.f);
        }
    }
}

// ------- 1x1 MLP 16->128->16, fire mask, h += mask*u, 1x1->1 + sigmoid ------
#define USTR 20
__launch_bounds__(256)
__global__ void k_update(const float* __restrict__ p, const float* __restrict__ h,
                         const float* __restrict__ fire, const float* __restrict__ Wu1,
                         const float* __restrict__ bu1, const float* __restrict__ Wu2,
                         const float* __restrict__ bu2, const float* __restrict__ Wo,
                         const float* __restrict__ bo, float* __restrict__ out_low) {
    __shared__ float sU1[128 * 16];
    __shared__ float sU2t[128 * 16];      // [hd][c] = Wu2[c][hd]
    __shared__ float sb1[128];
    __shared__ float uhalf[128 * USTR];
    int tid = threadIdx.x;
    for (int k = tid; k < 2048; k += 256) {
        sU1[k] = Wu1[k];
        sU2t[(k & 127) * 16 + (k >> 7)] = Wu2[k];   // coalesced read, scatter to LDS
    }
    if (tid < 128) sb1[tid] = bu1[tid];
    __syncthreads();
    int lnode = tid & 127, half = tid >> 7;
    long n = (long)blockIdx.x * 128 + lnode;         // 0..32767
    const float4* pp = (const float4*)&p[n * 16];
    float4 p0 = pp[0], p1 = pp[1], p2 = pp[2], p3 = pp[3];
    float pv[16] = { p0.x,p0.y,p0.z,p0.w, p1.x,p1.y,p1.z,p1.w,
                     p2.x,p2.y,p2.z,p2.w, p3.x,p3.y,p3.z,p3.w };
    float u[16];
#pragma unroll
    for (int c = 0; c < 16; c++) u[c] = 0.f;
    int hd0 = half * 64;
    for (int hd = hd0; hd < hd0 + 64; hd++) {
        const float4* r = (const float4*)&sU1[hd * 16];
        float4 r0 = r[0], r1 = r[1], r2 = r[2], r3 = r[3];
        float a = sb1[hd]
            + r0.x*pv[0] + r0.y*pv[1] + r0.z*pv[2] + r0.w*pv[3]
            + r1.x*pv[4] + r1.y*pv[5] + r1.z*pv[6] + r1.w*pv[7]
            + r2.x*pv[8] + r2.y*pv[9] + r2.z*pv[10]+ r2.w*pv[11]
            + r3.x*pv[12]+ r3.y*pv[13]+ r3.z*pv[14]+ r3.w*pv[15];
        a = fmaxf(a, 0.f);
        const float4* tt = (const float4*)&sU2t[hd * 16];
        float4 t0 = tt[0], t1 = tt[1], t2 = tt[2], t3 = tt[3];
        u[0] += t0.x*a; u[1] += t0.y*a; u[2] += t0.z*a; u[3] += t0.w*a;
        u[4] += t1.x*a; u[5] += t1.y*a; u[6] += t1.z*a; u[7] += t1.w*a;
        u[8] += t2.x*a; u[9] += t2.y*a; u[10]+= t2.z*a; u[11]+= t2.w*a;
        u[12]+= t3.x*a; u[13]+= t3.y*a; u[14]+= t3.z*a; u[15]+= t3.w*a;
    }
    if (half == 1) {
        float4* dst = (float4*)&uhalf[lnode * USTR];
        dst[0] = make_float4(u[0], u[1], u[2], u[3]);
        dst[1] = make_float4(u[4], u[5], u[6], u[7]);
        dst[2] = make_float4(u[8], u[9], u[10], u[11]);
        dst[3] = make_float4(u[12], u[13], u[14], u[15]);
    }
    __syncthreads();
    if (half == 0) {
        const float4* src = (const float4*)&uhalf[lnode * USTR];
        float4 o0 = src[0], o1 = src[1], o2 = src[2], o3 = src[3];
        float ou[16] = { o0.x,o0.y,o0.z,o0.w, o1.x,o1.y,o1.z,o1.w,
                         o2.x,o2.y,o2.z,o2.w, o3.x,o3.y,o3.z,o3.w };
        float mask = (fire[n] < 0.5f) ? 1.f : 0.f;
        const float4* hp = (const float4*)&h[n * 16];
        float4 h0 = hp[0], h1v = hp[1], h2 = hp[2], h3 = hp[3];
        float hv[16] = { h0.x,h0.y,h0.z,h0.w, h1v.x,h1v.y,h1v.z,h1v.w,
                         h2.x,h2.y,h2.z,h2.w, h3.x,h3.y,h3.z,h3.w };
        float o = bo[0];
#pragma unroll
        for (int c = 0; c < 16; c++)
            o += Wo[c] * (hv[c] + mask * (u[c] + ou[c] + bu2[c]));
        out_low[n] = 1.f / (1.f + expf(-o));
    }
}

// ---------------- bilinear upsample 64 -> 256 (half-pixel, clamp) -----------
__global__ void k_up(const float* __restrict__ ol, float* __restrict__ out) {
    int t = blockIdx.x * 256 + threadIdx.x;
    if (t >= BATCH * HIGH * HIGH) return;
    int b = t >> 16, oy = (t >> 8) & 255, ox = t & 255;
    float cy = (oy + 0.5f) * 0.25f - 0.5f;
    float cx = (ox + 0.5f) * 0.25f - 0.5f;
    int iy0 = (int)floorf(cy); float fy = cy - (float)iy0;
    int ix0 = (int)floorf(cx); float fx = cx - (float)ix0;
    int y0 = min(max(iy0, 0), 63), y1 = min(max(iy0 + 1, 0), 63);
    int x0 = min(max(ix0, 0), 63), x1 = min(max(ix0 + 1, 0), 63);
    const float* s = ol + b * NN;
    float v = (1.f - fy) * ((1.f - fx) * s[y0 * 64 + x0] + fx * s[y0 * 64 + x1])
            + fy * ((1.f - fx) * s[y1 * 64 + x0] + fx * s[y1 * 64 + x1]);
    out[t] = v;
}

extern "C" void kernel_launch(void* const* d_in, const int* in_sizes, int n_in,
                              void* d_out, int out_size, void* d_ws, size_t ws_size,
                              hipStream_t stream) {
    const float* x    = (const float*)d_in[0];
    const float* fire = (const float*)d_in[1];
    const float* W1   = (const float*)d_in[2];
    const float* b1   = (const float*)d_in[3];
    const float* g1   = (const float*)d_in[4];
    const float* be1  = (const float*)d_in[5];
    const float* m1   = (const float*)d_in[6];
    const float* v1   = (const float*)d_in[7];
    const float* W2   = (const float*)d_in[8];
    const float* b2   = (const float*)d_in[9];
    const float* g2   = (const float*)d_in[10];
    const float* be2  = (const float*)d_in[11];
    const float* m2   = (const float*)d_in[12];
    const float* v2   = (const float*)d_in[13];
    const float* Wg   = (const float*)d_in[14];
    const float* a_src= (const float*)d_in[15];
    const float* a_dst= (const float*)d_in[16];
    const float* bg   = (const float*)d_in[17];
    const float* Wu1  = (const float*)d_in[18];
    const float* bu1  = (const float*)d_in[19];
    const float* Wu2  = (const float*)d_in[20];
    const float* bu2  = (const float*)d_in[21];
    const float* Wo   = (const float*)d_in[22];
    const float* bo   = (const float*)d_in[23];

    float* ws  = (float*)d_ws;
    float* xl  = ws + OFF_XL;
    float* h1  = ws + OFF_H1;
    float* h   = ws + OFF_H;
    float* sq  = ws + OFF_SQ;
    float* xp  = ws + OFF_XP;
    float* asr = ws + OFF_ASR;
    float* adt = ws + OFF_ADT;
    float* p   = ws + OFF_P;
    float* ol  = ws + OFF_OL;
    uint4* cand_i = (uint4*)(ws + OFF_H1);          // reuse h1 (dead after conv2), 4 MB

    k_down  <<<(BATCH * NN + 127) / 128, 128, 0, stream>>>(x, xl);
    k_conv1 <<<(BATCH * C1 * NN) / 256, 256, 0, stream>>>(xl, W1, b1, g1, be1, m1, v1, h1);
    k_conv2 <<<BATCH * 32, 128, 0, stream>>>(h1, W2, b2, g2, be2, m2, v2, Wg, a_src, a_dst,
                                             h, sq, xp, asr, adt);
    k_scan  <<<BATCH * 16 * NSL, 256, 0, stream>>>(h, sq, cand_i);
    k_gat2  <<<BATCH * NN / 256, 256, 0, stream>>>(cand_i, h, sq, xp, asr, adt, bg, p);
    k_update<<<BATCH * NN / 128, 256, 0, stream>>>(p, h, fire, Wu1, bu1, Wu2, bu2, Wo, bo, ol);
    k_up    <<<(BATCH * HIGH * HIGH) / 256, 256, 0, stream>>>(ol, (float*)d_out);
}

// Round 3
// 393.641 us; speedup vs baseline: 1.1147x; 1.1147x over previous
//
#include <hip/hip_runtime.h>
#include <math.h>
#include <float.h>

#define BATCH 8
#define HIGH  256
#define LOWR  64
#define NN    4096          // LOWR*LOWR
#define HIDC  16
#define C1    64
#define NSL   8             // j-slices in kNN scan (512 j each)

// workspace layout (floats) — footprint identical to the validated R1/R2 layout
#define OFF_XL   0
#define OFF_H1   (OFF_XL  + BATCH*NN)            // 2.097M floats; reused after conv2:
                                                 //   [0 .. 1,048,575]        cand_i (4 MB)
                                                 //   [1,048,576 .. 1,835,007] bf16 hi/mid/lo splits
#define OFF_H    (OFF_H1  + BATCH*C1*NN)         // node-major [B*N][16]
#define OFF_SQ   (OFF_H   + BATCH*NN*HIDC)       // 0.5*|h|^2 per node
#define OFF_XP   (OFF_SQ  + BATCH*NN)
#define OFF_ASR  (OFF_XP  + BATCH*NN*HIDC)
#define OFF_ADT  (OFF_ASR + BATCH*NN*4)
#define OFF_P    (OFF_ADT + BATCH*NN*4)
#define OFF_OL   (OFF_P   + BATCH*NN*HIDC)

typedef __attribute__((ext_vector_type(8)))  short bf16x8;
typedef __attribute__((ext_vector_type(16))) float f32x16;

// identical-arithmetic dot used by k_gat2 (exact fp32 re-score of the pool —
// final selection semantics unchanged from the validated kernel)
__device__ __forceinline__ float dot16m(const float ni[16], float4 a0, float4 a1,
                                        float4 a2, float4 a3, float hs) {
    return ni[0]*a0.x + ni[1]*a0.y + ni[2]*a0.z + ni[3]*a0.w
         + ni[4]*a1.x + ni[5]*a1.y + ni[6]*a1.z + ni[7]*a1.w
         + ni[8]*a2.x + ni[9]*a2.y + ni[10]*a2.z + ni[11]*a2.w
         + ni[12]*a3.x + ni[13]*a3.y + ni[14]*a3.z + ni[15]*a3.w
         - hs;
}

// ---------------- bilinear downsample 256 -> 64 (antialiased triangle) -------
__global__ void k_down(const float* __restrict__ x, float* __restrict__ xl) {
    int t = blockIdx.x * 128 + threadIdx.x;
    if (t >= BATCH * NN) return;
    int b = t >> 12, oy = (t >> 6) & 63, ox = t & 63;
    const float* xb = x + b * HIGH * HIGH;
    float cy = 4.f * oy + 1.5f, cx = 4.f * ox + 1.5f;
    float wy[8], wx[8], sy = 0.f, sx = 0.f;
#pragma unroll
    for (int k = 0; k < 8; k++) {
        int iy = 4 * oy - 2 + k;
        float w = 1.f - fabsf((float)iy - cy) * 0.25f;
        if (iy < 0 || iy >= HIGH) w = 0.f;
        wy[k] = w; sy += w;
        int ix = 4 * ox - 2 + k;
        float v = 1.f - fabsf((float)ix - cx) * 0.25f;
        if (ix < 0 || ix >= HIGH) v = 0.f;
        wx[k] = v; sx += v;
    }
    float acc = 0.f;
#pragma unroll
    for (int ky = 0; ky < 8; ky++) {
        if (wy[ky] == 0.f) continue;
        int iy = 4 * oy - 2 + ky;
        float rowacc = 0.f;
#pragma unroll
        for (int kx = 0; kx < 8; kx++) {
            if (wx[kx] == 0.f) continue;
            int ix = 4 * ox - 2 + kx;
            rowacc += wx[kx] * xb[iy * HIGH + ix];
        }
        acc += wy[ky] * rowacc;
    }
    xl[t] = acc / (sy * sx);
}

// ---------------- conv3x3 1->64 + BN + relu ---------------------------------
__global__ void k_conv1(const float* __restrict__ xl, const float* __restrict__ W1,
                        const float* __restrict__ b1, const float* __restrict__ g1,
                        const float* __restrict__ be1, const float* __restrict__ m1,
                        const float* __restrict__ v1, float* __restrict__ h1) {
    int t = blockIdx.x * 256 + threadIdx.x;
    if (t >= BATCH * C1 * NN) return;
    int b = t >> 18, co = (t >> 12) & 63, y = (t >> 6) & 63, x = t & 63;
    const float* src = xl + b * NN;
    const float* w = W1 + co * 9;
    float acc = 0.f;
#pragma unroll
    for (int dy = -1; dy <= 1; dy++) {
        int yy = y + dy; if (yy < 0 || yy >= 64) continue;
#pragma unroll
        for (int dx = -1; dx <= 1; dx++) {
            int xx = x + dx; if (xx < 0 || xx >= 64) continue;
            acc += w[(dy + 1) * 3 + (dx + 1)] * src[yy * 64 + xx];
        }
    }
    acc += b1[co];
    float sc = g1[co] / sqrtf(v1[co] + 1e-5f);
    acc = (acc - m1[co]) * sc + be1[co];
    h1[t] = fmaxf(acc, 0.f);
}

// ------- conv3x3 64->16 + BN + relu, fused: h (node-major), sq, xp, asr, adt -
__launch_bounds__(128)
__global__ void k_conv2(const float* __restrict__ h1, const float* __restrict__ W2,
                        const float* __restrict__ b2, const float* __restrict__ g2,
                        const float* __restrict__ be2, const float* __restrict__ m2,
                        const float* __restrict__ v2, const float* __restrict__ Wg,
                        const float* __restrict__ a_src, const float* __restrict__ a_dst,
                        float* __restrict__ h, float* __restrict__ sq,
                        float* __restrict__ xp, float* __restrict__ asr,
                        float* __restrict__ adt) {
    __shared__ float sW2t[576 * 16];    // [ci*9+tap][o]
    __shared__ float sWg[256];
    __shared__ float sA[32];
    int tid = threadIdx.x;
    for (int k = tid; k < 9216; k += 128) {          // coalesced global read, scatter to LDS
        int o = k / 576, ct = k - o * 576;
        sW2t[ct * 16 + o] = W2[k];
    }
    for (int k = tid; k < 256; k += 128) sWg[k] = Wg[k];
    if (tid < 16) { sA[tid] = a_src[tid]; sA[16 + tid] = a_dst[tid]; }
    __syncthreads();
    int blk = blockIdx.x;                 // 8 batches * 32 y-tiles
    int b = blk >> 5, ytile = blk & 31;
    int ty = tid >> 6, x = tid & 63, y = ytile * 2 + ty;
    float acc[16];
#pragma unroll
    for (int o = 0; o < 16; o++) acc[o] = 0.f;
    const float* hb = h1 + (long)b * C1 * NN;
    for (int ci = 0; ci < 64; ci++) {
        const float* plane = hb + ci * NN;
#pragma unroll
        for (int dy = -1; dy <= 1; dy++) {
            int yy = y + dy; bool oky = (yy >= 0 && yy < 64);
#pragma unroll
            for (int dx = -1; dx <= 1; dx++) {
                int xx = x + dx;
                float v = (oky && xx >= 0 && xx < 64) ? plane[yy * 64 + xx] : 0.f;
                int ct = ci * 9 + (dy + 1) * 3 + (dx + 1);
                const float4* wr = (const float4*)&sW2t[ct * 16];
                float4 w0 = wr[0], w1 = wr[1], w2 = wr[2], w3 = wr[3];
                acc[0] += v * w0.x; acc[1] += v * w0.y; acc[2] += v * w0.z; acc[3] += v * w0.w;
                acc[4] += v * w1.x; acc[5] += v * w1.y; acc[6] += v * w1.z; acc[7] += v * w1.w;
                acc[8] += v * w2.x; acc[9] += v * w2.y; acc[10]+= v * w2.z; acc[11]+= v * w2.w;
                acc[12]+= v * w3.x; acc[13]+= v * w3.y; acc[14]+= v * w3.z; acc[15]+= v * w3.w;
            }
        }
    }
    int n = y * 64 + x;
    long node = (long)b * NN + n;
    float nodev[16], sqv = 0.f;
#pragma unroll
    for (int o = 0; o < 16; o++) {
        float a = acc[o] + b2[o];
        float sc = g2[o] / sqrtf(v2[o] + 1e-5f);
        a = (a - m2[o]) * sc + be2[o];
        a = fmaxf(a, 0.f);
        nodev[o] = a; sqv += a * a;
        h[node * 16 + o] = a;
    }
    sq[node] = 0.5f * sqv;                // pre-scaled: scan/merge use dot - 0.5|j|^2
    float xpv[16];
#pragma unroll
    for (int o = 0; o < 16; o++) {
        float a = 0.f;
#pragma unroll
        for (int c = 0; c < 16; c++) a += sWg[o * 16 + c] * nodev[c];
        xpv[o] = a;
        xp[node * 16 + o] = a;
    }
#pragma unroll
    for (int hh = 0; hh < 4; hh++) {
        float as = 0.f, ad = 0.f;
#pragma unroll
        for (int f = 0; f < 4; f++) {
            as += xpv[hh * 4 + f] * sA[hh * 4 + f];
            ad += xpv[hh * 4 + f] * sA[16 + hh * 4 + f];
        }
        asr[node * 4 + hh] = as;
        adt[node * 4 + hh] = ad;
    }
}

// ------- error-free 3-way bf16 split of h: h = hi + mid + lo + O(2^-27) -----
// hi = RNE-bf16(h); mid = RNE-bf16(h - hi); lo = RNE-bf16(h - hi - mid).
// Residual subtractions are exact (Sterbenz). Enables 6-product MFMA scoring
// with ~fp32-ulp-class total error.
__device__ __forceinline__ ushort f2bf(float f) {
    unsigned u = __float_as_uint(f);
    return (ushort)((u + 0x7FFFu + ((u >> 16) & 1u)) >> 16);
}
__device__ __forceinline__ float bf2f(ushort h) {
    return __uint_as_float(((unsigned)h) << 16);
}
__global__ void k_split(const float* __restrict__ h, ushort* __restrict__ hHi,
                        ushort* __restrict__ hMid, ushort* __restrict__ hLo) {
    long t = (long)blockIdx.x * 256 + threadIdx.x;   // node 0..32767
    const float4* hp = (const float4*)&h[t * 16];
    float4 v0 = hp[0], v1 = hp[1], v2 = hp[2], v3 = hp[3];
    float v[16] = { v0.x,v0.y,v0.z,v0.w, v1.x,v1.y,v1.z,v1.w,
                    v2.x,v2.y,v2.z,v2.w, v3.x,v3.y,v3.z,v3.w };
    unsigned wh[8], wm[8], wl[8];
#pragma unroll
    for (int p = 0; p < 8; p++) {
        unsigned packh = 0, packm = 0, packl = 0;
#pragma unroll
        for (int e = 0; e < 2; e++) {
            float f = v[p * 2 + e];
            ushort hi = f2bf(f);
            float t1 = f - bf2f(hi);
            ushort mi = f2bf(t1);
            float t2 = t1 - bf2f(mi);
            ushort lo = f2bf(t2);
            packh |= ((unsigned)hi) << (16 * e);
            packm |= ((unsigned)mi) << (16 * e);
            packl |= ((unsigned)lo) << (16 * e);
        }
        wh[p] = packh; wm[p] = packm; wl[p] = packl;
    }
    uint4* dh = (uint4*)&hHi[t * 16];
    uint4* dm = (uint4*)&hMid[t * 16];
    uint4* dl = (uint4*)&hLo[t * 16];
    dh[0] = make_uint4(wh[0], wh[1], wh[2], wh[3]);
    dh[1] = make_uint4(wh[4], wh[5], wh[6], wh[7]);
    dm[0] = make_uint4(wm[0], wm[1], wm[2], wm[3]);
    dm[1] = make_uint4(wm[4], wm[5], wm[6], wm[7]);
    dl[0] = make_uint4(wl[0], wl[1], wl[2], wl[3]);
    dl[1] = make_uint4(wl[4], wl[5], wl[6], wl[7]);
}

// --------- kNN scan via MFMA: per (32-i tile, j-slice) top-8 candidates -----
// Wave computes 32x32 score tiles D = Hj · Hi^T with v_mfma_f32_32x32x16_bf16
// (6 split-products: hh, hm, mh, hl, lh, mm — error ~2^-25 rel).
// C/D layout (m74/m101-verified): col = lane&31 (the i), row = (reg&3) +
// 8*(reg>>2) + 4*(lane>>5) (the j). A/B fragments: row = lane&31,
// k = 8*(lane>>5)+e — both operands loaded row-major (B^T pattern, as m97).
// Each lane streams its 16 rows/tile into a sorted top-8 (strict >, j
// ascending => lowest-index-on-ties), then lane<->lane^32 merge via the
// max(L[k],R[7-k]) top-8-of-16 trick under (score desc, id asc) total order.
// Output layout identical to the validated kernel; k_gat2 unchanged (exact
// fp32 re-score of the pool => final selection semantics preserved).
__launch_bounds__(256, 4)
__global__ void k_scan(const ushort* __restrict__ hHi, const ushort* __restrict__ hMid,
                       const ushort* __restrict__ hLo, const float* __restrict__ sq,
                       uint4* __restrict__ cand_i) {
    int tid = threadIdx.x, blk = blockIdx.x;
    int b    = blk >> 8;                 // 256 blocks per batch (32 igroups x 8 slices)
    int ig   = (blk >> 3) & 31;
    int sl   = blk & 7;
    int wid  = tid >> 6, lane = tid & 63;
    int ln31 = lane & 31, l5 = lane >> 5;
    int koff = l5 * 8;
    int i0w  = ig * 128 + wid * 32;      // this wave's 32-aligned i-tile base
    int i    = i0w + ln31;
    long bN  = (long)b * NN;

    // i-side fragments (B operand), loaded once
    bf16x8 bi_h = *(const bf16x8*)&hHi [(bN + i) * 16 + koff];
    bf16x8 bi_m = *(const bf16x8*)&hMid[(bN + i) * 16 + koff];
    bf16x8 bi_l = *(const bf16x8*)&hLo [(bN + i) * 16 + koff];

    float s[8]; int id[8];
#pragma unroll
    for (int k = 0; k < 8; k++) { s[k] = -FLT_MAX; id[k] = 65535; }

    int rbase = l5 * 4;
    int j0 = sl * 512;
    for (int t = 0; t < 16; t++, j0 += 32) {
        int jr = j0 + ln31;
        bf16x8 aj_h = *(const bf16x8*)&hHi [(bN + jr) * 16 + koff];
        bf16x8 aj_m = *(const bf16x8*)&hMid[(bN + jr) * 16 + koff];
        bf16x8 aj_l = *(const bf16x8*)&hLo [(bN + jr) * 16 + koff];

        f32x16 acc;
#pragma unroll
        for (int z = 0; z < 16; z++) acc[z] = 0.f;
        acc = __builtin_amdgcn_mfma_f32_32x32x16_bf16(aj_h, bi_h, acc, 0, 0, 0);
        acc = __builtin_amdgcn_mfma_f32_32x32x16_bf16(aj_h, bi_m, acc, 0, 0, 0);
        acc = __builtin_amdgcn_mfma_f32_32x32x16_bf16(aj_m, bi_h, acc, 0, 0, 0);
        acc = __builtin_amdgcn_mfma_f32_32x32x16_bf16(aj_h, bi_l, acc, 0, 0, 0);
        acc = __builtin_amdgcn_mfma_f32_32x32x16_bf16(aj_l, bi_h, acc, 0, 0, 0);
        acc = __builtin_amdgcn_mfma_f32_32x32x16_bf16(aj_m, bi_m, acc, 0, 0, 0);

        // sq for this lane's 16 rows: groups at j0 + 8g + rbase, g=0..3
        float4 sq0 = *(const float4*)&sq[bN + j0 +  0 + rbase];
        float4 sq1 = *(const float4*)&sq[bN + j0 +  8 + rbase];
        float4 sq2 = *(const float4*)&sq[bN + j0 + 16 + rbase];
        float4 sq3 = *(const float4*)&sq[bN + j0 + 24 + rbase];
        float sqv[16] = { sq0.x,sq0.y,sq0.z,sq0.w, sq1.x,sq1.y,sq1.z,sq1.w,
                          sq2.x,sq2.y,sq2.z,sq2.w, sq3.x,sq3.y,sq3.z,sq3.w };
        bool dia = (j0 == i0w);          // wave-uniform: diagonal tile
#pragma unroll
        for (int rr = 0; rr < 16; rr++) {
            int r = (rr & 3) + 8 * (rr >> 2) + rbase;
            float sc = acc[rr] - sqv[rr];
            if (dia && r == ln31) sc = -FLT_MAX;     // exclude self
            int j = j0 + r;
            if (sc > s[7]) {             // strict >: lowest-index kept on ties
                s[7] = sc; id[7] = j;
#pragma unroll
                for (int k = 7; k > 0; k--) {
                    if (s[k] > s[k - 1]) {
                        float td = s[k]; s[k] = s[k - 1]; s[k - 1] = td;
                        int tj = id[k]; id[k] = id[k - 1]; id[k - 1] = tj;
                    }
                }
            }
        }
    }

    // merge lane <-> lane^32 (the two 16-row interleaves of the same i column)
    float ps[8]; int pid[8];
#pragma unroll
    for (int k = 0; k < 8; k++) {
        ps[k]  = __shfl_xor(s[k], 32);
        pid[k] = __shfl_xor(id[k], 32);
    }
    unsigned wi[8];
#pragma unroll
    for (int k = 0; k < 8; k++) {
        float so = ps[7 - k]; int io = pid[7 - k];
        bool mine = (s[k] > so) || (s[k] == so && id[k] < io);
        wi[k] = (unsigned)(mine ? id[k] : io);
    }
    if (lane < 32) {
        uint4 pk;
        pk.x = wi[0] | (wi[1] << 16);
        pk.y = wi[2] | (wi[3] << 16);
        pk.z = wi[4] | (wi[5] << 16);
        pk.w = wi[6] | (wi[7] << 16);
        cand_i[(long)(b * NSL + sl) * NN + i] = pk;
    }
}

// --- merge 8 slice-lists (recompute scores in exact fp32) + GAT -> p --------
__launch_bounds__(256)
__global__ void k_gat2(const uint4* __restrict__ cand_i, const float* __restrict__ h,
                       const float* __restrict__ sq,
                       const float* __restrict__ xp, const float* __restrict__ asr,
                       const float* __restrict__ adt, const float* __restrict__ bg,
                       float* __restrict__ p) {
    int t = blockIdx.x * 256 + threadIdx.x;       // 0..32767
    int b = t >> 12, i = t & 4095;
    long bN = (long)b * NN;
    const float4* ip = (const float4*)&h[(bN + i) * 16];
    float4 r0 = ip[0], r1 = ip[1], r2 = ip[2], r3 = ip[3];
    float ni[16] = { r0.x,r0.y,r0.z,r0.w, r1.x,r1.y,r1.z,r1.w,
                     r2.x,r2.y,r2.z,r2.w, r3.x,r3.y,r3.z,r3.w };
    float fS[8]; int fI[8];
#pragma unroll
    for (int k = 0; k < 8; k++) { fS[k] = -FLT_MAX; fI[k] = 65535; }
    for (int sl = 0; sl < NSL; sl++) {
        uint4 pk = cand_i[(long)(b * NSL + sl) * NN + i];
        unsigned idx8[8] = { pk.x & 0xFFFF, pk.x >> 16, pk.y & 0xFFFF, pk.y >> 16,
                             pk.z & 0xFFFF, pk.z >> 16, pk.w & 0xFFFF, pk.w >> 16 };
#pragma unroll
        for (int k = 0; k < 8; k++) {
            int j = (int)idx8[k];
            const float4* np = (const float4*)&h[(bN + j) * 16];
            float4 a0 = np[0], a1 = np[1], a2 = np[2], a3 = np[3];
            float d = dot16m(ni, a0, a1, a2, a3, sq[bN + j]);
            bool bt = (d > fS[7]) || (d == fS[7] && j < fI[7]);
            if (bt) {
                fS[7] = d; fI[7] = j;
#pragma unroll
                for (int q = 7; q > 0; q--) {
                    bool sw = (fS[q] > fS[q - 1]) || (fS[q] == fS[q - 1] && fI[q] < fI[q - 1]);
                    if (sw) {
                        float td = fS[q]; fS[q] = fS[q - 1]; fS[q - 1] = td;
                        int tj = fI[q]; fI[q] = fI[q - 1]; fI[q - 1] = tj;
                    }
                }
            }
        }
    }
    int nbrs[9];
#pragma unroll
    for (int e = 0; e < 8; e++) nbrs[e] = fI[e];
    nbrs[8] = i;                                   // self-loop
    float adtv[4];
#pragma unroll
    for (int hh = 0; hh < 4; hh++) adtv[hh] = adt[(bN + i) * 4 + hh];
    float mx[4] = { -FLT_MAX, -FLT_MAX, -FLT_MAX, -FLT_MAX };
    float lg[9][4];
#pragma unroll
    for (int e = 0; e < 9; e++) {
        long nb = bN + nbrs[e];
#pragma unroll
        for (int hh = 0; hh < 4; hh++) {
            float l = asr[nb * 4 + hh] + adtv[hh];
            l = (l > 0.f) ? l : 0.2f * l;          // leaky_relu 0.2
            lg[e][hh] = l;
            mx[hh] = fmaxf(mx[hh], l);
        }
    }
    float sum[4] = { 0, 0, 0, 0 };
    float acc[16];
#pragma unroll
    for (int c = 0; c < 16; c++) acc[c] = 0.f;
#pragma unroll
    for (int e = 0; e < 9; e++) {
        long nb = bN + nbrs[e];
        const float4* xpn = (const float4*)&xp[nb * 16];
        float4 x0 = xpn[0], x1 = xpn[1], x2 = xpn[2], x3 = xpn[3];
        float xv[16] = { x0.x,x0.y,x0.z,x0.w, x1.x,x1.y,x1.z,x1.w,
                         x2.x,x2.y,x2.z,x2.w, x3.x,x3.y,x3.z,x3.w };
        float wv[4];
#pragma unroll
        for (int hh = 0; hh < 4; hh++) {
            float w = expf(lg[e][hh] - mx[hh]);
            sum[hh] += w; wv[hh] = w;
        }
#pragma unroll
        for (int hh = 0; hh < 4; hh++)
#pragma unroll
            for (int f = 0; f < 4; f++)
                acc[hh * 4 + f] += wv[hh] * xv[hh * 4 + f];
    }
#pragma unroll
    for (int hh = 0; hh < 4; hh++) {
        float inv = 1.f / sum[hh];
#pragma unroll
        for (int f = 0; f < 4; f++) {
            float o = acc[hh * 4 + f] * inv + bg[hh * 4 + f];
            p[(bN + i) * 16 + hh * 4 + f] = fmaxf(o, 0.f);
        }
    }
}

// ------- 1x1 MLP 16->128->16, fire mask, h += mask*u, 1x1->1 + sigmoid ------
#define USTR 20
__launch_bounds__(256)
__global__ void k_update(const float* __restrict__ p, const float* __restrict__ h,
                         const float* __restrict__ fire, const float* __restrict__ Wu1,
                         const float* __restrict__ bu1, const float* __restrict__ Wu2,
                         const float* __restrict__ bu2, const float* __restrict__ Wo,
                         const float* __restrict__ bo, float* __restrict__ out_low) {
    __shared__ float sU1[128 * 16];
    __shared__ float sU2t[128 * 16];      // [hd][c] = Wu2[c][hd]
    __shared__ float sb1[128];
    __shared__ float uhalf[128 * USTR];
    int tid = threadIdx.x;
    for (int k = tid; k < 2048; k += 256) {
        sU1[k] = Wu1[k];
        sU2t[(k & 127) * 16 + (k >> 7)] = Wu2[k];   // coalesced read, scatter to LDS
    }
    if (tid < 128) sb1[tid] = bu1[tid];
    __syncthreads();
    int lnode = tid & 127, half = tid >> 7;
    long n = (long)blockIdx.x * 128 + lnode;         // 0..32767
    const float4* pp = (const float4*)&p[n * 16];
    float4 p0 = pp[0], p1 = pp[1], p2 = pp[2], p3 = pp[3];
    float pv[16] = { p0.x,p0.y,p0.z,p0.w, p1.x,p1.y,p1.z,p1.w,
                     p2.x,p2.y,p2.z,p2.w, p3.x,p3.y,p3.z,p3.w };
    float u[16];
#pragma unroll
    for (int c = 0; c < 16; c++) u[c] = 0.f;
    int hd0 = half * 64;
    for (int hd = hd0; hd < hd0 + 64; hd++) {
        const float4* r = (const float4*)&sU1[hd * 16];
        float4 r0 = r[0], r1 = r[1], r2 = r[2], r3 = r[3];
        float a = sb1[hd]
            + r0.x*pv[0] + r0.y*pv[1] + r0.z*pv[2] + r0.w*pv[3]
            + r1.x*pv[4] + r1.y*pv[5] + r1.z*pv[6] + r1.w*pv[7]
            + r2.x*pv[8] + r2.y*pv[9] + r2.z*pv[10]+ r2.w*pv[11]
            + r3.x*pv[12]+ r3.y*pv[13]+ r3.z*pv[14]+ r3.w*pv[15];
        a = fmaxf(a, 0.f);
        const float4* tt = (const float4*)&sU2t[hd * 16];
        float4 t0 = tt[0], t1 = tt[1], t2 = tt[2], t3 = tt[3];
        u[0] += t0.x*a; u[1] += t0.y*a; u[2] += t0.z*a; u[3] += t0.w*a;
        u[4] += t1.x*a; u[5] += t1.y*a; u[6] += t1.z*a; u[7] += t1.w*a;
        u[8] += t2.x*a; u[9] += t2.y*a; u[10]+= t2.z*a; u[11]+= t2.w*a;
        u[12]+= t3.x*a; u[13]+= t3.y*a; u[14]+= t3.z*a; u[15]+= t3.w*a;
    }
    if (half == 1) {
        float4* dst = (float4*)&uhalf[lnode * USTR];
        dst[0] = make_float4(u[0], u[1], u[2], u[3]);
        dst[1] = make_float4(u[4], u[5], u[6], u[7]);
        dst[2] = make_float4(u[8], u[9], u[10], u[11]);
        dst[3] = make_float4(u[12], u[13], u[14], u[15]);
    }
    __syncthreads();
    if (half == 0) {
        const float4* src = (const float4*)&uhalf[lnode * USTR];
        float4 o0 = src[0], o1 = src[1], o2 = src[2], o3 = src[3];
        float ou[16] = { o0.x,o0.y,o0.z,o0.w, o1.x,o1.y,o1.z,o1.w,
                         o2.x,o2.y,o2.z,o2.w, o3.x,o3.y,o3.z,o3.w };
        float mask = (fire[n] < 0.5f) ? 1.f : 0.f;
        const float4* hp = (const float4*)&h[n * 16];
        float4 h0 = hp[0], h1v = hp[1], h2 = hp[2], h3 = hp[3];
        float hv[16] = { h0.x,h0.y,h0.z,h0.w, h1v.x,h1v.y,h1v.z,h1v.w,
                         h2.x,h2.y,h2.z,h2.w, h3.x,h3.y,h3.z,h3.w };
        float o = bo[0];
#pragma unroll
        for (int c = 0; c < 16; c++)
            o += Wo[c] * (hv[c] + mask * (u[c] + ou[c] + bu2[c]));
        out_low[n] = 1.f / (1.f + expf(-o));
    }
}

// ---------------- bilinear upsample 64 -> 256 (half-pixel, clamp) -----------
__global__ void k_up(const float* __restrict__ ol, float* __restrict__ out) {
    int t = blockIdx.x * 256 + threadIdx.x;
    if (t >= BATCH * HIGH * HIGH) return;
    int b = t >> 16, oy = (t >> 8) & 255, ox = t & 255;
    float cy = (oy + 0.5f) * 0.25f - 0.5f;
    float cx = (ox + 0.5f) * 0.25f - 0.5f;
    int iy0 = (int)floorf(cy); float fy = cy - (float)iy0;
    int ix0 = (int)floorf(cx); float fx = cx - (float)ix0;
    int y0 = min(max(iy0, 0), 63), y1 = min(max(iy0 + 1, 0), 63);
    int x0 = min(max(ix0, 0), 63), x1 = min(max(ix0 + 1, 0), 63);
    const float* s = ol + b * NN;
    float v = (1.f - fy) * ((1.f - fx) * s[y0 * 64 + x0] + fx * s[y0 * 64 + x1])
            + fy * ((1.f - fx) * s[y1 * 64 + x0] + fx * s[y1 * 64 + x1]);
    out[t] = v;
}

extern "C" void kernel_launch(void* const* d_in, const int* in_sizes, int n_in,
                              void* d_out, int out_size, void* d_ws, size_t ws_size,
                              hipStream_t stream) {
    const float* x    = (const float*)d_in[0];
    const float* fire = (const float*)d_in[1];
    const float* W1   = (const float*)d_in[2];
    const float* b1   = (const float*)d_in[3];
    const float* g1   = (const float*)d_in[4];
    const float* be1  = (const float*)d_in[5];
    const float* m1   = (const float*)d_in[6];
    const float* v1   = (const float*)d_in[7];
    const float* W2   = (const float*)d_in[8];
    const float* b2   = (const float*)d_in[9];
    const float* g2   = (const float*)d_in[10];
    const float* be2  = (const float*)d_in[11];
    const float* m2   = (const float*)d_in[12];
    const float* v2   = (const float*)d_in[13];
    const float* Wg   = (const float*)d_in[14];
    const float* a_src= (const float*)d_in[15];
    const float* a_dst= (const float*)d_in[16];
    const float* bg   = (const float*)d_in[17];
    const float* Wu1  = (const float*)d_in[18];
    const float* bu1  = (const float*)d_in[19];
    const float* Wu2  = (const float*)d_in[20];
    const float* bu2  = (const float*)d_in[21];
    const float* Wo   = (const float*)d_in[22];
    const float* bo   = (const float*)d_in[23];

    float* ws  = (float*)d_ws;
    float* xl  = ws + OFF_XL;
    float* h1  = ws + OFF_H1;
    float* h   = ws + OFF_H;
    float* sq  = ws + OFF_SQ;
    float* xp  = ws + OFF_XP;
    float* asr = ws + OFF_ASR;
    float* adt = ws + OFF_ADT;
    float* p   = ws + OFF_P;
    float* ol  = ws + OFF_OL;
    // H1 region reuse (dead after conv2): cand_i 1,048,576 floats, then the
    // three bf16 split arrays (262,144 floats each) — total 1,835,008 of
    // 2,097,152 available. No footprint growth.
    uint4*  cand_i = (uint4*)(ws + OFF_H1);
    ushort* hHi    = (ushort*)(ws + OFF_H1 + 1048576);
    ushort* hMid   = (ushort*)(ws + OFF_H1 + 1310720);
    ushort* hLo    = (ushort*)(ws + OFF_H1 + 1572864);

    k_down  <<<(BATCH * NN + 127) / 128, 128, 0, stream>>>(x, xl);
    k_conv1 <<<(BATCH * C1 * NN) / 256, 256, 0, stream>>>(xl, W1, b1, g1, be1, m1, v1, h1);
    k_conv2 <<<BATCH * 32, 128, 0, stream>>>(h1, W2, b2, g2, be2, m2, v2, Wg, a_src, a_dst,
                                             h, sq, xp, asr, adt);
    k_split <<<BATCH * NN / 256, 256, 0, stream>>>(h, hHi, hMid, hLo);
    k_scan  <<<BATCH * 32 * NSL, 256, 0, stream>>>(hHi, hMid, hLo, sq, cand_i);
    k_gat2  <<<BATCH * NN / 256, 256, 0, stream>>>(cand_i, h, sq, xp, asr, adt, bg, p);
    k_update<<<BATCH * NN / 128, 256, 0, stream>>>(p, h, fire, Wu1, bu1, Wu2, bu2, Wo, bo, ol);
    k_up    <<<(BATCH * HIGH * HIGH) / 256, 256, 0, stream>>>(ol, (float*)d_out);
}

// Round 4
// 372.358 us; speedup vs baseline: 1.1784x; 1.0572x over previous
//
#include <hip/hip_runtime.h>
#include <math.h>
#include <float.h>

#define BATCH 8
#define HIGH  256
#define LOWR  64
#define NN    4096          // LOWR*LOWR
#define HIDC  16
#define C1    64
#define NSL   4             // j-slices in kNN scan (1024 j each)

// workspace layout (floats) — footprint identical to the validated R1/R2 layout
#define OFF_XL   0
#define OFF_H1   (OFF_XL  + BATCH*NN)            // 2.097M floats; reused after conv2:
                                                 //   [0 .. 524,287]           cand_i (2 MB, NSL=4)
                                                 //   [1,048,576 .. 1,835,007] bf16 hi/mid/lo splits
#define OFF_H    (OFF_H1  + BATCH*C1*NN)         // node-major [B*N][16]
#define OFF_SQ   (OFF_H   + BATCH*NN*HIDC)       // 0.5*|h|^2 per node
#define OFF_XP   (OFF_SQ  + BATCH*NN)
#define OFF_ASR  (OFF_XP  + BATCH*NN*HIDC)
#define OFF_ADT  (OFF_ASR + BATCH*NN*4)
#define OFF_P    (OFF_ADT + BATCH*NN*4)
#define OFF_OL   (OFF_P   + BATCH*NN*HIDC)

typedef __attribute__((ext_vector_type(8)))  short bf16x8;
typedef __attribute__((ext_vector_type(16))) float f32x16;

// identical-arithmetic dot used by k_gat2 (exact fp32 re-score of the pool —
// final selection semantics unchanged from the validated kernel)
__device__ __forceinline__ float dot16m(const float ni[16], float4 a0, float4 a1,
                                        float4 a2, float4 a3, float hs) {
    return ni[0]*a0.x + ni[1]*a0.y + ni[2]*a0.z + ni[3]*a0.w
         + ni[4]*a1.x + ni[5]*a1.y + ni[6]*a1.z + ni[7]*a1.w
         + ni[8]*a2.x + ni[9]*a2.y + ni[10]*a2.z + ni[11]*a2.w
         + ni[12]*a3.x + ni[13]*a3.y + ni[14]*a3.z + ni[15]*a3.w
         - hs;
}

// ---------------- bilinear downsample 256 -> 64 (antialiased triangle) -------
__global__ void k_down(const float* __restrict__ x, float* __restrict__ xl) {
    int t = blockIdx.x * 128 + threadIdx.x;
    if (t >= BATCH * NN) return;
    int b = t >> 12, oy = (t >> 6) & 63, ox = t & 63;
    const float* xb = x + b * HIGH * HIGH;
    float cy = 4.f * oy + 1.5f, cx = 4.f * ox + 1.5f;
    float wy[8], wx[8], sy = 0.f, sx = 0.f;
#pragma unroll
    for (int k = 0; k < 8; k++) {
        int iy = 4 * oy - 2 + k;
        float w = 1.f - fabsf((float)iy - cy) * 0.25f;
        if (iy < 0 || iy >= HIGH) w = 0.f;
        wy[k] = w; sy += w;
        int ix = 4 * ox - 2 + k;
        float v = 1.f - fabsf((float)ix - cx) * 0.25f;
        if (ix < 0 || ix >= HIGH) v = 0.f;
        wx[k] = v; sx += v;
    }
    float acc = 0.f;
#pragma unroll
    for (int ky = 0; ky < 8; ky++) {
        if (wy[ky] == 0.f) continue;
        int iy = 4 * oy - 2 + ky;
        float rowacc = 0.f;
#pragma unroll
        for (int kx = 0; kx < 8; kx++) {
            if (wx[kx] == 0.f) continue;
            int ix = 4 * ox - 2 + kx;
            rowacc += wx[kx] * xb[iy * HIGH + ix];
        }
        acc += wy[ky] * rowacc;
    }
    xl[t] = acc / (sy * sx);
}

// ---------------- conv3x3 1->64 + BN + relu ---------------------------------
__global__ void k_conv1(const float* __restrict__ xl, const float* __restrict__ W1,
                        const float* __restrict__ b1, const float* __restrict__ g1,
                        const float* __restrict__ be1, const float* __restrict__ m1,
                        const float* __restrict__ v1, float* __restrict__ h1) {
    int t = blockIdx.x * 256 + threadIdx.x;
    if (t >= BATCH * C1 * NN) return;
    int b = t >> 18, co = (t >> 12) & 63, y = (t >> 6) & 63, x = t & 63;
    const float* src = xl + b * NN;
    const float* w = W1 + co * 9;
    float acc = 0.f;
#pragma unroll
    for (int dy = -1; dy <= 1; dy++) {
        int yy = y + dy; if (yy < 0 || yy >= 64) continue;
#pragma unroll
        for (int dx = -1; dx <= 1; dx++) {
            int xx = x + dx; if (xx < 0 || xx >= 64) continue;
            acc += w[(dy + 1) * 3 + (dx + 1)] * src[yy * 64 + xx];
        }
    }
    acc += b1[co];
    float sc = g1[co] / sqrtf(v1[co] + 1e-5f);
    acc = (acc - m1[co]) * sc + be1[co];
    h1[t] = fmaxf(acc, 0.f);
}

// ------- conv3x3 64->16 + BN + relu, fused: h (node-major), sq, xp, asr, adt -
__launch_bounds__(128)
__global__ void k_conv2(const float* __restrict__ h1, const float* __restrict__ W2,
                        const float* __restrict__ b2, const float* __restrict__ g2,
                        const float* __restrict__ be2, const float* __restrict__ m2,
                        const float* __restrict__ v2, const float* __restrict__ Wg,
                        const float* __restrict__ a_src, const float* __restrict__ a_dst,
                        float* __restrict__ h, float* __restrict__ sq,
                        float* __restrict__ xp, float* __restrict__ asr,
                        float* __restrict__ adt) {
    __shared__ float sW2t[576 * 16];    // [ci*9+tap][o]
    __shared__ float sWg[256];
    __shared__ float sA[32];
    int tid = threadIdx.x;
    for (int k = tid; k < 9216; k += 128) {          // coalesced global read, scatter to LDS
        int o = k / 576, ct = k - o * 576;
        sW2t[ct * 16 + o] = W2[k];
    }
    for (int k = tid; k < 256; k += 128) sWg[k] = Wg[k];
    if (tid < 16) { sA[tid] = a_src[tid]; sA[16 + tid] = a_dst[tid]; }
    __syncthreads();
    int blk = blockIdx.x;                 // 8 batches * 32 y-tiles
    int b = blk >> 5, ytile = blk & 31;
    int ty = tid >> 6, x = tid & 63, y = ytile * 2 + ty;
    float acc[16];
#pragma unroll
    for (int o = 0; o < 16; o++) acc[o] = 0.f;
    const float* hb = h1 + (long)b * C1 * NN;
    for (int ci = 0; ci < 64; ci++) {
        const float* plane = hb + ci * NN;
#pragma unroll
        for (int dy = -1; dy <= 1; dy++) {
            int yy = y + dy; bool oky = (yy >= 0 && yy < 64);
#pragma unroll
            for (int dx = -1; dx <= 1; dx++) {
                int xx = x + dx;
                float v = (oky && xx >= 0 && xx < 64) ? plane[yy * 64 + xx] : 0.f;
                int ct = ci * 9 + (dy + 1) * 3 + (dx + 1);
                const float4* wr = (const float4*)&sW2t[ct * 16];
                float4 w0 = wr[0], w1 = wr[1], w2 = wr[2], w3 = wr[3];
                acc[0] += v * w0.x; acc[1] += v * w0.y; acc[2] += v * w0.z; acc[3] += v * w0.w;
                acc[4] += v * w1.x; acc[5] += v * w1.y; acc[6] += v * w1.z; acc[7] += v * w1.w;
                acc[8] += v * w2.x; acc[9] += v * w2.y; acc[10]+= v * w2.z; acc[11]+= v * w2.w;
                acc[12]+= v * w3.x; acc[13]+= v * w3.y; acc[14]+= v * w3.z; acc[15]+= v * w3.w;
            }
        }
    }
    int n = y * 64 + x;
    long node = (long)b * NN + n;
    float nodev[16], sqv = 0.f;
#pragma unroll
    for (int o = 0; o < 16; o++) {
        float a = acc[o] + b2[o];
        float sc = g2[o] / sqrtf(v2[o] + 1e-5f);
        a = (a - m2[o]) * sc + be2[o];
        a = fmaxf(a, 0.f);
        nodev[o] = a; sqv += a * a;
        h[node * 16 + o] = a;
    }
    sq[node] = 0.5f * sqv;                // pre-scaled: scan/merge use dot - 0.5|j|^2
    float xpv[16];
#pragma unroll
    for (int o = 0; o < 16; o++) {
        float a = 0.f;
#pragma unroll
        for (int c = 0; c < 16; c++) a += sWg[o * 16 + c] * nodev[c];
        xpv[o] = a;
        xp[node * 16 + o] = a;
    }
#pragma unroll
    for (int hh = 0; hh < 4; hh++) {
        float as = 0.f, ad = 0.f;
#pragma unroll
        for (int f = 0; f < 4; f++) {
            as += xpv[hh * 4 + f] * sA[hh * 4 + f];
            ad += xpv[hh * 4 + f] * sA[16 + hh * 4 + f];
        }
        asr[node * 4 + hh] = as;
        adt[node * 4 + hh] = ad;
    }
}

// ------- error-free 3-way bf16 split of h: h = hi + mid + lo + O(2^-27) -----
__device__ __forceinline__ ushort f2bf(float f) {
    unsigned u = __float_as_uint(f);
    return (ushort)((u + 0x7FFFu + ((u >> 16) & 1u)) >> 16);
}
__device__ __forceinline__ float bf2f(ushort h) {
    return __uint_as_float(((unsigned)h) << 16);
}
__global__ void k_split(const float* __restrict__ h, ushort* __restrict__ hHi,
                        ushort* __restrict__ hMid, ushort* __restrict__ hLo) {
    long t = (long)blockIdx.x * 256 + threadIdx.x;   // node 0..32767
    const float4* hp = (const float4*)&h[t * 16];
    float4 v0 = hp[0], v1 = hp[1], v2 = hp[2], v3 = hp[3];
    float v[16] = { v0.x,v0.y,v0.z,v0.w, v1.x,v1.y,v1.z,v1.w,
                    v2.x,v2.y,v2.z,v2.w, v3.x,v3.y,v3.z,v3.w };
    unsigned wh[8], wm[8], wl[8];
#pragma unroll
    for (int p = 0; p < 8; p++) {
        unsigned packh = 0, packm = 0, packl = 0;
#pragma unroll
        for (int e = 0; e < 2; e++) {
            float f = v[p * 2 + e];
            ushort hi = f2bf(f);
            float t1 = f - bf2f(hi);
            ushort mi = f2bf(t1);
            float t2 = t1 - bf2f(mi);
            ushort lo = f2bf(t2);
            packh |= ((unsigned)hi) << (16 * e);
            packm |= ((unsigned)mi) << (16 * e);
            packl |= ((unsigned)lo) << (16 * e);
        }
        wh[p] = packh; wm[p] = packm; wl[p] = packl;
    }
    uint4* dh = (uint4*)&hHi[t * 16];
    uint4* dm = (uint4*)&hMid[t * 16];
    uint4* dl = (uint4*)&hLo[t * 16];
    dh[0] = make_uint4(wh[0], wh[1], wh[2], wh[3]);
    dh[1] = make_uint4(wh[4], wh[5], wh[6], wh[7]);
    dm[0] = make_uint4(wm[0], wm[1], wm[2], wm[3]);
    dm[1] = make_uint4(wm[4], wm[5], wm[6], wm[7]);
    dl[0] = make_uint4(wl[0], wl[1], wl[2], wl[3]);
    dl[1] = make_uint4(wl[4], wl[5], wl[6], wl[7]);
}

// --- shared tile-score routine: MUST be bit-identical between pass 1/2 ------
// MFMA chain is dependency-ordered (each op consumes prior acc) => the 6
// products always execute in the same order => deterministic recompute.
__device__ __forceinline__ void tile_scores(const ushort* __restrict__ hHi,
        const ushort* __restrict__ hMid, const ushort* __restrict__ hLo,
        const float* __restrict__ sq, long bN, int j0, int ln31, int koff,
        int rbase, int i0w, bf16x8 bi_h, bf16x8 bi_m, bf16x8 bi_l,
        float scv[16]) {
    int jr = j0 + ln31;
    bf16x8 aj_h = *(const bf16x8*)&hHi [(bN + jr) * 16 + koff];
    bf16x8 aj_m = *(const bf16x8*)&hMid[(bN + jr) * 16 + koff];
    bf16x8 aj_l = *(const bf16x8*)&hLo [(bN + jr) * 16 + koff];
    f32x16 acc;
#pragma unroll
    for (int z = 0; z < 16; z++) acc[z] = 0.f;
    acc = __builtin_amdgcn_mfma_f32_32x32x16_bf16(aj_h, bi_h, acc, 0, 0, 0);
    acc = __builtin_amdgcn_mfma_f32_32x32x16_bf16(aj_h, bi_m, acc, 0, 0, 0);
    acc = __builtin_amdgcn_mfma_f32_32x32x16_bf16(aj_m, bi_h, acc, 0, 0, 0);
    acc = __builtin_amdgcn_mfma_f32_32x32x16_bf16(aj_h, bi_l, acc, 0, 0, 0);
    acc = __builtin_amdgcn_mfma_f32_32x32x16_bf16(aj_l, bi_h, acc, 0, 0, 0);
    acc = __builtin_amdgcn_mfma_f32_32x32x16_bf16(aj_m, bi_m, acc, 0, 0, 0);
    float4 sq0 = *(const float4*)&sq[bN + j0 +  0 + rbase];
    float4 sq1 = *(const float4*)&sq[bN + j0 +  8 + rbase];
    float4 sq2 = *(const float4*)&sq[bN + j0 + 16 + rbase];
    float4 sq3 = *(const float4*)&sq[bN + j0 + 24 + rbase];
    float sqv[16] = { sq0.x,sq0.y,sq0.z,sq0.w, sq1.x,sq1.y,sq1.z,sq1.w,
                      sq2.x,sq2.y,sq2.z,sq2.w, sq3.x,sq3.y,sq3.z,sq3.w };
#pragma unroll
    for (int rr = 0; rr < 16; rr++) scv[rr] = acc[rr] - sqv[rr];
    if (j0 == i0w) {                       // diagonal tile: exclude self
#pragma unroll
        for (int rr = 0; rr < 16; rr++) {
            int r = (rr & 3) + 8 * (rr >> 2) + rbase;
            if (r == ln31) scv[rr] = -FLT_MAX;
        }
    }
}

// --------- kNN scan, two-pass scores-only selection --------------------------
// Pass 1: branchless 16-instr value-bubble keeps exact top-8 SCORES per lane;
//         pair-merge (shfl_xor + max trick) => theta = exact 8th-best score
//         (with multiplicity) of the (column, slice).
// Pass 2: recompute scores bit-identically; push ids with sc > theta (<=7
//         guaranteed) and first-8 (j-ascending) ids with sc == theta to LDS.
// Assembly emits the exact reference top-8 SET per slice (order irrelevant:
// k_gat2 re-scores the pool in exact fp32 with the reference tie-break).
// amdgpu_waves_per_eu(4,4): grid = 1024 blocks = 4 blocks/CU resident; pin
// occupancy so the allocator uses the full 128-VGPR budget (R3 showed
// VGPR_Count=40 + ~28 extra VALU/candidate = AGPR shuttling).
__global__ __attribute__((amdgpu_waves_per_eu(4, 4))) __launch_bounds__(256)
void k_scan(const ushort* __restrict__ hHi, const ushort* __restrict__ hMid,
            const ushort* __restrict__ hLo, const float* __restrict__ sq,
            uint4* __restrict__ cand_i) {
    __shared__ unsigned lists[256][17];  // [tid][0..7]=A ids, [8..15]=B ids, [16]=trash
    __shared__ ushort outl[256][8];
    int tid = threadIdx.x, blk = blockIdx.x;
    int b  = blk >> 7;                   // 128 blocks per batch (32 ig x 4 sl)
    int ig = (blk >> 2) & 31;
    int sl = blk & 3;
    int wid = tid >> 6, lane = tid & 63;
    int ln31 = lane & 31, l5 = lane >> 5;
    int koff = l5 * 8;
    int i0w = ig * 128 + wid * 32;       // this wave's 32-aligned i-tile base
    int i   = i0w + ln31;
    long bN = (long)b * NN;
    int rbase = l5 * 4;
    int jbase = sl * 1024;

    bf16x8 bi_h = *(const bf16x8*)&hHi [(bN + i) * 16 + koff];
    bf16x8 bi_m = *(const bf16x8*)&hMid[(bN + i) * 16 + koff];
    bf16x8 bi_l = *(const bf16x8*)&hLo [(bN + i) * 16 + koff];

    // ---- pass 1: top-8 scores only ----
    float s[8];
#pragma unroll
    for (int k = 0; k < 8; k++) s[k] = -FLT_MAX;
    for (int t = 0; t < 32; t++) {
        int j0 = jbase + t * 32;
        float scv[16];
        tile_scores(hHi, hMid, hLo, sq, bN, j0, ln31, koff, rbase, i0w,
                    bi_h, bi_m, bi_l, scv);
        float tmax = scv[0];
#pragma unroll
        for (int rr = 1; rr < 16; rr++) tmax = fmaxf(tmax, scv[rr]);
        if (__any(tmax > s[7])) {        // equal-to-s[7] can't change the value multiset
#pragma unroll
            for (int rr = 0; rr < 16; rr++) {
                float x = scv[rr];
#pragma unroll
                for (int k = 0; k < 8; k++) {
                    float hi = fmaxf(s[k], x);
                    x = fminf(s[k], x);
                    s[k] = hi;
                }
            }
        }
    }
    // pair-merge: top-8 of union(lane, lane^32) as a multiset; theta = its min.
    float mv[8];
#pragma unroll
    for (int k = 0; k < 8; k++) mv[k] = fmaxf(s[k], __shfl_xor(s[7 - k], 32));
    float theta = mv[0];
#pragma unroll
    for (int k = 1; k < 8; k++) theta = fminf(theta, mv[k]);

    // ---- pass 2: id recovery ----
    unsigned* ldsw = &lists[0][0];
    int baseA = tid * 17, baseB = baseA + 8, trash = baseA + 16;
    int nA = 0, nB = 0;
    for (int t = 0; t < 32; t++) {
        int j0 = jbase + t * 32;
        float scv[16];
        tile_scores(hHi, hMid, hLo, sq, bN, j0, ln31, koff, rbase, i0w,
                    bi_h, bi_m, bi_l, scv);
        float tmax = scv[0];
#pragma unroll
        for (int rr = 1; rr < 16; rr++) tmax = fmaxf(tmax, scv[rr]);
        if (!__any(tmax >= theta)) continue;
#pragma unroll
        for (int rr = 0; rr < 16; rr++) {
            float sc = scv[rr];
            int r = (rr & 3) + 8 * (rr >> 2) + rbase;
            int j = j0 + r;
            bool cA = (sc > theta) && (nA < 8);   // nA<8 is pure insurance (<=7 by math)
            bool cB = (sc == theta) && (nB < 8);  // first-8 ties, j-ascending
            if (__any(cA || cB)) {
                int ia = cA ? (baseA + nA) : trash;
                ldsw[ia] = (unsigned)j;
                nA += cA;
                int ib = cB ? (baseB + nB) : trash;
                ldsw[ib] = (unsigned)j;
                nB += cB;
            }
        }
    }
    int pA = __shfl_xor(nA, 32);
    int pB = __shfl_xor(nB, 32);
    __syncthreads();
    // ---- assembly (per column, lane<32): A ids + smallest-j ties to fill 8 ----
    if (lane < 32) {
        int tp = tid + 32;
        int n = 0;
        for (int k = 0; k < nA && n < 8; k++) outl[tid][n++] = (ushort)lists[tid][k];
        for (int k = 0; k < pA && n < 8; k++) outl[tid][n++] = (ushort)lists[tp][k];
        int p0 = 0, p1 = 0;
        while (n < 8) {                  // two-pointer merge of j-ascending tie lists
            unsigned a = (p0 < nB) ? lists[tid][8 + p0] : 0xFFFFFFFFu;
            unsigned c = (p1 < pB) ? lists[tp][8 + p1] : 0xFFFFFFFFu;
            bool t0 = a < c;
            outl[tid][n++] = (ushort)(t0 ? a : c);
            p0 += t0 ? 1 : 0; p1 += t0 ? 0 : 1;
        }
        uint4 pk = *(const uint4*)&outl[tid][0];
        cand_i[(long)(b * NSL + sl) * NN + i] = pk;
    }
}

// --- merge 4 slice-lists (recompute scores in exact fp32) + GAT -> p --------
__launch_bounds__(256)
__global__ void k_gat2(const uint4* __restrict__ cand_i, const float* __restrict__ h,
                       const float* __restrict__ sq,
                       const float* __restrict__ xp, const float* __restrict__ asr,
                       const float* __restrict__ adt, const float* __restrict__ bg,
                       float* __restrict__ p) {
    int t = blockIdx.x * 256 + threadIdx.x;       // 0..32767
    int b = t >> 12, i = t & 4095;
    long bN = (long)b * NN;
    const float4* ip = (const float4*)&h[(bN + i) * 16];
    float4 r0 = ip[0], r1 = ip[1], r2 = ip[2], r3 = ip[3];
    float ni[16] = { r0.x,r0.y,r0.z,r0.w, r1.x,r1.y,r1.z,r1.w,
                     r2.x,r2.y,r2.z,r2.w, r3.x,r3.y,r3.z,r3.w };
    float fS[8]; int fI[8];
#pragma unroll
    for (int k = 0; k < 8; k++) { fS[k] = -FLT_MAX; fI[k] = 65535; }
    for (int sl = 0; sl < NSL; sl++) {
        uint4 pk = cand_i[(long)(b * NSL + sl) * NN + i];
        unsigned idx8[8] = { pk.x & 0xFFFF, pk.x >> 16, pk.y & 0xFFFF, pk.y >> 16,
                             pk.z & 0xFFFF, pk.z >> 16, pk.w & 0xFFFF, pk.w >> 16 };
#pragma unroll
        for (int k = 0; k < 8; k++) {
            int j = (int)idx8[k];
            const float4* np = (const float4*)&h[(bN + j) * 16];
            float4 a0 = np[0], a1 = np[1], a2 = np[2], a3 = np[3];
            float d = dot16m(ni, a0, a1, a2, a3, sq[bN + j]);
            bool bt = (d > fS[7]) || (d == fS[7] && j < fI[7]);
            if (bt) {
                fS[7] = d; fI[7] = j;
#pragma unroll
                for (int q = 7; q > 0; q--) {
                    bool sw = (fS[q] > fS[q - 1]) || (fS[q] == fS[q - 1] && fI[q] < fI[q - 1]);
                    if (sw) {
                        float td = fS[q]; fS[q] = fS[q - 1]; fS[q - 1] = td;
                        int tj = fI[q]; fI[q] = fI[q - 1]; fI[q - 1] = tj;
                    }
                }
            }
        }
    }
    int nbrs[9];
#pragma unroll
    for (int e = 0; e < 8; e++) nbrs[e] = fI[e];
    nbrs[8] = i;                                   // self-loop
    float adtv[4];
#pragma unroll
    for (int hh = 0; hh < 4; hh++) adtv[hh] = adt[(bN + i) * 4 + hh];
    float mx[4] = { -FLT_MAX, -FLT_MAX, -FLT_MAX, -FLT_MAX };
    float lg[9][4];
#pragma unroll
    for (int e = 0; e < 9; e++) {
        long nb = bN + nbrs[e];
#pragma unroll
        for (int hh = 0; hh < 4; hh++) {
            float l = asr[nb * 4 + hh] + adtv[hh];
            l = (l > 0.f) ? l : 0.2f * l;          // leaky_relu 0.2
            lg[e][hh] = l;
            mx[hh] = fmaxf(mx[hh], l);
        }
    }
    float sum[4] = { 0, 0, 0, 0 };
    float acc[16];
#pragma unroll
    for (int c = 0; c < 16; c++) acc[c] = 0.f;
#pragma unroll
    for (int e = 0; e < 9; e++) {
        long nb = bN + nbrs[e];
        const float4* xpn = (const float4*)&xp[nb * 16];
        float4 x0 = xpn[0], x1 = xpn[1], x2 = xpn[2], x3 = xpn[3];
        float xv[16] = { x0.x,x0.y,x0.z,x0.w, x1.x,x1.y,x1.z,x1.w,
                         x2.x,x2.y,x2.z,x2.w, x3.x,x3.y,x3.z,x3.w };
        float wv[4];
#pragma unroll
        for (int hh = 0; hh < 4; hh++) {
            float w = expf(lg[e][hh] - mx[hh]);
            sum[hh] += w; wv[hh] = w;
        }
#pragma unroll
        for (int hh = 0; hh < 4; hh++)
#pragma unroll
            for (int f = 0; f < 4; f++)
                acc[hh * 4 + f] += wv[hh] * xv[hh * 4 + f];
    }
#pragma unroll
    for (int hh = 0; hh < 4; hh++) {
        float inv = 1.f / sum[hh];
#pragma unroll
        for (int f = 0; f < 4; f++) {
            float o = acc[hh * 4 + f] * inv + bg[hh * 4 + f];
            p[(bN + i) * 16 + hh * 4 + f] = fmaxf(o, 0.f);
        }
    }
}

// ------- 1x1 MLP 16->128->16, fire mask, h += mask*u, 1x1->1 + sigmoid ------
#define USTR 20
__launch_bounds__(256)
__global__ void k_update(const float* __restrict__ p, const float* __restrict__ h,
                         const float* __restrict__ fire, const float* __restrict__ Wu1,
                         const float* __restrict__ bu1, const float* __restrict__ Wu2,
                         const float* __restrict__ bu2, const float* __restrict__ Wo,
                         const float* __restrict__ bo, float* __restrict__ out_low) {
    __shared__ float sU1[128 * 16];
    __shared__ float sU2t[128 * 16];      // [hd][c] = Wu2[c][hd]
    __shared__ float sb1[128];
    __shared__ float uhalf[128 * USTR];
    int tid = threadIdx.x;
    for (int k = tid; k < 2048; k += 256) {
        sU1[k] = Wu1[k];
        sU2t[(k & 127) * 16 + (k >> 7)] = Wu2[k];   // coalesced read, scatter to LDS
    }
    if (tid < 128) sb1[tid] = bu1[tid];
    __syncthreads();
    int lnode = tid & 127, half = tid >> 7;
    long n = (long)blockIdx.x * 128 + lnode;         // 0..32767
    const float4* pp = (const float4*)&p[n * 16];
    float4 p0 = pp[0], p1 = pp[1], p2 = pp[2], p3 = pp[3];
    float pv[16] = { p0.x,p0.y,p0.z,p0.w, p1.x,p1.y,p1.z,p1.w,
                     p2.x,p2.y,p2.z,p2.w, p3.x,p3.y,p3.z,p3.w };
    float u[16];
#pragma unroll
    for (int c = 0; c < 16; c++) u[c] = 0.f;
    int hd0 = half * 64;
    for (int hd = hd0; hd < hd0 + 64; hd++) {
        const float4* r = (const float4*)&sU1[hd * 16];
        float4 r0 = r[0], r1 = r[1], r2 = r[2], r3 = r[3];
        float a = sb1[hd]
            + r0.x*pv[0] + r0.y*pv[1] + r0.z*pv[2] + r0.w*pv[3]
            + r1.x*pv[4] + r1.y*pv[5] + r1.z*pv[6] + r1.w*pv[7]
            + r2.x*pv[8] + r2.y*pv[9] + r2.z*pv[10]+ r2.w*pv[11]
            + r3.x*pv[12]+ r3.y*pv[13]+ r3.z*pv[14]+ r3.w*pv[15];
        a = fmaxf(a, 0.f);
        const float4* tt = (const float4*)&sU2t[hd * 16];
        float4 t0 = tt[0], t1 = tt[1], t2 = tt[2], t3 = tt[3];
        u[0] += t0.x*a; u[1] += t0.y*a; u[2] += t0.z*a; u[3] += t0.w*a;
        u[4] += t1.x*a; u[5] += t1.y*a; u[6] += t1.z*a; u[7] += t1.w*a;
        u[8] += t2.x*a; u[9] += t2.y*a; u[10]+= t2.z*a; u[11]+= t2.w*a;
        u[12]+= t3.x*a; u[13]+= t3.y*a; u[14]+= t3.z*a; u[15]+= t3.w*a;
    }
    if (half == 1) {
        float4* dst = (float4*)&uhalf[lnode * USTR];
        dst[0] = make_float4(u[0], u[1], u[2], u[3]);
        dst[1] = make_float4(u[4], u[5], u[6], u[7]);
        dst[2] = make_float4(u[8], u[9], u[10], u[11]);
        dst[3] = make_float4(u[12], u[13], u[14], u[15]);
    }
    __syncthreads();
    if (half == 0) {
        const float4* src = (const float4*)&uhalf[lnode * USTR];
        float4 o0 = src[0], o1 = src[1], o2 = src[2], o3 = src[3];
        float ou[16] = { o0.x,o0.y,o0.z,o0.w, o1.x,o1.y,o1.z,o1.w,
                         o2.x,o2.y,o2.z,o2.w, o3.x,o3.y,o3.z,o3.w };
        float mask = (fire[n] < 0.5f) ? 1.f : 0.f;
        const float4* hp = (const float4*)&h[n * 16];
        float4 h0 = hp[0], h1v = hp[1], h2 = hp[2], h3 = hp[3];
        float hv[16] = { h0.x,h0.y,h0.z,h0.w, h1v.x,h1v.y,h1v.z,h1v.w,
                         h2.x,h2.y,h2.z,h2.w, h3.x,h3.y,h3.z,h3.w };
        float o = bo[0];
#pragma unroll
        for (int c = 0; c < 16; c++)
            o += Wo[c] * (hv[c] + mask * (u[c] + ou[c] + bu2[c]));
        out_low[n] = 1.f / (1.f + expf(-o));
    }
}

// ---------------- bilinear upsample 64 -> 256 (half-pixel, clamp) -----------
__global__ void k_up(const float* __restrict__ ol, float* __restrict__ out) {
    int t = blockIdx.x * 256 + threadIdx.x;
    if (t >= BATCH * HIGH * HIGH) return;
    int b = t >> 16, oy = (t >> 8) & 255, ox = t & 255;
    float cy = (oy + 0.5f) * 0.25f - 0.5f;
    float cx = (ox + 0.5f) * 0.25f - 0.5f;
    int iy0 = (int)floorf(cy); float fy = cy - (float)iy0;
    int ix0 = (int)floorf(cx); float fx = cx - (float)ix0;
    int y0 = min(max(iy0, 0), 63), y1 = min(max(iy0 + 1, 0), 63);
    int x0 = min(max(ix0, 0), 63), x1 = min(max(ix0 + 1, 0), 63);
    const float* s = ol + b * NN;
    float v = (1.f - fy) * ((1.f - fx) * s[y0 * 64 + x0] + fx * s[y0 * 64 + x1])
            + fy * ((1.f - fx) * s[y1 * 64 + x0] + fx * s[y1 * 64 + x1]);
    out[t] = v;
}

extern "C" void kernel_launch(void* const* d_in, const int* in_sizes, int n_in,
                              void* d_out, int out_size, void* d_ws, size_t ws_size,
                              hipStream_t stream) {
    const float* x    = (const float*)d_in[0];
    const float* fire = (const float*)d_in[1];
    const float* W1   = (const float*)d_in[2];
    const float* b1   = (const float*)d_in[3];
    const float* g1   = (const float*)d_in[4];
    const float* be1  = (const float*)d_in[5];
    const float* m1   = (const float*)d_in[6];
    const float* v1   = (const float*)d_in[7];
    const float* W2   = (const float*)d_in[8];
    const float* b2   = (const float*)d_in[9];
    const float* g2   = (const float*)d_in[10];
    const float* be2  = (const float*)d_in[11];
    const float* m2   = (const float*)d_in[12];
    const float* v2   = (const float*)d_in[13];
    const float* Wg   = (const float*)d_in[14];
    const float* a_src= (const float*)d_in[15];
    const float* a_dst= (const float*)d_in[16];
    const float* bg   = (const float*)d_in[17];
    const float* Wu1  = (const float*)d_in[18];
    const float* bu1  = (const float*)d_in[19];
    const float* Wu2  = (const float*)d_in[20];
    const float* bu2  = (const float*)d_in[21];
    const float* Wo   = (const float*)d_in[22];
    const float* bo   = (const float*)d_in[23];

    float* ws  = (float*)d_ws;
    float* xl  = ws + OFF_XL;
    float* h1  = ws + OFF_H1;
    float* h   = ws + OFF_H;
    float* sq  = ws + OFF_SQ;
    float* xp  = ws + OFF_XP;
    float* asr = ws + OFF_ASR;
    float* adt = ws + OFF_ADT;
    float* p   = ws + OFF_P;
    float* ol  = ws + OFF_OL;
    // H1 region reuse (dead after conv2): cand_i 2 MB (NSL=4), then the three
    // bf16 split arrays at the same offsets as R3. No footprint growth.
    uint4*  cand_i = (uint4*)(ws + OFF_H1);
    ushort* hHi    = (ushort*)(ws + OFF_H1 + 1048576);
    ushort* hMid   = (ushort*)(ws + OFF_H1 + 1310720);
    ushort* hLo    = (ushort*)(ws + OFF_H1 + 1572864);

    k_down  <<<(BATCH * NN + 127) / 128, 128, 0, stream>>>(x, xl);
    k_conv1 <<<(BATCH * C1 * NN) / 256, 256, 0, stream>>>(xl, W1, b1, g1, be1, m1, v1, h1);
    k_conv2 <<<BATCH * 32, 128, 0, stream>>>(h1, W2, b2, g2, be2, m2, v2, Wg, a_src, a_dst,
                                             h, sq, xp, asr, adt);
    k_split <<<BATCH * NN / 256, 256, 0, stream>>>(h, hHi, hMid, hLo);
    k_scan  <<<BATCH * 32 * NSL, 256, 0, stream>>>(hHi, hMid, hLo, sq, cand_i);
    k_gat2  <<<BATCH * NN / 256, 256, 0, stream>>>(cand_i, h, sq, xp, asr, adt, bg, p);
    k_update<<<BATCH * NN / 128, 256, 0, stream>>>(p, h, fire, Wu1, bu1, Wu2, bu2, Wo, bo, ol);
    k_up    <<<(BATCH * HIGH * HIGH) / 256, 256, 0, stream>>>(ol, (float*)d_out);
}

// Round 5
// 357.088 us; speedup vs baseline: 1.2288x; 1.0428x over previous
//
#include <hip/hip_runtime.h>
#include <math.h>
#include <float.h>

#define BATCH 8
#define HIGH  256
#define LOWR  64
#define NN    4096          // LOWR*LOWR
#define HIDC  16
#define C1    64
#define NSL   4             // j-slices in kNN scan (1024 j each)

// workspace layout (floats) — footprint identical to the validated layout
#define OFF_XL   0
#define OFF_H1   (OFF_XL  + BATCH*NN)            // 2.097M floats; reused after conv2:
                                                 //   [0 .. 524,287]           cand_i (2 MB, NSL=4)
                                                 //   [1,048,576 .. 1,835,007] bf16 hi/mid/lo splits
                                                 //   [1,835,008 .. 1,867,775] nsq (= -sq)
#define OFF_H    (OFF_H1  + BATCH*C1*NN)         // node-major [B*N][16]
#define OFF_SQ   (OFF_H   + BATCH*NN*HIDC)       // 0.5*|h|^2 per node
#define OFF_XP   (OFF_SQ  + BATCH*NN)
#define OFF_ASR  (OFF_XP  + BATCH*NN*HIDC)
#define OFF_ADT  (OFF_ASR + BATCH*NN*4)
#define OFF_P    (OFF_ADT + BATCH*NN*4)
#define OFF_OL   (OFF_P   + BATCH*NN*HIDC)

typedef __attribute__((ext_vector_type(8)))  short bf16x8;
typedef __attribute__((ext_vector_type(16))) float f32x16;

// identical-arithmetic dot used by k_gat2 (exact fp32 re-score of the pool —
// final selection semantics unchanged from the validated kernel)
__device__ __forceinline__ float dot16m(const float ni[16], float4 a0, float4 a1,
                                        float4 a2, float4 a3, float hs) {
    return ni[0]*a0.x + ni[1]*a0.y + ni[2]*a0.z + ni[3]*a0.w
         + ni[4]*a1.x + ni[5]*a1.y + ni[6]*a1.z + ni[7]*a1.w
         + ni[8]*a2.x + ni[9]*a2.y + ni[10]*a2.z + ni[11]*a2.w
         + ni[12]*a3.x + ni[13]*a3.y + ni[14]*a3.z + ni[15]*a3.w
         - hs;
}

// ---------------- bilinear downsample 256 -> 64 (antialiased triangle) -------
__global__ void k_down(const float* __restrict__ x, float* __restrict__ xl) {
    int t = blockIdx.x * 128 + threadIdx.x;
    if (t >= BATCH * NN) return;
    int b = t >> 12, oy = (t >> 6) & 63, ox = t & 63;
    const float* xb = x + b * HIGH * HIGH;
    float cy = 4.f * oy + 1.5f, cx = 4.f * ox + 1.5f;
    float wy[8], wx[8], sy = 0.f, sx = 0.f;
#pragma unroll
    for (int k = 0; k < 8; k++) {
        int iy = 4 * oy - 2 + k;
        float w = 1.f - fabsf((float)iy - cy) * 0.25f;
        if (iy < 0 || iy >= HIGH) w = 0.f;
        wy[k] = w; sy += w;
        int ix = 4 * ox - 2 + k;
        float v = 1.f - fabsf((float)ix - cx) * 0.25f;
        if (ix < 0 || ix >= HIGH) v = 0.f;
        wx[k] = v; sx += v;
    }
    float acc = 0.f;
#pragma unroll
    for (int ky = 0; ky < 8; ky++) {
        if (wy[ky] == 0.f) continue;
        int iy = 4 * oy - 2 + ky;
        float rowacc = 0.f;
#pragma unroll
        for (int kx = 0; kx < 8; kx++) {
            if (wx[kx] == 0.f) continue;
            int ix = 4 * ox - 2 + kx;
            rowacc += wx[kx] * xb[iy * HIGH + ix];
        }
        acc += wy[ky] * rowacc;
    }
    xl[t] = acc / (sy * sx);
}

// ---------------- conv3x3 1->64 + BN + relu ---------------------------------
__global__ void k_conv1(const float* __restrict__ xl, const float* __restrict__ W1,
                        const float* __restrict__ b1, const float* __restrict__ g1,
                        const float* __restrict__ be1, const float* __restrict__ m1,
                        const float* __restrict__ v1, float* __restrict__ h1) {
    int t = blockIdx.x * 256 + threadIdx.x;
    if (t >= BATCH * C1 * NN) return;
    int b = t >> 18, co = (t >> 12) & 63, y = (t >> 6) & 63, x = t & 63;
    const float* src = xl + b * NN;
    const float* w = W1 + co * 9;
    float acc = 0.f;
#pragma unroll
    for (int dy = -1; dy <= 1; dy++) {
        int yy = y + dy; if (yy < 0 || yy >= 64) continue;
#pragma unroll
        for (int dx = -1; dx <= 1; dx++) {
            int xx = x + dx; if (xx < 0 || xx >= 64) continue;
            acc += w[(dy + 1) * 3 + (dx + 1)] * src[yy * 64 + xx];
        }
    }
    acc += b1[co];
    float sc = g1[co] / sqrtf(v1[co] + 1e-5f);
    acc = (acc - m1[co]) * sc + be1[co];
    h1[t] = fmaxf(acc, 0.f);
}

// ------- conv3x3 64->16 + BN + relu, fused: h (node-major), sq, xp, asr, adt -
__launch_bounds__(128)
__global__ void k_conv2(const float* __restrict__ h1, const float* __restrict__ W2,
                        const float* __restrict__ b2, const float* __restrict__ g2,
                        const float* __restrict__ be2, const float* __restrict__ m2,
                        const float* __restrict__ v2, const float* __restrict__ Wg,
                        const float* __restrict__ a_src, const float* __restrict__ a_dst,
                        float* __restrict__ h, float* __restrict__ sq,
                        float* __restrict__ xp, float* __restrict__ asr,
                        float* __restrict__ adt) {
    __shared__ float sW2t[576 * 16];    // [ci*9+tap][o]
    __shared__ float sWg[256];
    __shared__ float sA[32];
    int tid = threadIdx.x;
    for (int k = tid; k < 9216; k += 128) {          // coalesced global read, scatter to LDS
        int o = k / 576, ct = k - o * 576;
        sW2t[ct * 16 + o] = W2[k];
    }
    for (int k = tid; k < 256; k += 128) sWg[k] = Wg[k];
    if (tid < 16) { sA[tid] = a_src[tid]; sA[16 + tid] = a_dst[tid]; }
    __syncthreads();
    int blk = blockIdx.x;                 // 8 batches * 32 y-tiles
    int b = blk >> 5, ytile = blk & 31;
    int ty = tid >> 6, x = tid & 63, y = ytile * 2 + ty;
    float acc[16];
#pragma unroll
    for (int o = 0; o < 16; o++) acc[o] = 0.f;
    const float* hb = h1 + (long)b * C1 * NN;
    for (int ci = 0; ci < 64; ci++) {
        const float* plane = hb + ci * NN;
#pragma unroll
        for (int dy = -1; dy <= 1; dy++) {
            int yy = y + dy; bool oky = (yy >= 0 && yy < 64);
#pragma unroll
            for (int dx = -1; dx <= 1; dx++) {
                int xx = x + dx;
                float v = (oky && xx >= 0 && xx < 64) ? plane[yy * 64 + xx] : 0.f;
                int ct = ci * 9 + (dy + 1) * 3 + (dx + 1);
                const float4* wr = (const float4*)&sW2t[ct * 16];
                float4 w0 = wr[0], w1 = wr[1], w2 = wr[2], w3 = wr[3];
                acc[0] += v * w0.x; acc[1] += v * w0.y; acc[2] += v * w0.z; acc[3] += v * w0.w;
                acc[4] += v * w1.x; acc[5] += v * w1.y; acc[6] += v * w1.z; acc[7] += v * w1.w;
                acc[8] += v * w2.x; acc[9] += v * w2.y; acc[10]+= v * w2.z; acc[11]+= v * w2.w;
                acc[12]+= v * w3.x; acc[13]+= v * w3.y; acc[14]+= v * w3.z; acc[15]+= v * w3.w;
            }
        }
    }
    int n = y * 64 + x;
    long node = (long)b * NN + n;
    float nodev[16], sqv = 0.f;
#pragma unroll
    for (int o = 0; o < 16; o++) {
        float a = acc[o] + b2[o];
        float sc = g2[o] / sqrtf(v2[o] + 1e-5f);
        a = (a - m2[o]) * sc + be2[o];
        a = fmaxf(a, 0.f);
        nodev[o] = a; sqv += a * a;
        h[node * 16 + o] = a;
    }
    sq[node] = 0.5f * sqv;                // pre-scaled: scan/merge use dot - 0.5|j|^2
    float xpv[16];
#pragma unroll
    for (int o = 0; o < 16; o++) {
        float a = 0.f;
#pragma unroll
        for (int c = 0; c < 16; c++) a += sWg[o * 16 + c] * nodev[c];
        xpv[o] = a;
        xp[node * 16 + o] = a;
    }
#pragma unroll
    for (int hh = 0; hh < 4; hh++) {
        float as = 0.f, ad = 0.f;
#pragma unroll
        for (int f = 0; f < 4; f++) {
            as += xpv[hh * 4 + f] * sA[hh * 4 + f];
            ad += xpv[hh * 4 + f] * sA[16 + hh * 4 + f];
        }
        asr[node * 4 + hh] = as;
        adt[node * 4 + hh] = ad;
    }
}

// ------- error-free 3-way bf16 split of h: h = hi + mid + lo + O(2^-27) -----
__device__ __forceinline__ ushort f2bf(float f) {
    unsigned u = __float_as_uint(f);
    return (ushort)((u + 0x7FFFu + ((u >> 16) & 1u)) >> 16);
}
__device__ __forceinline__ float bf2f(ushort h) {
    return __uint_as_float(((unsigned)h) << 16);
}
__global__ void k_split(const float* __restrict__ h, const float* __restrict__ sq,
                        ushort* __restrict__ hHi, ushort* __restrict__ hMid,
                        ushort* __restrict__ hLo, float* __restrict__ nsq) {
    long t = (long)blockIdx.x * 256 + threadIdx.x;   // node 0..32767
    nsq[t] = -sq[t];                                  // negated for MFMA C-init
    const float4* hp = (const float4*)&h[t * 16];
    float4 v0 = hp[0], v1 = hp[1], v2 = hp[2], v3 = hp[3];
    float v[16] = { v0.x,v0.y,v0.z,v0.w, v1.x,v1.y,v1.z,v1.w,
                    v2.x,v2.y,v2.z,v2.w, v3.x,v3.y,v3.z,v3.w };
    unsigned wh[8], wm[8], wl[8];
#pragma unroll
    for (int p = 0; p < 8; p++) {
        unsigned packh = 0, packm = 0, packl = 0;
#pragma unroll
        for (int e = 0; e < 2; e++) {
            float f = v[p * 2 + e];
            ushort hi = f2bf(f);
            float t1 = f - bf2f(hi);
            ushort mi = f2bf(t1);
            float t2 = t1 - bf2f(mi);
            ushort lo = f2bf(t2);
            packh |= ((unsigned)hi) << (16 * e);
            packm |= ((unsigned)mi) << (16 * e);
            packl |= ((unsigned)lo) << (16 * e);
        }
        wh[p] = packh; wm[p] = packm; wl[p] = packl;
    }
    uint4* dh = (uint4*)&hHi[t * 16];
    uint4* dm = (uint4*)&hMid[t * 16];
    uint4* dl = (uint4*)&hLo[t * 16];
    dh[0] = make_uint4(wh[0], wh[1], wh[2], wh[3]);
    dh[1] = make_uint4(wh[4], wh[5], wh[6], wh[7]);
    dm[0] = make_uint4(wm[0], wm[1], wm[2], wm[3]);
    dm[1] = make_uint4(wm[4], wm[5], wm[6], wm[7]);
    dl[0] = make_uint4(wl[0], wl[1], wl[2], wl[3]);
    dl[1] = make_uint4(wl[4], wl[5], wl[6], wl[7]);
}

// --- shared tile-score routine: MUST be bit-identical between pass 1/2 ------
// C-operand initialized to -0.5|h_j|^2 (nsq), so scv = acc directly — saves
// 16 zero-inits + 16 subs per tile vs R4. MFMA chain dependency-ordered =>
// deterministic recompute in pass 2.
__device__ __forceinline__ void tile_scores(const ushort* __restrict__ hHi,
        const ushort* __restrict__ hMid, const ushort* __restrict__ hLo,
        const float* __restrict__ nsq, long bN, int j0, int ln31, int koff,
        int rbase, int i0w, bf16x8 bi_h, bf16x8 bi_m, bf16x8 bi_l,
        float scv[16]) {
    int jr = j0 + ln31;
    bf16x8 aj_h = *(const bf16x8*)&hHi [(bN + jr) * 16 + koff];
    bf16x8 aj_m = *(const bf16x8*)&hMid[(bN + jr) * 16 + koff];
    bf16x8 aj_l = *(const bf16x8*)&hLo [(bN + jr) * 16 + koff];
    float4 q0 = *(const float4*)&nsq[bN + j0 +  0 + rbase];
    float4 q1 = *(const float4*)&nsq[bN + j0 +  8 + rbase];
    float4 q2 = *(const float4*)&nsq[bN + j0 + 16 + rbase];
    float4 q3 = *(const float4*)&nsq[bN + j0 + 24 + rbase];
    f32x16 acc;
    acc[0]  = q0.x; acc[1]  = q0.y; acc[2]  = q0.z; acc[3]  = q0.w;
    acc[4]  = q1.x; acc[5]  = q1.y; acc[6]  = q1.z; acc[7]  = q1.w;
    acc[8]  = q2.x; acc[9]  = q2.y; acc[10] = q2.z; acc[11] = q2.w;
    acc[12] = q3.x; acc[13] = q3.y; acc[14] = q3.z; acc[15] = q3.w;
    acc = __builtin_amdgcn_mfma_f32_32x32x16_bf16(aj_h, bi_h, acc, 0, 0, 0);
    acc = __builtin_amdgcn_mfma_f32_32x32x16_bf16(aj_h, bi_m, acc, 0, 0, 0);
    acc = __builtin_amdgcn_mfma_f32_32x32x16_bf16(aj_m, bi_h, acc, 0, 0, 0);
    acc = __builtin_amdgcn_mfma_f32_32x32x16_bf16(aj_h, bi_l, acc, 0, 0, 0);
    acc = __builtin_amdgcn_mfma_f32_32x32x16_bf16(aj_l, bi_h, acc, 0, 0, 0);
    acc = __builtin_amdgcn_mfma_f32_32x32x16_bf16(aj_m, bi_m, acc, 0, 0, 0);
#pragma unroll
    for (int rr = 0; rr < 16; rr++) scv[rr] = acc[rr];
    if (j0 == i0w) {                       // wave-uniform: diagonal tile, mask self
#pragma unroll
        for (int rr = 0; rr < 16; rr++) {
            int r = (rr & 3) + 8 * (rr >> 2) + rbase;
            if (r == ln31) scv[rr] = -FLT_MAX;
        }
    }
}

// --------- kNN scan, two-pass scores-only selection --------------------------
// Pass 1: branchless value-bubble (16 VALU/score) => exact top-8 SCORES/lane;
//         pair-merge via shfl_xor + max trick => theta = exact 8th-best of
//         the (column, slice) multiset. No tile guard (never fires: qualifying
//         events blanket all tiles — R4 PMC-backed reasoning).
// Pass 2: recompute scores bit-identically; build per-lane gt/eq bitmasks in
//         the static unroll, then short ffs-loop pushes ids to LDS (A: >theta,
//         <=7 by math; B: ==theta first-8 j-ascending). Assembly emits the
//         exact reference top-8 SET per slice (order irrelevant: k_gat2
//         re-scores the pool in exact fp32 with the reference tie-break).
__global__ __attribute__((amdgpu_waves_per_eu(4, 4))) __launch_bounds__(256)
void k_scan(const ushort* __restrict__ hHi, const ushort* __restrict__ hMid,
            const ushort* __restrict__ hLo, const float* __restrict__ nsq,
            uint4* __restrict__ cand_i) {
    __shared__ unsigned lists[256][17];  // [tid][0..7]=A ids, [8..15]=B ids, [16]=trash
    __shared__ ushort outl[256][8];
    int tid = threadIdx.x, blk = blockIdx.x;
    int b  = blk >> 7;                   // 128 blocks per batch (32 ig x 4 sl)
    int ig = (blk >> 2) & 31;
    int sl = blk & 3;
    int wid = tid >> 6, lane = tid & 63;
    int ln31 = lane & 31, l5 = lane >> 5;
    int koff = l5 * 8;
    int i0w = ig * 128 + wid * 32;       // this wave's 32-aligned i-tile base
    int i   = i0w + ln31;
    long bN = (long)b * NN;
    int rbase = l5 * 4;
    int jbase = sl * 1024;

    bf16x8 bi_h = *(const bf16x8*)&hHi [(bN + i) * 16 + koff];
    bf16x8 bi_m = *(const bf16x8*)&hMid[(bN + i) * 16 + koff];
    bf16x8 bi_l = *(const bf16x8*)&hLo [(bN + i) * 16 + koff];

    // ---- pass 1: top-8 scores only ----
    float s[8];
#pragma unroll
    for (int k = 0; k < 8; k++) s[k] = -FLT_MAX;
    for (int t = 0; t < 32; t++) {
        int j0 = jbase + t * 32;
        float scv[16];
        tile_scores(hHi, hMid, hLo, nsq, bN, j0, ln31, koff, rbase, i0w,
                    bi_h, bi_m, bi_l, scv);
#pragma unroll
        for (int rr = 0; rr < 16; rr++) {
            float x = scv[rr];
#pragma unroll
            for (int k = 0; k < 8; k++) {
                float hi = fmaxf(s[k], x);
                x = fminf(s[k], x);
                s[k] = hi;
            }
        }
    }
    // pair-merge: top-8 of union(lane, lane^32) as a multiset; theta = its min.
    float mv[8];
#pragma unroll
    for (int k = 0; k < 8; k++) mv[k] = fmaxf(s[k], __shfl_xor(s[7 - k], 32));
    float theta = mv[0];
#pragma unroll
    for (int k = 1; k < 8; k++) theta = fminf(theta, mv[k]);

    // ---- pass 2: id recovery via bitmask + ffs ----
    unsigned* ldsw = &lists[0][0];
    int baseA = tid * 17, baseB = baseA + 8, trash = baseA + 16;
    int nA = 0, nB = 0;
    for (int t = 0; t < 32; t++) {
        int j0 = jbase + t * 32;
        float scv[16];
        tile_scores(hHi, hMid, hLo, nsq, bN, j0, ln31, koff, rbase, i0w,
                    bi_h, bi_m, bi_l, scv);
        unsigned gm = 0, em = 0;
#pragma unroll
        for (int rr = 0; rr < 16; rr++) {
            gm |= (scv[rr] >  theta) ? (1u << rr) : 0u;
            em |= (scv[rr] == theta) ? (1u << rr) : 0u;
        }
        unsigned m = gm | em;
        while (__any(m != 0u)) {
            if (m) {
                int rr = __ffs(m) - 1;
                m &= m - 1u;
                int r = (rr & 3) + ((rr >> 2) << 3) + rbase;
                int j = j0 + r;
                bool isGt = (gm >> rr) & 1u;
                bool cA = isGt && (nA < 8);   // <=7 by math; insurance
                bool cB = (!isGt) && (nB < 8);
                int ia = cA ? (baseA + nA) : trash;
                ldsw[ia] = (unsigned)j;
                nA += cA;
                int ib = cB ? (baseB + nB) : trash;
                ldsw[ib] = (unsigned)j;
                nB += cB;
            }
        }
    }
    int pA = __shfl_xor(nA, 32);
    int pB = __shfl_xor(nB, 32);
    __syncthreads();
    // ---- assembly (per column, lane<32): A ids + smallest-j ties to fill 8 ----
    if (lane < 32) {
        int tp = tid + 32;
        int n = 0;
        for (int k = 0; k < nA && n < 8; k++) outl[tid][n++] = (ushort)lists[tid][k];
        for (int k = 0; k < pA && n < 8; k++) outl[tid][n++] = (ushort)lists[tp][k];
        int p0 = 0, p1 = 0;
        while (n < 8) {                  // two-pointer merge of j-ascending tie lists
            unsigned a = (p0 < nB) ? lists[tid][8 + p0] : 0xFFFFFFFFu;
            unsigned c = (p1 < pB) ? lists[tp][8 + p1] : 0xFFFFFFFFu;
            bool t0 = a < c;
            outl[tid][n++] = (ushort)(t0 ? a : c);
            p0 += t0 ? 1 : 0; p1 += t0 ? 0 : 1;
        }
        uint4 pk = *(const uint4*)&outl[tid][0];
        cand_i[(long)(b * NSL + sl) * NN + i] = pk;
    }
}

// --- merge 4 slice-lists (recompute scores in exact fp32) + GAT -> p --------
__launch_bounds__(256)
__global__ void k_gat2(const uint4* __restrict__ cand_i, const float* __restrict__ h,
                       const float* __restrict__ sq,
                       const float* __restrict__ xp, const float* __restrict__ asr,
                       const float* __restrict__ adt, const float* __restrict__ bg,
                       float* __restrict__ p) {
    int t = blockIdx.x * 256 + threadIdx.x;       // 0..32767
    int b = t >> 12, i = t & 4095;
    long bN = (long)b * NN;
    const float4* ip = (const float4*)&h[(bN + i) * 16];
    float4 r0 = ip[0], r1 = ip[1], r2 = ip[2], r3 = ip[3];
    float ni[16] = { r0.x,r0.y,r0.z,r0.w, r1.x,r1.y,r1.z,r1.w,
                     r2.x,r2.y,r2.z,r2.w, r3.x,r3.y,r3.z,r3.w };
    float fS[8]; int fI[8];
#pragma unroll
    for (int k = 0; k < 8; k++) { fS[k] = -FLT_MAX; fI[k] = 65535; }
    for (int sl = 0; sl < NSL; sl++) {
        uint4 pk = cand_i[(long)(b * NSL + sl) * NN + i];
        unsigned idx8[8] = { pk.x & 0xFFFF, pk.x >> 16, pk.y & 0xFFFF, pk.y >> 16,
                             pk.z & 0xFFFF, pk.z >> 16, pk.w & 0xFFFF, pk.w >> 16 };
#pragma unroll
        for (int k = 0; k < 8; k++) {
            int j = (int)idx8[k];
            const float4* np = (const float4*)&h[(bN + j) * 16];
            float4 a0 = np[0], a1 = np[1], a2 = np[2], a3 = np[3];
            float d = dot16m(ni, a0, a1, a2, a3, sq[bN + j]);
            bool bt = (d > fS[7]) || (d == fS[7] && j < fI[7]);
            if (bt) {
                fS[7] = d; fI[7] = j;
#pragma unroll
                for (int q = 7; q > 0; q--) {
                    bool sw = (fS[q] > fS[q - 1]) || (fS[q] == fS[q - 1] && fI[q] < fI[q - 1]);
                    if (sw) {
                        float td = fS[q]; fS[q] = fS[q - 1]; fS[q - 1] = td;
                        int tj = fI[q]; fI[q] = fI[q - 1]; fI[q - 1] = tj;
                    }
                }
            }
        }
    }
    int nbrs[9];
#pragma unroll
    for (int e = 0; e < 8; e++) nbrs[e] = fI[e];
    nbrs[8] = i;                                   // self-loop
    float adtv[4];
#pragma unroll
    for (int hh = 0; hh < 4; hh++) adtv[hh] = adt[(bN + i) * 4 + hh];
    float mx[4] = { -FLT_MAX, -FLT_MAX, -FLT_MAX, -FLT_MAX };
    float lg[9][4];
#pragma unroll
    for (int e = 0; e < 9; e++) {
        long nb = bN + nbrs[e];
#pragma unroll
        for (int hh = 0; hh < 4; hh++) {
            float l = asr[nb * 4 + hh] + adtv[hh];
            l = (l > 0.f) ? l : 0.2f * l;          // leaky_relu 0.2
            lg[e][hh] = l;
            mx[hh] = fmaxf(mx[hh], l);
        }
    }
    float sum[4] = { 0, 0, 0, 0 };
    float acc[16];
#pragma unroll
    for (int c = 0; c < 16; c++) acc[c] = 0.f;
#pragma unroll
    for (int e = 0; e < 9; e++) {
        long nb = bN + nbrs[e];
        const float4* xpn = (const float4*)&xp[nb * 16];
        float4 x0 = xpn[0], x1 = xpn[1], x2 = xpn[2], x3 = xpn[3];
        float xv[16] = { x0.x,x0.y,x0.z,x0.w, x1.x,x1.y,x1.z,x1.w,
                         x2.x,x2.y,x2.z,x2.w, x3.x,x3.y,x3.z,x3.w };
        float wv[4];
#pragma unroll
        for (int hh = 0; hh < 4; hh++) {
            float w = expf(lg[e][hh] - mx[hh]);
            sum[hh] += w; wv[hh] = w;
        }
#pragma unroll
        for (int hh = 0; hh < 4; hh++)
#pragma unroll
            for (int f = 0; f < 4; f++)
                acc[hh * 4 + f] += wv[hh] * xv[hh * 4 + f];
    }
#pragma unroll
    for (int hh = 0; hh < 4; hh++) {
        float inv = 1.f / sum[hh];
#pragma unroll
        for (int f = 0; f < 4; f++) {
            float o = acc[hh * 4 + f] * inv + bg[hh * 4 + f];
            p[(bN + i) * 16 + hh * 4 + f] = fmaxf(o, 0.f);
        }
    }
}

// ------- 1x1 MLP 16->128->16, fire mask, h += mask*u, 1x1->1 + sigmoid ------
#define USTR 20
__launch_bounds__(256)
__global__ void k_update(const float* __restrict__ p, const float* __restrict__ h,
                         const float* __restrict__ fire, const float* __restrict__ Wu1,
                         const float* __restrict__ bu1, const float* __restrict__ Wu2,
                         const float* __restrict__ bu2, const float* __restrict__ Wo,
                         const float* __restrict__ bo, float* __restrict__ out_low) {
    __shared__ float sU1[128 * 16];
    __shared__ float sU2t[128 * 16];      // [hd][c] = Wu2[c][hd]
    __shared__ float sb1[128];
    __shared__ float uhalf[128 * USTR];
    int tid = threadIdx.x;
    for (int k = tid; k < 2048; k += 256) {
        sU1[k] = Wu1[k];
        sU2t[(k & 127) * 16 + (k >> 7)] = Wu2[k];   // coalesced read, scatter to LDS
    }
    if (tid < 128) sb1[tid] = bu1[tid];
    __syncthreads();
    int lnode = tid & 127, half = tid >> 7;
    long n = (long)blockIdx.x * 128 + lnode;         // 0..32767
    const float4* pp = (const float4*)&p[n * 16];
    float4 p0 = pp[0], p1 = pp[1], p2 = pp[2], p3 = pp[3];
    float pv[16] = { p0.x,p0.y,p0.z,p0.w, p1.x,p1.y,p1.z,p1.w,
                     p2.x,p2.y,p2.z,p2.w, p3.x,p3.y,p3.z,p3.w };
    float u[16];
#pragma unroll
    for (int c = 0; c < 16; c++) u[c] = 0.f;
    int hd0 = half * 64;
    for (int hd = hd0; hd < hd0 + 64; hd++) {
        const float4* r = (const float4*)&sU1[hd * 16];
        float4 r0 = r[0], r1 = r[1], r2 = r[2], r3 = r[3];
        float a = sb1[hd]
            + r0.x*pv[0] + r0.y*pv[1] + r0.z*pv[2] + r0.w*pv[3]
            + r1.x*pv[4] + r1.y*pv[5] + r1.z*pv[6] + r1.w*pv[7]
            + r2.x*pv[8] + r2.y*pv[9] + r2.z*pv[10]+ r2.w*pv[11]
            + r3.x*pv[12]+ r3.y*pv[13]+ r3.z*pv[14]+ r3.w*pv[15];
        a = fmaxf(a, 0.f);
        const float4* tt = (const float4*)&sU2t[hd * 16];
        float4 t0 = tt[0], t1 = tt[1], t2 = tt[2], t3 = tt[3];
        u[0] += t0.x*a; u[1] += t0.y*a; u[2] += t0.z*a; u[3] += t0.w*a;
        u[4] += t1.x*a; u[5] += t1.y*a; u[6] += t1.z*a; u[7] += t1.w*a;
        u[8] += t2.x*a; u[9] += t2.y*a; u[10]+= t2.z*a; u[11]+= t2.w*a;
        u[12]+= t3.x*a; u[13]+= t3.y*a; u[14]+= t3.z*a; u[15]+= t3.w*a;
    }
    if (half == 1) {
        float4* dst = (float4*)&uhalf[lnode * USTR];
        dst[0] = make_float4(u[0], u[1], u[2], u[3]);
        dst[1] = make_float4(u[4], u[5], u[6], u[7]);
        dst[2] = make_float4(u[8], u[9], u[10], u[11]);
        dst[3] = make_float4(u[12], u[13], u[14], u[15]);
    }
    __syncthreads();
    if (half == 0) {
        const float4* src = (const float4*)&uhalf[lnode * USTR];
        float4 o0 = src[0], o1 = src[1], o2 = src[2], o3 = src[3];
        float ou[16] = { o0.x,o0.y,o0.z,o0.w, o1.x,o1.y,o1.z,o1.w,
                         o2.x,o2.y,o2.z,o2.w, o3.x,o3.y,o3.z,o3.w };
        float mask = (fire[n] < 0.5f) ? 1.f : 0.f;
        const float4* hp = (const float4*)&h[n * 16];
        float4 h0 = hp[0], h1v = hp[1], h2 = hp[2], h3 = hp[3];
        float hv[16] = { h0.x,h0.y,h0.z,h0.w, h1v.x,h1v.y,h1v.z,h1v.w,
                         h2.x,h2.y,h2.z,h2.w, h3.x,h3.y,h3.z,h3.w };
        float o = bo[0];
#pragma unroll
        for (int c = 0; c < 16; c++)
            o += Wo[c] * (hv[c] + mask * (u[c] + ou[c] + bu2[c]));
        out_low[n] = 1.f / (1.f + expf(-o));
    }
}

// ---------------- bilinear upsample 64 -> 256 (half-pixel, clamp) -----------
__global__ void k_up(const float* __restrict__ ol, float* __restrict__ out) {
    int t = blockIdx.x * 256 + threadIdx.x;
    if (t >= BATCH * HIGH * HIGH) return;
    int b = t >> 16, oy = (t >> 8) & 255, ox = t & 255;
    float cy = (oy + 0.5f) * 0.25f - 0.5f;
    float cx = (ox + 0.5f) * 0.25f - 0.5f;
    int iy0 = (int)floorf(cy); float fy = cy - (float)iy0;
    int ix0 = (int)floorf(cx); float fx = cx - (float)ix0;
    int y0 = min(max(iy0, 0), 63), y1 = min(max(iy0 + 1, 0), 63);
    int x0 = min(max(ix0, 0), 63), x1 = min(max(ix0 + 1, 0), 63);
    const float* s = ol + b * NN;
    float v = (1.f - fy) * ((1.f - fx) * s[y0 * 64 + x0] + fx * s[y0 * 64 + x1])
            + fy * ((1.f - fx) * s[y1 * 64 + x0] + fx * s[y1 * 64 + x1]);
    out[t] = v;
}

extern "C" void kernel_launch(void* const* d_in, const int* in_sizes, int n_in,
                              void* d_out, int out_size, void* d_ws, size_t ws_size,
                              hipStream_t stream) {
    const float* x    = (const float*)d_in[0];
    const float* fire = (const float*)d_in[1];
    const float* W1   = (const float*)d_in[2];
    const float* b1   = (const float*)d_in[3];
    const float* g1   = (const float*)d_in[4];
    const float* be1  = (const float*)d_in[5];
    const float* m1   = (const float*)d_in[6];
    const float* v1   = (const float*)d_in[7];
    const float* W2   = (const float*)d_in[8];
    const float* b2   = (const float*)d_in[9];
    const float* g2   = (const float*)d_in[10];
    const float* be2  = (const float*)d_in[11];
    const float* m2   = (const float*)d_in[12];
    const float* v2   = (const float*)d_in[13];
    const float* Wg   = (const float*)d_in[14];
    const float* a_src= (const float*)d_in[15];
    const float* a_dst= (const float*)d_in[16];
    const float* bg   = (const float*)d_in[17];
    const float* Wu1  = (const float*)d_in[18];
    const float* bu1  = (const float*)d_in[19];
    const float* Wu2  = (const float*)d_in[20];
    const float* bu2  = (const float*)d_in[21];
    const float* Wo   = (const float*)d_in[22];
    const float* bo   = (const float*)d_in[23];

    float* ws  = (float*)d_ws;
    float* xl  = ws + OFF_XL;
    float* h1  = ws + OFF_H1;
    float* h   = ws + OFF_H;
    float* sq  = ws + OFF_SQ;
    float* xp  = ws + OFF_XP;
    float* asr = ws + OFF_ASR;
    float* adt = ws + OFF_ADT;
    float* p   = ws + OFF_P;
    float* ol  = ws + OFF_OL;
    // H1 region reuse (dead after conv2): cand_i 2 MB (NSL=4), bf16 splits,
    // nsq. Total 1,867,776 of 2,097,152 floats — no footprint growth.
    uint4*  cand_i = (uint4*)(ws + OFF_H1);
    ushort* hHi    = (ushort*)(ws + OFF_H1 + 1048576);
    ushort* hMid   = (ushort*)(ws + OFF_H1 + 1310720);
    ushort* hLo    = (ushort*)(ws + OFF_H1 + 1572864);
    float*  nsq    = ws + OFF_H1 + 1835008;

    k_down  <<<(BATCH * NN + 127) / 128, 128, 0, stream>>>(x, xl);
    k_conv1 <<<(BATCH * C1 * NN) / 256, 256, 0, stream>>>(xl, W1, b1, g1, be1, m1, v1, h1);
    k_conv2 <<<BATCH * 32, 128, 0, stream>>>(h1, W2, b2, g2, be2, m2, v2, Wg, a_src, a_dst,
                                             h, sq, xp, asr, adt);
    k_split <<<BATCH * NN / 256, 256, 0, stream>>>(h, sq, hHi, hMid, hLo, nsq);
    k_scan  <<<BATCH * 32 * NSL, 256, 0, stream>>>(hHi, hMid, hLo, nsq, cand_i);
    k_gat2  <<<BATCH * NN / 256, 256, 0, stream>>>(cand_i, h, sq, xp, asr, adt, bg, p);
    k_update<<<BATCH * NN / 128, 256, 0, stream>>>(p, h, fire, Wu1, bu1, Wu2, bu2, Wo, bo, ol);
    k_up    <<<(BATCH * HIGH * HIGH) / 256, 256, 0, stream>>>(ol, (float*)d_out);
}

// Round 6
// 325.962 us; speedup vs baseline: 1.3462x; 1.0955x over previous
//
#include <hip/hip_runtime.h>
#include <math.h>
#include <float.h>

#define BATCH 8
#define HIGH  256
#define LOWR  64
#define NN    4096          // LOWR*LOWR
#define HIDC  16
#define C1    64
#define NSL   4             // j-slices in kNN scan (1024 j each)

// workspace layout (floats) — footprint identical to the validated layout
#define OFF_XL   0
#define OFF_H1   (OFF_XL  + BATCH*NN)            // 2.097M floats; reused after conv2:
                                                 //   [0 .. 524,287]           cand_i (2 MB, NSL=4)
                                                 //   [1,048,576 .. 1,835,007] bf16 hi/mid/lo splits
                                                 //   [1,835,008 .. 1,867,775] nsq (= -sq)
#define OFF_H    (OFF_H1  + BATCH*C1*NN)         // node-major [B*N][16]
#define OFF_SQ   (OFF_H   + BATCH*NN*HIDC)       // 0.5*|h|^2 per node
#define OFF_XP   (OFF_SQ  + BATCH*NN)
#define OFF_ASR  (OFF_XP  + BATCH*NN*HIDC)
#define OFF_ADT  (OFF_ASR + BATCH*NN*4)
#define OFF_P    (OFF_ADT + BATCH*NN*4)
#define OFF_OL   (OFF_P   + BATCH*NN*HIDC)

typedef __attribute__((ext_vector_type(8)))  short bf16x8;
typedef __attribute__((ext_vector_type(16))) float f32x16;

// identical-arithmetic dot used by k_gat2 (exact fp32 re-score of the pool —
// final selection semantics unchanged from the validated kernel)
__device__ __forceinline__ float dot16m(const float ni[16], float4 a0, float4 a1,
                                        float4 a2, float4 a3, float hs) {
    return ni[0]*a0.x + ni[1]*a0.y + ni[2]*a0.z + ni[3]*a0.w
         + ni[4]*a1.x + ni[5]*a1.y + ni[6]*a1.z + ni[7]*a1.w
         + ni[8]*a2.x + ni[9]*a2.y + ni[10]*a2.z + ni[11]*a2.w
         + ni[12]*a3.x + ni[13]*a3.y + ni[14]*a3.z + ni[15]*a3.w
         - hs;
}

// ---------------- bilinear downsample 256 -> 64 (antialiased triangle) -------
__global__ void k_down(const float* __restrict__ x, float* __restrict__ xl) {
    int t = blockIdx.x * 128 + threadIdx.x;
    if (t >= BATCH * NN) return;
    int b = t >> 12, oy = (t >> 6) & 63, ox = t & 63;
    const float* xb = x + b * HIGH * HIGH;
    float cy = 4.f * oy + 1.5f, cx = 4.f * ox + 1.5f;
    float wy[8], wx[8], sy = 0.f, sx = 0.f;
#pragma unroll
    for (int k = 0; k < 8; k++) {
        int iy = 4 * oy - 2 + k;
        float w = 1.f - fabsf((float)iy - cy) * 0.25f;
        if (iy < 0 || iy >= HIGH) w = 0.f;
        wy[k] = w; sy += w;
        int ix = 4 * ox - 2 + k;
        float v = 1.f - fabsf((float)ix - cx) * 0.25f;
        if (ix < 0 || ix >= HIGH) v = 0.f;
        wx[k] = v; sx += v;
    }
    float acc = 0.f;
#pragma unroll
    for (int ky = 0; ky < 8; ky++) {
        if (wy[ky] == 0.f) continue;
        int iy = 4 * oy - 2 + ky;
        float rowacc = 0.f;
#pragma unroll
        for (int kx = 0; kx < 8; kx++) {
            if (wx[kx] == 0.f) continue;
            int ix = 4 * ox - 2 + kx;
            rowacc += wx[kx] * xb[iy * HIGH + ix];
        }
        acc += wy[ky] * rowacc;
    }
    xl[t] = acc / (sy * sx);
}

// ---------------- conv3x3 1->64 + BN + relu ---------------------------------
__global__ void k_conv1(const float* __restrict__ xl, const float* __restrict__ W1,
                        const float* __restrict__ b1, const float* __restrict__ g1,
                        const float* __restrict__ be1, const float* __restrict__ m1,
                        const float* __restrict__ v1, float* __restrict__ h1) {
    int t = blockIdx.x * 256 + threadIdx.x;
    if (t >= BATCH * C1 * NN) return;
    int b = t >> 18, co = (t >> 12) & 63, y = (t >> 6) & 63, x = t & 63;
    const float* src = xl + b * NN;
    const float* w = W1 + co * 9;
    float acc = 0.f;
#pragma unroll
    for (int dy = -1; dy <= 1; dy++) {
        int yy = y + dy; if (yy < 0 || yy >= 64) continue;
#pragma unroll
        for (int dx = -1; dx <= 1; dx++) {
            int xx = x + dx; if (xx < 0 || xx >= 64) continue;
            acc += w[(dy + 1) * 3 + (dx + 1)] * src[yy * 64 + xx];
        }
    }
    acc += b1[co];
    float sc = g1[co] / sqrtf(v1[co] + 1e-5f);
    acc = (acc - m1[co]) * sc + be1[co];
    h1[t] = fmaxf(acc, 0.f);
}

// ------- conv3x3 64->16 + BN + relu, fused: h (node-major), sq, xp, asr, adt -
__launch_bounds__(128)
__global__ void k_conv2(const float* __restrict__ h1, const float* __restrict__ W2,
                        const float* __restrict__ b2, const float* __restrict__ g2,
                        const float* __restrict__ be2, const float* __restrict__ m2,
                        const float* __restrict__ v2, const float* __restrict__ Wg,
                        const float* __restrict__ a_src, const float* __restrict__ a_dst,
                        float* __restrict__ h, float* __restrict__ sq,
                        float* __restrict__ xp, float* __restrict__ asr,
                        float* __restrict__ adt) {
    __shared__ float sW2t[576 * 16];    // [ci*9+tap][o]
    __shared__ float sWg[256];
    __shared__ float sA[32];
    int tid = threadIdx.x;
    for (int k = tid; k < 9216; k += 128) {          // coalesced global read, scatter to LDS
        int o = k / 576, ct = k - o * 576;
        sW2t[ct * 16 + o] = W2[k];
    }
    for (int k = tid; k < 256; k += 128) sWg[k] = Wg[k];
    if (tid < 16) { sA[tid] = a_src[tid]; sA[16 + tid] = a_dst[tid]; }
    __syncthreads();
    int blk = blockIdx.x;                 // 8 batches * 32 y-tiles
    int b = blk >> 5, ytile = blk & 31;
    int ty = tid >> 6, x = tid & 63, y = ytile * 2 + ty;
    float acc[16];
#pragma unroll
    for (int o = 0; o < 16; o++) acc[o] = 0.f;
    const float* hb = h1 + (long)b * C1 * NN;
    for (int ci = 0; ci < 64; ci++) {
        const float* plane = hb + ci * NN;
#pragma unroll
        for (int dy = -1; dy <= 1; dy++) {
            int yy = y + dy; bool oky = (yy >= 0 && yy < 64);
#pragma unroll
            for (int dx = -1; dx <= 1; dx++) {
                int xx = x + dx;
                float v = (oky && xx >= 0 && xx < 64) ? plane[yy * 64 + xx] : 0.f;
                int ct = ci * 9 + (dy + 1) * 3 + (dx + 1);
                const float4* wr = (const float4*)&sW2t[ct * 16];
                float4 w0 = wr[0], w1 = wr[1], w2 = wr[2], w3 = wr[3];
                acc[0] += v * w0.x; acc[1] += v * w0.y; acc[2] += v * w0.z; acc[3] += v * w0.w;
                acc[4] += v * w1.x; acc[5] += v * w1.y; acc[6] += v * w1.z; acc[7] += v * w1.w;
                acc[8] += v * w2.x; acc[9] += v * w2.y; acc[10]+= v * w2.z; acc[11]+= v * w2.w;
                acc[12]+= v * w3.x; acc[13]+= v * w3.y; acc[14]+= v * w3.z; acc[15]+= v * w3.w;
            }
        }
    }
    int n = y * 64 + x;
    long node = (long)b * NN + n;
    float nodev[16], sqv = 0.f;
#pragma unroll
    for (int o = 0; o < 16; o++) {
        float a = acc[o] + b2[o];
        float sc = g2[o] / sqrtf(v2[o] + 1e-5f);
        a = (a - m2[o]) * sc + be2[o];
        a = fmaxf(a, 0.f);
        nodev[o] = a; sqv += a * a;
        h[node * 16 + o] = a;
    }
    sq[node] = 0.5f * sqv;                // pre-scaled: scan/merge use dot - 0.5|j|^2
    float xpv[16];
#pragma unroll
    for (int o = 0; o < 16; o++) {
        float a = 0.f;
#pragma unroll
        for (int c = 0; c < 16; c++) a += sWg[o * 16 + c] * nodev[c];
        xpv[o] = a;
        xp[node * 16 + o] = a;
    }
#pragma unroll
    for (int hh = 0; hh < 4; hh++) {
        float as = 0.f, ad = 0.f;
#pragma unroll
        for (int f = 0; f < 4; f++) {
            as += xpv[hh * 4 + f] * sA[hh * 4 + f];
            ad += xpv[hh * 4 + f] * sA[16 + hh * 4 + f];
        }
        asr[node * 4 + hh] = as;
        adt[node * 4 + hh] = ad;
    }
}

// ------- error-free 3-way bf16 split of h: h = hi + mid + lo + O(2^-27) -----
__device__ __forceinline__ ushort f2bf(float f) {
    unsigned u = __float_as_uint(f);
    return (ushort)((u + 0x7FFFu + ((u >> 16) & 1u)) >> 16);
}
__device__ __forceinline__ float bf2f(ushort h) {
    return __uint_as_float(((unsigned)h) << 16);
}
__global__ void k_split(const float* __restrict__ h, const float* __restrict__ sq,
                        ushort* __restrict__ hHi, ushort* __restrict__ hMid,
                        ushort* __restrict__ hLo, float* __restrict__ nsq) {
    long t = (long)blockIdx.x * 64 + threadIdx.x;    // node 0..32767
    nsq[t] = -sq[t];                                  // negated for MFMA C-init
    const float4* hp = (const float4*)&h[t * 16];
    float4 v0 = hp[0], v1 = hp[1], v2 = hp[2], v3 = hp[3];
    float v[16] = { v0.x,v0.y,v0.z,v0.w, v1.x,v1.y,v1.z,v1.w,
                    v2.x,v2.y,v2.z,v2.w, v3.x,v3.y,v3.z,v3.w };
    unsigned wh[8], wm[8], wl[8];
#pragma unroll
    for (int p = 0; p < 8; p++) {
        unsigned packh = 0, packm = 0, packl = 0;
#pragma unroll
        for (int e = 0; e < 2; e++) {
            float f = v[p * 2 + e];
            ushort hi = f2bf(f);
            float t1 = f - bf2f(hi);
            ushort mi = f2bf(t1);
            float t2 = t1 - bf2f(mi);
            ushort lo = f2bf(t2);
            packh |= ((unsigned)hi) << (16 * e);
            packm |= ((unsigned)mi) << (16 * e);
            packl |= ((unsigned)lo) << (16 * e);
        }
        wh[p] = packh; wm[p] = packm; wl[p] = packl;
    }
    uint4* dh = (uint4*)&hHi[t * 16];
    uint4* dm = (uint4*)&hMid[t * 16];
    uint4* dl = (uint4*)&hLo[t * 16];
    dh[0] = make_uint4(wh[0], wh[1], wh[2], wh[3]);
    dh[1] = make_uint4(wh[4], wh[5], wh[6], wh[7]);
    dm[0] = make_uint4(wm[0], wm[1], wm[2], wm[3]);
    dm[1] = make_uint4(wm[4], wm[5], wm[6], wm[7]);
    dl[0] = make_uint4(wl[0], wl[1], wl[2], wl[3]);
    dl[1] = make_uint4(wl[4], wl[5], wl[6], wl[7]);
}

// --- shared tile-score routine: MUST be bit-identical between pass 1/2 ------
// C-operand initialized to -0.5|h_j|^2 (nsq), so scv = acc directly. MFMA
// chain dependency-ordered => deterministic recompute in pass 2.
__device__ __forceinline__ void tile_scores(const ushort* __restrict__ hHi,
        const ushort* __restrict__ hMid, const ushort* __restrict__ hLo,
        const float* __restrict__ nsq, long bN, int j0, int ln31, int koff,
        int rbase, int i0w, bf16x8 bi_h, bf16x8 bi_m, bf16x8 bi_l,
        float scv[16]) {
    int jr = j0 + ln31;
    bf16x8 aj_h = *(const bf16x8*)&hHi [(bN + jr) * 16 + koff];
    bf16x8 aj_m = *(const bf16x8*)&hMid[(bN + jr) * 16 + koff];
    bf16x8 aj_l = *(const bf16x8*)&hLo [(bN + jr) * 16 + koff];
    float4 q0 = *(const float4*)&nsq[bN + j0 +  0 + rbase];
    float4 q1 = *(const float4*)&nsq[bN + j0 +  8 + rbase];
    float4 q2 = *(const float4*)&nsq[bN + j0 + 16 + rbase];
    float4 q3 = *(const float4*)&nsq[bN + j0 + 24 + rbase];
    f32x16 acc;
    acc[0]  = q0.x; acc[1]  = q0.y; acc[2]  = q0.z; acc[3]  = q0.w;
    acc[4]  = q1.x; acc[5]  = q1.y; acc[6]  = q1.z; acc[7]  = q1.w;
    acc[8]  = q2.x; acc[9]  = q2.y; acc[10] = q2.z; acc[11] = q2.w;
    acc[12] = q3.x; acc[13] = q3.y; acc[14] = q3.z; acc[15] = q3.w;
    acc = __builtin_amdgcn_mfma_f32_32x32x16_bf16(aj_h, bi_h, acc, 0, 0, 0);
    acc = __builtin_amdgcn_mfma_f32_32x32x16_bf16(aj_h, bi_m, acc, 0, 0, 0);
    acc = __builtin_amdgcn_mfma_f32_32x32x16_bf16(aj_m, bi_h, acc, 0, 0, 0);
    acc = __builtin_amdgcn_mfma_f32_32x32x16_bf16(aj_h, bi_l, acc, 0, 0, 0);
    acc = __builtin_amdgcn_mfma_f32_32x32x16_bf16(aj_l, bi_h, acc, 0, 0, 0);
    acc = __builtin_amdgcn_mfma_f32_32x32x16_bf16(aj_m, bi_m, acc, 0, 0, 0);
#pragma unroll
    for (int rr = 0; rr < 16; rr++) scv[rr] = acc[rr];
    if (j0 == i0w) {                       // wave-uniform: diagonal tile, mask self
#pragma unroll
        for (int rr = 0; rr < 16; rr++) {
            int r = (rr & 3) + 8 * (rr >> 2) + rbase;
            if (r == ln31) scv[rr] = -FLT_MAX;
        }
    }
}

// --- sorting-network primitives (compare-exchange = max/min pair: exact
// multiset preservation, fully unrolled constant indexing) ------------------
#define CEX(a, b) { float ce_hi = fmaxf(a, b), ce_lo = fminf(a, b); (a) = ce_hi; (b) = ce_lo; }
// Batcher odd-even mergesort, 8 values descending (19 CE)
__device__ __forceinline__ void sort8d(float v[8]) {
    CEX(v[0],v[1]); CEX(v[2],v[3]); CEX(v[4],v[5]); CEX(v[6],v[7]);
    CEX(v[0],v[2]); CEX(v[1],v[3]); CEX(v[4],v[6]); CEX(v[5],v[7]);
    CEX(v[1],v[2]); CEX(v[5],v[6]);
    CEX(v[0],v[4]); CEX(v[1],v[5]); CEX(v[2],v[6]); CEX(v[3],v[7]);
    CEX(v[2],v[4]); CEX(v[3],v[5]);
    CEX(v[1],v[2]); CEX(v[3],v[4]); CEX(v[5],v[6]);
}
// bitonic 8-sequence -> sorted descending (12 CE)
__device__ __forceinline__ void bsort8d(float v[8]) {
    CEX(v[0],v[4]); CEX(v[1],v[5]); CEX(v[2],v[6]); CEX(v[3],v[7]);
    CEX(v[0],v[2]); CEX(v[1],v[3]); CEX(v[4],v[6]); CEX(v[5],v[7]);
    CEX(v[0],v[1]); CEX(v[2],v[3]); CEX(v[4],v[5]); CEX(v[6],v[7]);
}

// --------- kNN scan, two-pass scores-only selection --------------------------
// Pass 1: per tile, sorting-network top-8: sort8d on each half of the 16
//         scores, max(a[k],b[7-k]) bitonic merge -> top-8-of-16, bsort8d,
//         same merge against running s[8] (140 VALU/tile vs 256 bubble).
//         All CE ops preserve the score multiset exactly => theta = exact
//         8th-best of the (column, slice) after the lane^32 pair-merge.
// Pass 2: recompute scores bit-identically; gt/eq bitmasks + ffs-loop pushes
//         ids to LDS (single predicated ds_write per event). Assembly emits
//         the exact reference top-8 SET per slice (order irrelevant: k_gat2
//         re-scores the pool in exact fp32 with the reference tie-break).
__global__ __attribute__((amdgpu_waves_per_eu(4, 4))) __launch_bounds__(256)
void k_scan(const ushort* __restrict__ hHi, const ushort* __restrict__ hMid,
            const ushort* __restrict__ hLo, const float* __restrict__ nsq,
            uint4* __restrict__ cand_i) {
    __shared__ unsigned lists[256][17];  // [tid][0..7]=A ids, [8..15]=B ids, [16]=trash
    __shared__ ushort outl[256][8];
    int tid = threadIdx.x, blk = blockIdx.x;
    int b  = blk >> 7;                   // 128 blocks per batch (32 ig x 4 sl)
    int ig = (blk >> 2) & 31;
    int sl = blk & 3;
    int wid = tid >> 6, lane = tid & 63;
    int ln31 = lane & 31, l5 = lane >> 5;
    int koff = l5 * 8;
    int i0w = ig * 128 + wid * 32;       // this wave's 32-aligned i-tile base
    int i   = i0w + ln31;
    long bN = (long)b * NN;
    int rbase = l5 * 4;
    int jbase = sl * 1024;

    bf16x8 bi_h = *(const bf16x8*)&hHi [(bN + i) * 16 + koff];
    bf16x8 bi_m = *(const bf16x8*)&hMid[(bN + i) * 16 + koff];
    bf16x8 bi_l = *(const bf16x8*)&hLo [(bN + i) * 16 + koff];

    // ---- pass 1: top-8 scores only (sorted descending invariant) ----
    float s[8];
#pragma unroll
    for (int k = 0; k < 8; k++) s[k] = -FLT_MAX;
    for (int t = 0; t < 32; t++) {
        int j0 = jbase + t * 32;
        float scv[16];
        tile_scores(hHi, hMid, hLo, nsq, bN, j0, ln31, koff, rbase, i0w,
                    bi_h, bi_m, bi_l, scv);
        float va[8] = { scv[0], scv[1], scv[2], scv[3], scv[4], scv[5], scv[6], scv[7] };
        float vb[8] = { scv[8], scv[9], scv[10], scv[11], scv[12], scv[13], scv[14], scv[15] };
        sort8d(va); sort8d(vb);
        float mg[8];
#pragma unroll
        for (int k = 0; k < 8; k++) mg[k] = fmaxf(va[k], vb[7 - k]);  // top-8 of 16, bitonic
        bsort8d(mg);
#pragma unroll
        for (int k = 0; k < 8; k++) s[k] = fmaxf(s[k], mg[7 - k]);    // top-8 of (s ∪ mg), bitonic
        bsort8d(s);
    }
    // pair-merge: top-8 of union(lane, lane^32) as a multiset; theta = its min.
    float mv[8];
#pragma unroll
    for (int k = 0; k < 8; k++) mv[k] = fmaxf(s[k], __shfl_xor(s[7 - k], 32));
    float theta = mv[0];
#pragma unroll
    for (int k = 1; k < 8; k++) theta = fminf(theta, mv[k]);

    // ---- pass 2: id recovery via bitmask + ffs ----
    unsigned* ldsw = &lists[0][0];
    int baseA = tid * 17, baseB = baseA + 8, trash = baseA + 16;
    int nA = 0, nB = 0;
    for (int t = 0; t < 32; t++) {
        int j0 = jbase + t * 32;
        float scv[16];
        tile_scores(hHi, hMid, hLo, nsq, bN, j0, ln31, koff, rbase, i0w,
                    bi_h, bi_m, bi_l, scv);
        unsigned gm = 0, em = 0;
#pragma unroll
        for (int rr = 0; rr < 16; rr++) {
            gm |= (scv[rr] >  theta) ? (1u << rr) : 0u;
            em |= (scv[rr] == theta) ? (1u << rr) : 0u;
        }
        unsigned m = gm | em;
        while (__any(m != 0u)) {
            if (m) {
                int rr = __ffs(m) - 1;
                m &= m - 1u;
                int r = (rr & 3) + ((rr >> 2) << 3) + rbase;
                int j = j0 + r;
                bool isGt = (gm >> rr) & 1u;
                bool cA = isGt && (nA < 8);   // <=7 by math; insurance
                bool cB = (!isGt) && (nB < 8);
                int ia = cA ? (baseA + nA) : (cB ? (baseB + nB) : trash);
                ldsw[ia] = (unsigned)j;       // single predicated write
                nA += cA;
                nB += cB;
            }
        }
    }
    int pA = __shfl_xor(nA, 32);
    int pB = __shfl_xor(nB, 32);
    __syncthreads();
    // ---- assembly (per column, lane<32): A ids + smallest-j ties to fill 8 ----
    if (lane < 32) {
        int tp = tid + 32;
        int n = 0;
        for (int k = 0; k < nA && n < 8; k++) outl[tid][n++] = (ushort)lists[tid][k];
        for (int k = 0; k < pA && n < 8; k++) outl[tid][n++] = (ushort)lists[tp][k];
        int p0 = 0, p1 = 0;
        while (n < 8) {                  // two-pointer merge of j-ascending tie lists
            unsigned a = (p0 < nB) ? lists[tid][8 + p0] : 0xFFFFFFFFu;
            unsigned c = (p1 < pB) ? lists[tp][8 + p1] : 0xFFFFFFFFu;
            bool t0 = a < c;
            outl[tid][n++] = (ushort)(t0 ? a : c);
            p0 += t0 ? 1 : 0; p1 += t0 ? 0 : 1;
        }
        uint4 pk = *(const uint4*)&outl[tid][0];
        cand_i[(long)(b * NSL + sl) * NN + i] = pk;
    }
}

// --- merge 4 slice-lists (recompute scores in exact fp32) + GAT -> p --------
// 64-thread blocks, 512-block grid: full 256-CU coverage (was 128 blocks =
// half the GPU idle). No intra-block communication — block-size independent.
__launch_bounds__(64)
__global__ void k_gat2(const uint4* __restrict__ cand_i, const float* __restrict__ h,
                       const float* __restrict__ sq,
                       const float* __restrict__ xp, const float* __restrict__ asr,
                       const float* __restrict__ adt, const float* __restrict__ bg,
                       float* __restrict__ p) {
    int t = blockIdx.x * 64 + threadIdx.x;        // 0..32767
    int b = t >> 12, i = t & 4095;
    long bN = (long)b * NN;
    const float4* ip = (const float4*)&h[(bN + i) * 16];
    float4 r0 = ip[0], r1 = ip[1], r2 = ip[2], r3 = ip[3];
    float ni[16] = { r0.x,r0.y,r0.z,r0.w, r1.x,r1.y,r1.z,r1.w,
                     r2.x,r2.y,r2.z,r2.w, r3.x,r3.y,r3.z,r3.w };
    float fS[8]; int fI[8];
#pragma unroll
    for (int k = 0; k < 8; k++) { fS[k] = -FLT_MAX; fI[k] = 65535; }
    for (int sl = 0; sl < NSL; sl++) {
        uint4 pk = cand_i[(long)(b * NSL + sl) * NN + i];
        unsigned idx8[8] = { pk.x & 0xFFFF, pk.x >> 16, pk.y & 0xFFFF, pk.y >> 16,
                             pk.z & 0xFFFF, pk.z >> 16, pk.w & 0xFFFF, pk.w >> 16 };
#pragma unroll
        for (int k = 0; k < 8; k++) {
            int j = (int)idx8[k];
            const float4* np = (const float4*)&h[(bN + j) * 16];
            float4 a0 = np[0], a1 = np[1], a2 = np[2], a3 = np[3];
            float d = dot16m(ni, a0, a1, a2, a3, sq[bN + j]);
            bool bt = (d > fS[7]) || (d == fS[7] && j < fI[7]);
            if (bt) {
                fS[7] = d; fI[7] = j;
#pragma unroll
                for (int q = 7; q > 0; q--) {
                    bool sw = (fS[q] > fS[q - 1]) || (fS[q] == fS[q - 1] && fI[q] < fI[q - 1]);
                    if (sw) {
                        float td = fS[q]; fS[q] = fS[q - 1]; fS[q - 1] = td;
                        int tj = fI[q]; fI[q] = fI[q - 1]; fI[q - 1] = tj;
                    }
                }
            }
        }
    }
    int nbrs[9];
#pragma unroll
    for (int e = 0; e < 8; e++) nbrs[e] = fI[e];
    nbrs[8] = i;                                   // self-loop
    float adtv[4];
#pragma unroll
    for (int hh = 0; hh < 4; hh++) adtv[hh] = adt[(bN + i) * 4 + hh];
    float mx[4] = { -FLT_MAX, -FLT_MAX, -FLT_MAX, -FLT_MAX };
    float lg[9][4];
#pragma unroll
    for (int e = 0; e < 9; e++) {
        long nb = bN + nbrs[e];
#pragma unroll
        for (int hh = 0; hh < 4; hh++) {
            float l = asr[nb * 4 + hh] + adtv[hh];
            l = (l > 0.f) ? l : 0.2f * l;          // leaky_relu 0.2
            lg[e][hh] = l;
            mx[hh] = fmaxf(mx[hh], l);
        }
    }
    float sum[4] = { 0, 0, 0, 0 };
    float acc[16];
#pragma unroll
    for (int c = 0; c < 16; c++) acc[c] = 0.f;
#pragma unroll
    for (int e = 0; e < 9; e++) {
        long nb = bN + nbrs[e];
        const float4* xpn = (const float4*)&xp[nb * 16];
        float4 x0 = xpn[0], x1 = xpn[1], x2 = xpn[2], x3 = xpn[3];
        float xv[16] = { x0.x,x0.y,x0.z,x0.w, x1.x,x1.y,x1.z,x1.w,
                         x2.x,x2.y,x2.z,x2.w, x3.x,x3.y,x3.z,x3.w };
        float wv[4];
#pragma unroll
        for (int hh = 0; hh < 4; hh++) {
            float w = expf(lg[e][hh] - mx[hh]);
            sum[hh] += w; wv[hh] = w;
        }
#pragma unroll
        for (int hh = 0; hh < 4; hh++)
#pragma unroll
            for (int f = 0; f < 4; f++)
                acc[hh * 4 + f] += wv[hh] * xv[hh * 4 + f];
    }
#pragma unroll
    for (int hh = 0; hh < 4; hh++) {
        float inv = 1.f / sum[hh];
#pragma unroll
        for (int f = 0; f < 4; f++) {
            float o = acc[hh * 4 + f] * inv + bg[hh * 4 + f];
            p[(bN + i) * 16 + hh * 4 + f] = fmaxf(o, 0.f);
        }
    }
}

// ------- 1x1 MLP 16->128->16, fire mask, h += mask*u, 1x1->1 + sigmoid ------
#define USTR 20
__launch_bounds__(256)
__global__ void k_update(const float* __restrict__ p, const float* __restrict__ h,
                         const float* __restrict__ fire, const float* __restrict__ Wu1,
                         const float* __restrict__ bu1, const float* __restrict__ Wu2,
                         const float* __restrict__ bu2, const float* __restrict__ Wo,
                         const float* __restrict__ bo, float* __restrict__ out_low) {
    __shared__ float sU1[128 * 16];
    __shared__ float sU2t[128 * 16];      // [hd][c] = Wu2[c][hd]
    __shared__ float sb1[128];
    __shared__ float uhalf[128 * USTR];
    int tid = threadIdx.x;
    for (int k = tid; k < 2048; k += 256) {
        sU1[k] = Wu1[k];
        sU2t[(k & 127) * 16 + (k >> 7)] = Wu2[k];   // coalesced read, scatter to LDS
    }
    if (tid < 128) sb1[tid] = bu1[tid];
    __syncthreads();
    int lnode = tid & 127, half = tid >> 7;
    long n = (long)blockIdx.x * 128 + lnode;         // 0..32767
    const float4* pp = (const float4*)&p[n * 16];
    float4 p0 = pp[0], p1 = pp[1], p2 = pp[2], p3 = pp[3];
    float pv[16] = { p0.x,p0.y,p0.z,p0.w, p1.x,p1.y,p1.z,p1.w,
                     p2.x,p2.y,p2.z,p2.w, p3.x,p3.y,p3.z,p3.w };
    float u[16];
#pragma unroll
    for (int c = 0; c < 16; c++) u[c] = 0.f;
    int hd0 = half * 64;
    for (int hd = hd0; hd < hd0 + 64; hd++) {
        const float4* r = (const float4*)&sU1[hd * 16];
        float4 r0 = r[0], r1 = r[1], r2 = r[2], r3 = r[3];
        float a = sb1[hd]
            + r0.x*pv[0] + r0.y*pv[1] + r0.z*pv[2] + r0.w*pv[3]
            + r1.x*pv[4] + r1.y*pv[5] + r1.z*pv[6] + r1.w*pv[7]
            + r2.x*pv[8] + r2.y*pv[9] + r2.z*pv[10]+ r2.w*pv[11]
            + r3.x*pv[12]+ r3.y*pv[13]+ r3.z*pv[14]+ r3.w*pv[15];
        a = fmaxf(a, 0.f);
        const float4* tt = (const float4*)&sU2t[hd * 16];
        float4 t0 = tt[0], t1 = tt[1], t2 = tt[2], t3 = tt[3];
        u[0] += t0.x*a; u[1] += t0.y*a; u[2] += t0.z*a; u[3] += t0.w*a;
        u[4] += t1.x*a; u[5] += t1.y*a; u[6] += t1.z*a; u[7] += t1.w*a;
        u[8] += t2.x*a; u[9] += t2.y*a; u[10]+= t2.z*a; u[11]+= t2.w*a;
        u[12]+= t3.x*a; u[13]+= t3.y*a; u[14]+= t3.z*a; u[15]+= t3.w*a;
    }
    if (half == 1) {
        float4* dst = (float4*)&uhalf[lnode * USTR];
        dst[0] = make_float4(u[0], u[1], u[2], u[3]);
        dst[1] = make_float4(u[4], u[5], u[6], u[7]);
        dst[2] = make_float4(u[8], u[9], u[10], u[11]);
        dst[3] = make_float4(u[12], u[13], u[14], u[15]);
    }
    __syncthreads();
    if (half == 0) {
        const float4* src = (const float4*)&uhalf[lnode * USTR];
        float4 o0 = src[0], o1 = src[1], o2 = src[2], o3 = src[3];
        float ou[16] = { o0.x,o0.y,o0.z,o0.w, o1.x,o1.y,o1.z,o1.w,
                         o2.x,o2.y,o2.z,o2.w, o3.x,o3.y,o3.z,o3.w };
        float mask = (fire[n] < 0.5f) ? 1.f : 0.f;
        const float4* hp = (const float4*)&h[n * 16];
        float4 h0 = hp[0], h1v = hp[1], h2 = hp[2], h3 = hp[3];
        float hv[16] = { h0.x,h0.y,h0.z,h0.w, h1v.x,h1v.y,h1v.z,h1v.w,
                         h2.x,h2.y,h2.z,h2.w, h3.x,h3.y,h3.z,h3.w };
        float o = bo[0];
#pragma unroll
        for (int c = 0; c < 16; c++)
            o += Wo[c] * (hv[c] + mask * (u[c] + ou[c] + bu2[c]));
        out_low[n] = 1.f / (1.f + expf(-o));
    }
}

// ---------------- bilinear upsample 64 -> 256 (half-pixel, clamp) -----------
__global__ void k_up(const float* __restrict__ ol, float* __restrict__ out) {
    int t = blockIdx.x * 256 + threadIdx.x;
    if (t >= BATCH * HIGH * HIGH) return;
    int b = t >> 16, oy = (t >> 8) & 255, ox = t & 255;
    float cy = (oy + 0.5f) * 0.25f - 0.5f;
    float cx = (ox + 0.5f) * 0.25f - 0.5f;
    int iy0 = (int)floorf(cy); float fy = cy - (float)iy0;
    int ix0 = (int)floorf(cx); float fx = cx - (float)ix0;
    int y0 = min(max(iy0, 0), 63), y1 = min(max(iy0 + 1, 0), 63);
    int x0 = min(max(ix0, 0), 63), x1 = min(max(ix0 + 1, 0), 63);
    const float* s = ol + b * NN;
    float v = (1.f - fy) * ((1.f - fx) * s[y0 * 64 + x0] + fx * s[y0 * 64 + x1])
            + fy * ((1.f - fx) * s[y1 * 64 + x0] + fx * s[y1 * 64 + x1]);
    out[t] = v;
}

extern "C" void kernel_launch(void* const* d_in, const int* in_sizes, int n_in,
                              void* d_out, int out_size, void* d_ws, size_t ws_size,
                              hipStream_t stream) {
    const float* x    = (const float*)d_in[0];
    const float* fire = (const float*)d_in[1];
    const float* W1   = (const float*)d_in[2];
    const float* b1   = (const float*)d_in[3];
    const float* g1   = (const float*)d_in[4];
    const float* be1  = (const float*)d_in[5];
    const float* m1   = (const float*)d_in[6];
    const float* v1   = (const float*)d_in[7];
    const float* W2   = (const float*)d_in[8];
    const float* b2   = (const float*)d_in[9];
    const float* g2   = (const float*)d_in[10];
    const float* be2  = (const float*)d_in[11];
    const float* m2   = (const float*)d_in[12];
    const float* v2   = (const float*)d_in[13];
    const float* Wg   = (const float*)d_in[14];
    const float* a_src= (const float*)d_in[15];
    const float* a_dst= (const float*)d_in[16];
    const float* bg   = (const float*)d_in[17];
    const float* Wu1  = (const float*)d_in[18];
    const float* bu1  = (const float*)d_in[19];
    const float* Wu2  = (const float*)d_in[20];
    const float* bu2  = (const float*)d_in[21];
    const float* Wo   = (const float*)d_in[22];
    const float* bo   = (const float*)d_in[23];

    float* ws  = (float*)d_ws;
    float* xl  = ws + OFF_XL;
    float* h1  = ws + OFF_H1;
    float* h   = ws + OFF_H;
    float* sq  = ws + OFF_SQ;
    float* xp  = ws + OFF_XP;
    float* asr = ws + OFF_ASR;
    float* adt = ws + OFF_ADT;
    float* p   = ws + OFF_P;
    float* ol  = ws + OFF_OL;
    // H1 region reuse (dead after conv2): cand_i 2 MB (NSL=4), bf16 splits,
    // nsq. Total 1,867,776 of 2,097,152 floats — no footprint growth.
    uint4*  cand_i = (uint4*)(ws + OFF_H1);
    ushort* hHi    = (ushort*)(ws + OFF_H1 + 1048576);
    ushort* hMid   = (ushort*)(ws + OFF_H1 + 1310720);
    ushort* hLo    = (ushort*)(ws + OFF_H1 + 1572864);
    float*  nsq    = ws + OFF_H1 + 1835008;

    k_down  <<<(BATCH * NN + 127) / 128, 128, 0, stream>>>(x, xl);
    k_conv1 <<<(BATCH * C1 * NN) / 256, 256, 0, stream>>>(xl, W1, b1, g1, be1, m1, v1, h1);
    k_conv2 <<<BATCH * 32, 128, 0, stream>>>(h1, W2, b2, g2, be2, m2, v2, Wg, a_src, a_dst,
                                             h, sq, xp, asr, adt);
    k_split <<<BATCH * NN / 64, 64, 0, stream>>>(h, sq, hHi, hMid, hLo, nsq);
    k_scan  <<<BATCH * 32 * NSL, 256, 0, stream>>>(hHi, hMid, hLo, nsq, cand_i);
    k_gat2  <<<BATCH * NN / 64, 64, 0, stream>>>(cand_i, h, sq, xp, asr, adt, bg, p);
    k_update<<<BATCH * NN / 128, 256, 0, stream>>>(p, h, fire, Wu1, bu1, Wu2, bu2, Wo, bo, ol);
    k_up    <<<(BATCH * HIGH * HIGH) / 256, 256, 0, stream>>>(ol, (float*)d_out);
}

// Round 7
// 299.955 us; speedup vs baseline: 1.4629x; 1.0867x over previous
//
#include <hip/hip_runtime.h>
#include <math.h>
#include <float.h>

#define BATCH 8
#define HIGH  256
#define LOWR  64
#define NN    4096          // LOWR*LOWR
#define HIDC  16
#define C1    64
#define NSL   4             // j-slices in kNN scan (1024 j each)

// workspace layout (floats) — footprint identical to the validated layout
#define OFF_XL   0
#define OFF_H1   (OFF_XL  + BATCH*NN)            // 2.097M floats; reused after conv2:
                                                 //   [0 .. 524,287]           cand_i (2 MB, NSL=4)
                                                 //   [1,048,576 .. 1,835,007] bf16 hi/mid/lo splits
                                                 //   [1,835,008 .. 1,867,775] nsq (= -sq)
#define OFF_H    (OFF_H1  + BATCH*C1*NN)         // node-major [B*N][16]
#define OFF_SQ   (OFF_H   + BATCH*NN*HIDC)       // 0.5*|h|^2 per node
#define OFF_XP   (OFF_SQ  + BATCH*NN)
#define OFF_ASR  (OFF_XP  + BATCH*NN*HIDC)
#define OFF_ADT  (OFF_ASR + BATCH*NN*4)
#define OFF_P    (OFF_ADT + BATCH*NN*4)
#define OFF_OL   (OFF_P   + BATCH*NN*HIDC)

typedef __attribute__((ext_vector_type(8)))  short bf16x8;
typedef __attribute__((ext_vector_type(16))) float f32x16;

// identical-arithmetic dot used by k_gat2 (exact fp32 re-score of the pool —
// final selection semantics unchanged from the validated kernel)
__device__ __forceinline__ float dot16m(const float ni[16], float4 a0, float4 a1,
                                        float4 a2, float4 a3, float hs) {
    return ni[0]*a0.x + ni[1]*a0.y + ni[2]*a0.z + ni[3]*a0.w
         + ni[4]*a1.x + ni[5]*a1.y + ni[6]*a1.z + ni[7]*a1.w
         + ni[8]*a2.x + ni[9]*a2.y + ni[10]*a2.z + ni[11]*a2.w
         + ni[12]*a3.x + ni[13]*a3.y + ni[14]*a3.z + ni[15]*a3.w
         - hs;
}

// ---------------- bilinear downsample 256 -> 64 (antialiased triangle) -------
__global__ void k_down(const float* __restrict__ x, float* __restrict__ xl) {
    int t = blockIdx.x * 128 + threadIdx.x;
    if (t >= BATCH * NN) return;
    int b = t >> 12, oy = (t >> 6) & 63, ox = t & 63;
    const float* xb = x + b * HIGH * HIGH;
    float cy = 4.f * oy + 1.5f, cx = 4.f * ox + 1.5f;
    float wy[8], wx[8], sy = 0.f, sx = 0.f;
#pragma unroll
    for (int k = 0; k < 8; k++) {
        int iy = 4 * oy - 2 + k;
        float w = 1.f - fabsf((float)iy - cy) * 0.25f;
        if (iy < 0 || iy >= HIGH) w = 0.f;
        wy[k] = w; sy += w;
        int ix = 4 * ox - 2 + k;
        float v = 1.f - fabsf((float)ix - cx) * 0.25f;
        if (ix < 0 || ix >= HIGH) v = 0.f;
        wx[k] = v; sx += v;
    }
    float acc = 0.f;
#pragma unroll
    for (int ky = 0; ky < 8; ky++) {
        if (wy[ky] == 0.f) continue;
        int iy = 4 * oy - 2 + ky;
        float rowacc = 0.f;
#pragma unroll
        for (int kx = 0; kx < 8; kx++) {
            if (wx[kx] == 0.f) continue;
            int ix = 4 * ox - 2 + kx;
            rowacc += wx[kx] * xb[iy * HIGH + ix];
        }
        acc += wy[ky] * rowacc;
    }
    xl[t] = acc / (sy * sx);
}

// ---------------- conv3x3 1->64 + BN + relu ---------------------------------
__global__ void k_conv1(const float* __restrict__ xl, const float* __restrict__ W1,
                        const float* __restrict__ b1, const float* __restrict__ g1,
                        const float* __restrict__ be1, const float* __restrict__ m1,
                        const float* __restrict__ v1, float* __restrict__ h1) {
    int t = blockIdx.x * 256 + threadIdx.x;
    if (t >= BATCH * C1 * NN) return;
    int b = t >> 18, co = (t >> 12) & 63, y = (t >> 6) & 63, x = t & 63;
    const float* src = xl + b * NN;
    const float* w = W1 + co * 9;
    float acc = 0.f;
#pragma unroll
    for (int dy = -1; dy <= 1; dy++) {
        int yy = y + dy; if (yy < 0 || yy >= 64) continue;
#pragma unroll
        for (int dx = -1; dx <= 1; dx++) {
            int xx = x + dx; if (xx < 0 || xx >= 64) continue;
            acc += w[(dy + 1) * 3 + (dx + 1)] * src[yy * 64 + xx];
        }
    }
    acc += b1[co];
    float sc = g1[co] / sqrtf(v1[co] + 1e-5f);
    acc = (acc - m1[co]) * sc + be1[co];
    h1[t] = fmaxf(acc, 0.f);
}

// ------- conv3x3 64->16 + BN + relu, fused: h (node-major), sq, xp, asr, adt -
// R7: 512 threads, 4-way ci-split (16 ci per thread) -> 8 waves/CU on all 4
// SIMDs (was 2 waves/CU, half the SIMDs idle). Quarters 1-3 write partials to
// LDS (17-pad rows, b32), quarter 0 reduces + runs the unchanged epilogue.
__launch_bounds__(512)
__global__ void k_conv2(const float* __restrict__ h1, const float* __restrict__ W2,
                        const float* __restrict__ b2, const float* __restrict__ g2,
                        const float* __restrict__ be2, const float* __restrict__ m2,
                        const float* __restrict__ v2, const float* __restrict__ Wg,
                        const float* __restrict__ a_src, const float* __restrict__ a_dst,
                        float* __restrict__ h, float* __restrict__ sq,
                        float* __restrict__ xp, float* __restrict__ asr,
                        float* __restrict__ adt) {
    __shared__ float sW2t[576 * 16];    // [ci*9+tap][o]
    __shared__ float sWg[256];
    __shared__ float sA[32];
    __shared__ float accH[3][128][17];  // partials from quarters 1..3 (17-pad)
    int tid = threadIdx.x;
    for (int k = tid; k < 9216; k += 512) {          // coalesced global read, scatter to LDS
        int o = k / 576, ct = k - o * 576;
        sW2t[ct * 16 + o] = W2[k];
    }
    if (tid < 256) sWg[tid] = Wg[tid];
    if (tid < 16) { sA[tid] = a_src[tid]; sA[16 + tid] = a_dst[tid]; }
    __syncthreads();
    int blk = blockIdx.x;                 // 8 batches * 32 y-tiles
    int b = blk >> 5, ytile = blk & 31;
    int q = tid >> 7;                     // ci quarter 0..3
    int sub = tid & 127;
    int ty = sub >> 6, x = sub & 63, y = ytile * 2 + ty;
    float acc[16];
#pragma unroll
    for (int o = 0; o < 16; o++) acc[o] = 0.f;
    const float* hb = h1 + (long)b * C1 * NN + (long)q * 16 * NN;
    for (int ci = 0; ci < 16; ci++) {
        const float* plane = hb + ci * NN;
#pragma unroll
        for (int dy = -1; dy <= 1; dy++) {
            int yy = y + dy; bool oky = (yy >= 0 && yy < 64);
#pragma unroll
            for (int dx = -1; dx <= 1; dx++) {
                int xx = x + dx;
                float v = (oky && xx >= 0 && xx < 64) ? plane[yy * 64 + xx] : 0.f;
                int ct = (q * 16 + ci) * 9 + (dy + 1) * 3 + (dx + 1);
                const float4* wr = (const float4*)&sW2t[ct * 16];
                float4 w0 = wr[0], w1 = wr[1], w2 = wr[2], w3 = wr[3];
                acc[0] += v * w0.x; acc[1] += v * w0.y; acc[2] += v * w0.z; acc[3] += v * w0.w;
                acc[4] += v * w1.x; acc[5] += v * w1.y; acc[6] += v * w1.z; acc[7] += v * w1.w;
                acc[8] += v * w2.x; acc[9] += v * w2.y; acc[10]+= v * w2.z; acc[11]+= v * w2.w;
                acc[12]+= v * w3.x; acc[13]+= v * w3.y; acc[14]+= v * w3.z; acc[15]+= v * w3.w;
            }
        }
    }
    if (q != 0) {
        float* dst = &accH[q - 1][sub][0];
#pragma unroll
        for (int o = 0; o < 16; o++) dst[o] = acc[o];
    }
    __syncthreads();
    if (q != 0) return;
#pragma unroll
    for (int qq = 0; qq < 3; qq++) {
        const float* src = &accH[qq][sub][0];
#pragma unroll
        for (int o = 0; o < 16; o++) acc[o] += src[o];
    }
    int n = y * 64 + x;
    long node = (long)b * NN + n;
    float nodev[16], sqv = 0.f;
#pragma unroll
    for (int o = 0; o < 16; o++) {
        float a = acc[o] + b2[o];
        float sc = g2[o] / sqrtf(v2[o] + 1e-5f);
        a = (a - m2[o]) * sc + be2[o];
        a = fmaxf(a, 0.f);
        nodev[o] = a; sqv += a * a;
        h[node * 16 + o] = a;
    }
    sq[node] = 0.5f * sqv;                // pre-scaled: scan/merge use dot - 0.5|j|^2
    float xpv[16];
#pragma unroll
    for (int o = 0; o < 16; o++) {
        float a = 0.f;
#pragma unroll
        for (int c = 0; c < 16; c++) a += sWg[o * 16 + c] * nodev[c];
        xpv[o] = a;
        xp[node * 16 + o] = a;
    }
#pragma unroll
    for (int hh = 0; hh < 4; hh++) {
        float as = 0.f, ad = 0.f;
#pragma unroll
        for (int f = 0; f < 4; f++) {
            as += xpv[hh * 4 + f] * sA[hh * 4 + f];
            ad += xpv[hh * 4 + f] * sA[16 + hh * 4 + f];
        }
        asr[node * 4 + hh] = as;
        adt[node * 4 + hh] = ad;
    }
}

// ------- error-free 3-way bf16 split of h: h = hi + mid + lo + O(2^-27) -----
__device__ __forceinline__ ushort f2bf(float f) {
    unsigned u = __float_as_uint(f);
    return (ushort)((u + 0x7FFFu + ((u >> 16) & 1u)) >> 16);
}
__device__ __forceinline__ float bf2f(ushort h) {
    return __uint_as_float(((unsigned)h) << 16);
}
__global__ void k_split(const float* __restrict__ h, const float* __restrict__ sq,
                        ushort* __restrict__ hHi, ushort* __restrict__ hMid,
                        ushort* __restrict__ hLo, float* __restrict__ nsq) {
    long t = (long)blockIdx.x * 64 + threadIdx.x;    // node 0..32767
    nsq[t] = -sq[t];                                  // negated for MFMA C-init
    const float4* hp = (const float4*)&h[t * 16];
    float4 v0 = hp[0], v1 = hp[1], v2 = hp[2], v3 = hp[3];
    float v[16] = { v0.x,v0.y,v0.z,v0.w, v1.x,v1.y,v1.z,v1.w,
                    v2.x,v2.y,v2.z,v2.w, v3.x,v3.y,v3.z,v3.w };
    unsigned wh[8], wm[8], wl[8];
#pragma unroll
    for (int p = 0; p < 8; p++) {
        unsigned packh = 0, packm = 0, packl = 0;
#pragma unroll
        for (int e = 0; e < 2; e++) {
            float f = v[p * 2 + e];
            ushort hi = f2bf(f);
            float t1 = f - bf2f(hi);
            ushort mi = f2bf(t1);
            float t2 = t1 - bf2f(mi);
            ushort lo = f2bf(t2);
            packh |= ((unsigned)hi) << (16 * e);
            packm |= ((unsigned)mi) << (16 * e);
            packl |= ((unsigned)lo) << (16 * e);
        }
        wh[p] = packh; wm[p] = packm; wl[p] = packl;
    }
    uint4* dh = (uint4*)&hHi[t * 16];
    uint4* dm = (uint4*)&hMid[t * 16];
    uint4* dl = (uint4*)&hLo[t * 16];
    dh[0] = make_uint4(wh[0], wh[1], wh[2], wh[3]);
    dh[1] = make_uint4(wh[4], wh[5], wh[6], wh[7]);
    dm[0] = make_uint4(wm[0], wm[1], wm[2], wm[3]);
    dm[1] = make_uint4(wm[4], wm[5], wm[6], wm[7]);
    dl[0] = make_uint4(wl[0], wl[1], wl[2], wl[3]);
    dl[1] = make_uint4(wl[4], wl[5], wl[6], wl[7]);
}

// --- shared tile-score routine: MUST be bit-identical between pass 1/2 ------
// C-operand initialized to -0.5|h_j|^2 (nsq), so scv = acc directly. MFMA
// chain dependency-ordered => deterministic recompute in pass 2.
__device__ __forceinline__ void tile_scores(const ushort* __restrict__ hHi,
        const ushort* __restrict__ hMid, const ushort* __restrict__ hLo,
        const float* __restrict__ nsq, long bN, int j0, int ln31, int koff,
        int rbase, int i0w, bf16x8 bi_h, bf16x8 bi_m, bf16x8 bi_l,
        float scv[16]) {
    int jr = j0 + ln31;
    bf16x8 aj_h = *(const bf16x8*)&hHi [(bN + jr) * 16 + koff];
    bf16x8 aj_m = *(const bf16x8*)&hMid[(bN + jr) * 16 + koff];
    bf16x8 aj_l = *(const bf16x8*)&hLo [(bN + jr) * 16 + koff];
    float4 q0 = *(const float4*)&nsq[bN + j0 +  0 + rbase];
    float4 q1 = *(const float4*)&nsq[bN + j0 +  8 + rbase];
    float4 q2 = *(const float4*)&nsq[bN + j0 + 16 + rbase];
    float4 q3 = *(const float4*)&nsq[bN + j0 + 24 + rbase];
    f32x16 acc;
    acc[0]  = q0.x; acc[1]  = q0.y; acc[2]  = q0.z; acc[3]  = q0.w;
    acc[4]  = q1.x; acc[5]  = q1.y; acc[6]  = q1.z; acc[7]  = q1.w;
    acc[8]  = q2.x; acc[9]  = q2.y; acc[10] = q2.z; acc[11] = q2.w;
    acc[12] = q3.x; acc[13] = q3.y; acc[14] = q3.z; acc[15] = q3.w;
    acc = __builtin_amdgcn_mfma_f32_32x32x16_bf16(aj_h, bi_h, acc, 0, 0, 0);
    acc = __builtin_amdgcn_mfma_f32_32x32x16_bf16(aj_h, bi_m, acc, 0, 0, 0);
    acc = __builtin_amdgcn_mfma_f32_32x32x16_bf16(aj_m, bi_h, acc, 0, 0, 0);
    acc = __builtin_amdgcn_mfma_f32_32x32x16_bf16(aj_h, bi_l, acc, 0, 0, 0);
    acc = __builtin_amdgcn_mfma_f32_32x32x16_bf16(aj_l, bi_h, acc, 0, 0, 0);
    acc = __builtin_amdgcn_mfma_f32_32x32x16_bf16(aj_m, bi_m, acc, 0, 0, 0);
#pragma unroll
    for (int rr = 0; rr < 16; rr++) scv[rr] = acc[rr];
    if (j0 == i0w) {                       // wave-uniform: diagonal tile, mask self
#pragma unroll
        for (int rr = 0; rr < 16; rr++) {
            int r = (rr & 3) + 8 * (rr >> 2) + rbase;
            if (r == ln31) scv[rr] = -FLT_MAX;
        }
    }
}

// --- sorting-network primitives (compare-exchange = max/min pair: exact
// multiset preservation, fully unrolled constant indexing) ------------------
#define CEX(a, b) { float ce_hi = fmaxf(a, b), ce_lo = fminf(a, b); (a) = ce_hi; (b) = ce_lo; }
// Batcher odd-even mergesort, 8 values descending (19 CE)
__device__ __forceinline__ void sort8d(float v[8]) {
    CEX(v[0],v[1]); CEX(v[2],v[3]); CEX(v[4],v[5]); CEX(v[6],v[7]);
    CEX(v[0],v[2]); CEX(v[1],v[3]); CEX(v[4],v[6]); CEX(v[5],v[7]);
    CEX(v[1],v[2]); CEX(v[5],v[6]);
    CEX(v[0],v[4]); CEX(v[1],v[5]); CEX(v[2],v[6]); CEX(v[3],v[7]);
    CEX(v[2],v[4]); CEX(v[3],v[5]);
    CEX(v[1],v[2]); CEX(v[3],v[4]); CEX(v[5],v[6]);
}
// bitonic 8-sequence -> sorted descending (12 CE)
__device__ __forceinline__ void bsort8d(float v[8]) {
    CEX(v[0],v[4]); CEX(v[1],v[5]); CEX(v[2],v[6]); CEX(v[3],v[7]);
    CEX(v[0],v[2]); CEX(v[1],v[3]); CEX(v[4],v[6]); CEX(v[5],v[7]);
    CEX(v[0],v[1]); CEX(v[2],v[3]); CEX(v[4],v[5]); CEX(v[6],v[7]);
}

// --------- kNN scan, two-pass scores-only selection --------------------------
// Pass 1: per tile, sorting-network top-8 (exact score multiset -> theta =
//         exact 8th-best of the (column, slice) after the lane^32 pair-merge).
// Pass 2: recompute scores bit-identically; gt/eq bitmasks + ffs-loop pushes
//         ids to LDS. Assembly emits the exact reference top-8 SET per slice
//         (order irrelevant: k_gat2 re-scores the pool in exact fp32).
// R7: #pragma unroll 2 on both tile loops — two independent 6-deep MFMA
// chains in flight to hide MFMA latency + load latency (the ~20% of time
// the pipes sat idle in R6's counters).
__global__ __attribute__((amdgpu_waves_per_eu(4, 4))) __launch_bounds__(256)
void k_scan(const ushort* __restrict__ hHi, const ushort* __restrict__ hMid,
            const ushort* __restrict__ hLo, const float* __restrict__ nsq,
            uint4* __restrict__ cand_i) {
    __shared__ unsigned lists[256][17];  // [tid][0..7]=A ids, [8..15]=B ids, [16]=trash
    __shared__ ushort outl[256][8];
    int tid = threadIdx.x, blk = blockIdx.x;
    int b  = blk >> 7;                   // 128 blocks per batch (32 ig x 4 sl)
    int ig = (blk >> 2) & 31;
    int sl = blk & 3;
    int wid = tid >> 6, lane = tid & 63;
    int ln31 = lane & 31, l5 = lane >> 5;
    int koff = l5 * 8;
    int i0w = ig * 128 + wid * 32;       // this wave's 32-aligned i-tile base
    int i   = i0w + ln31;
    long bN = (long)b * NN;
    int rbase = l5 * 4;
    int jbase = sl * 1024;

    bf16x8 bi_h = *(const bf16x8*)&hHi [(bN + i) * 16 + koff];
    bf16x8 bi_m = *(const bf16x8*)&hMid[(bN + i) * 16 + koff];
    bf16x8 bi_l = *(const bf16x8*)&hLo [(bN + i) * 16 + koff];

    // ---- pass 1: top-8 scores only (sorted descending invariant) ----
    float s[8];
#pragma unroll
    for (int k = 0; k < 8; k++) s[k] = -FLT_MAX;
#pragma unroll 2
    for (int t = 0; t < 32; t++) {
        int j0 = jbase + t * 32;
        float scv[16];
        tile_scores(hHi, hMid, hLo, nsq, bN, j0, ln31, koff, rbase, i0w,
                    bi_h, bi_m, bi_l, scv);
        float va[8] = { scv[0], scv[1], scv[2], scv[3], scv[4], scv[5], scv[6], scv[7] };
        float vb[8] = { scv[8], scv[9], scv[10], scv[11], scv[12], scv[13], scv[14], scv[15] };
        sort8d(va); sort8d(vb);
        float mg[8];
#pragma unroll
        for (int k = 0; k < 8; k++) mg[k] = fmaxf(va[k], vb[7 - k]);  // top-8 of 16, bitonic
        bsort8d(mg);
#pragma unroll
        for (int k = 0; k < 8; k++) s[k] = fmaxf(s[k], mg[7 - k]);    // top-8 of (s ∪ mg), bitonic
        bsort8d(s);
    }
    // pair-merge: top-8 of union(lane, lane^32) as a multiset; theta = its min.
    float mv[8];
#pragma unroll
    for (int k = 0; k < 8; k++) mv[k] = fmaxf(s[k], __shfl_xor(s[7 - k], 32));
    float theta = mv[0];
#pragma unroll
    for (int k = 1; k < 8; k++) theta = fminf(theta, mv[k]);

    // ---- pass 2: id recovery via bitmask + ffs ----
    unsigned* ldsw = &lists[0][0];
    int baseA = tid * 17, baseB = baseA + 8, trash = baseA + 16;
    int nA = 0, nB = 0;
#pragma unroll 2
    for (int t = 0; t < 32; t++) {
        int j0 = jbase + t * 32;
        float scv[16];
        tile_scores(hHi, hMid, hLo, nsq, bN, j0, ln31, koff, rbase, i0w,
                    bi_h, bi_m, bi_l, scv);
        unsigned gm = 0, em = 0;
#pragma unroll
        for (int rr = 0; rr < 16; rr++) {
            gm |= (scv[rr] >  theta) ? (1u << rr) : 0u;
            em |= (scv[rr] == theta) ? (1u << rr) : 0u;
        }
        unsigned m = gm | em;
        while (__any(m != 0u)) {
            if (m) {
                int rr = __ffs(m) - 1;
                m &= m - 1u;
                int r = (rr & 3) + ((rr >> 2) << 3) + rbase;
                int j = j0 + r;
                bool isGt = (gm >> rr) & 1u;
                bool cA = isGt && (nA < 8);   // <=7 by math; insurance
                bool cB = (!isGt) && (nB < 8);
                int ia = cA ? (baseA + nA) : (cB ? (baseB + nB) : trash);
                ldsw[ia] = (unsigned)j;       // single predicated write
                nA += cA;
                nB += cB;
            }
        }
    }
    int pA = __shfl_xor(nA, 32);
    int pB = __shfl_xor(nB, 32);
    __syncthreads();
    // ---- assembly (per column, lane<32): A ids + smallest-j ties to fill 8 ----
    if (lane < 32) {
        int tp = tid + 32;
        int n = 0;
        for (int k = 0; k < nA && n < 8; k++) outl[tid][n++] = (ushort)lists[tid][k];
        for (int k = 0; k < pA && n < 8; k++) outl[tid][n++] = (ushort)lists[tp][k];
        int p0 = 0, p1 = 0;
        while (n < 8) {                  // two-pointer merge of j-ascending tie lists
            unsigned a = (p0 < nB) ? lists[tid][8 + p0] : 0xFFFFFFFFu;
            unsigned c = (p1 < pB) ? lists[tp][8 + p1] : 0xFFFFFFFFu;
            bool t0 = a < c;
            outl[tid][n++] = (ushort)(t0 ? a : c);
            p0 += t0 ? 1 : 0; p1 += t0 ? 0 : 1;
        }
        uint4 pk = *(const uint4*)&outl[tid][0];
        cand_i[(long)(b * NSL + sl) * NN + i] = pk;
    }
}

// --- merge 4 slice-lists (recompute scores in exact fp32) + GAT -> p --------
// 64-thread blocks, 512-block grid: full 256-CU coverage. #pragma unroll on
// the slice loop lets the compiler hoist all 4 independent cand_i loads and
// overlap the 32 h-row gathers (latency-bound kernel).
__launch_bounds__(64)
__global__ void k_gat2(const uint4* __restrict__ cand_i, const float* __restrict__ h,
                       const float* __restrict__ sq,
                       const float* __restrict__ xp, const float* __restrict__ asr,
                       const float* __restrict__ adt, const float* __restrict__ bg,
                       float* __restrict__ p) {
    int t = blockIdx.x * 64 + threadIdx.x;        // 0..32767
    int b = t >> 12, i = t & 4095;
    long bN = (long)b * NN;
    const float4* ip = (const float4*)&h[(bN + i) * 16];
    float4 r0 = ip[0], r1 = ip[1], r2 = ip[2], r3 = ip[3];
    float ni[16] = { r0.x,r0.y,r0.z,r0.w, r1.x,r1.y,r1.z,r1.w,
                     r2.x,r2.y,r2.z,r2.w, r3.x,r3.y,r3.z,r3.w };
    float fS[8]; int fI[8];
#pragma unroll
    for (int k = 0; k < 8; k++) { fS[k] = -FLT_MAX; fI[k] = 65535; }
#pragma unroll
    for (int sl = 0; sl < NSL; sl++) {
        uint4 pk = cand_i[(long)(b * NSL + sl) * NN + i];
        unsigned idx8[8] = { pk.x & 0xFFFF, pk.x >> 16, pk.y & 0xFFFF, pk.y >> 16,
                             pk.z & 0xFFFF, pk.z >> 16, pk.w & 0xFFFF, pk.w >> 16 };
#pragma unroll
        for (int k = 0; k < 8; k++) {
            int j = (int)idx8[k];
            const float4* np = (const float4*)&h[(bN + j) * 16];
            float4 a0 = np[0], a1 = np[1], a2 = np[2], a3 = np[3];
            float d = dot16m(ni, a0, a1, a2, a3, sq[bN + j]);
            bool bt = (d > fS[7]) || (d == fS[7] && j < fI[7]);
            if (bt) {
                fS[7] = d; fI[7] = j;
#pragma unroll
                for (int q = 7; q > 0; q--) {
                    bool sw = (fS[q] > fS[q - 1]) || (fS[q] == fS[q - 1] && fI[q] < fI[q - 1]);
                    if (sw) {
                        float td = fS[q]; fS[q] = fS[q - 1]; fS[q - 1] = td;
                        int tj = fI[q]; fI[q] = fI[q - 1]; fI[q - 1] = tj;
                    }
                }
            }
        }
    }
    int nbrs[9];
#pragma unroll
    for (int e = 0; e < 8; e++) nbrs[e] = fI[e];
    nbrs[8] = i;                                   // self-loop
    float adtv[4];
#pragma unroll
    for (int hh = 0; hh < 4; hh++) adtv[hh] = adt[(bN + i) * 4 + hh];
    float mx[4] = { -FLT_MAX, -FLT_MAX, -FLT_MAX, -FLT_MAX };
    float lg[9][4];
#pragma unroll
    for (int e = 0; e < 9; e++) {
        long nb = bN + nbrs[e];
#pragma unroll
        for (int hh = 0; hh < 4; hh++) {
            float l = asr[nb * 4 + hh] + adtv[hh];
            l = (l > 0.f) ? l : 0.2f * l;          // leaky_relu 0.2
            lg[e][hh] = l;
            mx[hh] = fmaxf(mx[hh], l);
        }
    }
    float sum[4] = { 0, 0, 0, 0 };
    float acc[16];
#pragma unroll
    for (int c = 0; c < 16; c++) acc[c] = 0.f;
#pragma unroll
    for (int e = 0; e < 9; e++) {
        long nb = bN + nbrs[e];
        const float4* xpn = (const float4*)&xp[nb * 16];
        float4 x0 = xpn[0], x1 = xpn[1], x2 = xpn[2], x3 = xpn[3];
        float xv[16] = { x0.x,x0.y,x0.z,x0.w, x1.x,x1.y,x1.z,x1.w,
                         x2.x,x2.y,x2.z,x2.w, x3.x,x3.y,x3.z,x3.w };
        float wv[4];
#pragma unroll
        for (int hh = 0; hh < 4; hh++) {
            float w = expf(lg[e][hh] - mx[hh]);
            sum[hh] += w; wv[hh] = w;
        }
#pragma unroll
        for (int hh = 0; hh < 4; hh++)
#pragma unroll
            for (int f = 0; f < 4; f++)
                acc[hh * 4 + f] += wv[hh] * xv[hh * 4 + f];
    }
#pragma unroll
    for (int hh = 0; hh < 4; hh++) {
        float inv = 1.f / sum[hh];
#pragma unroll
        for (int f = 0; f < 4; f++) {
            float o = acc[hh * 4 + f] * inv + bg[hh * 4 + f];
            p[(bN + i) * 16 + hh * 4 + f] = fmaxf(o, 0.f);
        }
    }
}

// ------- 1x1 MLP 16->128->16, fire mask, h += mask*u, 1x1->1 + sigmoid ------
#define USTR 20
__launch_bounds__(256)
__global__ void k_update(const float* __restrict__ p, const float* __restrict__ h,
                         const float* __restrict__ fire, const float* __restrict__ Wu1,
                         const float* __restrict__ bu1, const float* __restrict__ Wu2,
                         const float* __restrict__ bu2, const float* __restrict__ Wo,
                         const float* __restrict__ bo, float* __restrict__ out_low) {
    __shared__ float sU1[128 * 16];
    __shared__ float sU2t[128 * 16];      // [hd][c] = Wu2[c][hd]
    __shared__ float sb1[128];
    __shared__ float uhalf[128 * USTR];
    int tid = threadIdx.x;
    for (int k = tid; k < 2048; k += 256) {
        sU1[k] = Wu1[k];
        sU2t[(k & 127) * 16 + (k >> 7)] = Wu2[k];   // coalesced read, scatter to LDS
    }
    if (tid < 128) sb1[tid] = bu1[tid];
    __syncthreads();
    int lnode = tid & 127, half = tid >> 7;
    long n = (long)blockIdx.x * 128 + lnode;         // 0..32767
    const float4* pp = (const float4*)&p[n * 16];
    float4 p0 = pp[0], p1 = pp[1], p2 = pp[2], p3 = pp[3];
    float pv[16] = { p0.x,p0.y,p0.z,p0.w, p1.x,p1.y,p1.z,p1.w,
                     p2.x,p2.y,p2.z,p2.w, p3.x,p3.y,p3.z,p3.w };
    float u[16];
#pragma unroll
    for (int c = 0; c < 16; c++) u[c] = 0.f;
    int hd0 = half * 64;
    for (int hd = hd0; hd < hd0 + 64; hd++) {
        const float4* r = (const float4*)&sU1[hd * 16];
        float4 r0 = r[0], r1 = r[1], r2 = r[2], r3 = r[3];
        float a = sb1[hd]
            + r0.x*pv[0] + r0.y*pv[1] + r0.z*pv[2] + r0.w*pv[3]
            + r1.x*pv[4] + r1.y*pv[5] + r1.z*pv[6] + r1.w*pv[7]
            + r2.x*pv[8] + r2.y*pv[9] + r2.z*pv[10]+ r2.w*pv[11]
            + r3.x*pv[12]+ r3.y*pv[13]+ r3.z*pv[14]+ r3.w*pv[15];
        a = fmaxf(a, 0.f);
        const float4* tt = (const float4*)&sU2t[hd * 16];
        float4 t0 = tt[0], t1 = tt[1], t2 = tt[2], t3 = tt[3];
        u[0] += t0.x*a; u[1] += t0.y*a; u[2] += t0.z*a; u[3] += t0.w*a;
        u[4] += t1.x*a; u[5] += t1.y*a; u[6] += t1.z*a; u[7] += t1.w*a;
        u[8] += t2.x*a; u[9] += t2.y*a; u[10]+= t2.z*a; u[11]+= t2.w*a;
        u[12]+= t3.x*a; u[13]+= t3.y*a; u[14]+= t3.z*a; u[15]+= t3.w*a;
    }
    if (half == 1) {
        float4* dst = (float4*)&uhalf[lnode * USTR];
        dst[0] = make_float4(u[0], u[1], u[2], u[3]);
        dst[1] = make_float4(u[4], u[5], u[6], u[7]);
        dst[2] = make_float4(u[8], u[9], u[10], u[11]);
        dst[3] = make_float4(u[12], u[13], u[14], u[15]);
    }
    __syncthreads();
    if (half == 0) {
        const float4* src = (const float4*)&uhalf[lnode * USTR];
        float4 o0 = src[0], o1 = src[1], o2 = src[2], o3 = src[3];
        float ou[16] = { o0.x,o0.y,o0.z,o0.w, o1.x,o1.y,o1.z,o1.w,
                         o2.x,o2.y,o2.z,o2.w, o3.x,o3.y,o3.z,o3.w };
        float mask = (fire[n] < 0.5f) ? 1.f : 0.f;
        const float4* hp = (const float4*)&h[n * 16];
        float4 h0 = hp[0], h1v = hp[1], h2 = hp[2], h3 = hp[3];
        float hv[16] = { h0.x,h0.y,h0.z,h0.w, h1v.x,h1v.y,h1v.z,h1v.w,
                         h2.x,h2.y,h2.z,h2.w, h3.x,h3.y,h3.z,h3.w };
        float o = bo[0];
#pragma unroll
        for (int c = 0; c < 16; c++)
            o += Wo[c] * (hv[c] + mask * (u[c] + ou[c] + bu2[c]));
        out_low[n] = 1.f / (1.f + expf(-o));
    }
}

// ---------------- bilinear upsample 64 -> 256 (half-pixel, clamp) -----------
__global__ void k_up(const float* __restrict__ ol, float* __restrict__ out) {
    int t = blockIdx.x * 256 + threadIdx.x;
    if (t >= BATCH * HIGH * HIGH) return;
    int b = t >> 16, oy = (t >> 8) & 255, ox = t & 255;
    float cy = (oy + 0.5f) * 0.25f - 0.5f;
    float cx = (ox + 0.5f) * 0.25f - 0.5f;
    int iy0 = (int)floorf(cy); float fy = cy - (float)iy0;
    int ix0 = (int)floorf(cx); float fx = cx - (float)ix0;
    int y0 = min(max(iy0, 0), 63), y1 = min(max(iy0 + 1, 0), 63);
    int x0 = min(max(ix0, 0), 63), x1 = min(max(ix0 + 1, 0), 63);
    const float* s = ol + b * NN;
    float v = (1.f - fy) * ((1.f - fx) * s[y0 * 64 + x0] + fx * s[y0 * 64 + x1])
            + fy * ((1.f - fx) * s[y1 * 64 + x0] + fx * s[y1 * 64 + x1]);
    out[t] = v;
}

extern "C" void kernel_launch(void* const* d_in, const int* in_sizes, int n_in,
                              void* d_out, int out_size, void* d_ws, size_t ws_size,
                              hipStream_t stream) {
    const float* x    = (const float*)d_in[0];
    const float* fire = (const float*)d_in[1];
    const float* W1   = (const float*)d_in[2];
    const float* b1   = (const float*)d_in[3];
    const float* g1   = (const float*)d_in[4];
    const float* be1  = (const float*)d_in[5];
    const float* m1   = (const float*)d_in[6];
    const float* v1   = (const float*)d_in[7];
    const float* W2   = (const float*)d_in[8];
    const float* b2   = (const float*)d_in[9];
    const float* g2   = (const float*)d_in[10];
    const float* be2  = (const float*)d_in[11];
    const float* m2   = (const float*)d_in[12];
    const float* v2   = (const float*)d_in[13];
    const float* Wg   = (const float*)d_in[14];
    const float* a_src= (const float*)d_in[15];
    const float* a_dst= (const float*)d_in[16];
    const float* bg   = (const float*)d_in[17];
    const float* Wu1  = (const float*)d_in[18];
    const float* bu1  = (const float*)d_in[19];
    const float* Wu2  = (const float*)d_in[20];
    const float* bu2  = (const float*)d_in[21];
    const float* Wo   = (const float*)d_in[22];
    const float* bo   = (const float*)d_in[23];

    float* ws  = (float*)d_ws;
    float* xl  = ws + OFF_XL;
    float* h1  = ws + OFF_H1;
    float* h   = ws + OFF_H;
    float* sq  = ws + OFF_SQ;
    float* xp  = ws + OFF_XP;
    float* asr = ws + OFF_ASR;
    float* adt = ws + OFF_ADT;
    float* p   = ws + OFF_P;
    float* ol  = ws + OFF_OL;
    // H1 region reuse (dead after conv2): cand_i 2 MB (NSL=4), bf16 splits,
    // nsq. Total 1,867,776 of 2,097,152 floats — no footprint growth.
    uint4*  cand_i = (uint4*)(ws + OFF_H1);
    ushort* hHi    = (ushort*)(ws + OFF_H1 + 1048576);
    ushort* hMid   = (ushort*)(ws + OFF_H1 + 1310720);
    ushort* hLo    = (ushort*)(ws + OFF_H1 + 1572864);
    float*  nsq    = ws + OFF_H1 + 1835008;

    k_down  <<<(BATCH * NN + 127) / 128, 128, 0, stream>>>(x, xl);
    k_conv1 <<<(BATCH * C1 * NN) / 256, 256, 0, stream>>>(xl, W1, b1, g1, be1, m1, v1, h1);
    k_conv2 <<<BATCH * 32, 512, 0, stream>>>(h1, W2, b2, g2, be2, m2, v2, Wg, a_src, a_dst,
                                             h, sq, xp, asr, adt);
    k_split <<<BATCH * NN / 64, 64, 0, stream>>>(h, sq, hHi, hMid, hLo, nsq);
    k_scan  <<<BATCH * 32 * NSL, 256, 0, stream>>>(hHi, hMid, hLo, nsq, cand_i);
    k_gat2  <<<BATCH * NN / 64, 64, 0, stream>>>(cand_i, h, sq, xp, asr, adt, bg, p);
    k_update<<<BATCH * NN / 128, 256, 0, stream>>>(p, h, fire, Wu1, bu1, Wu2, bu2, Wo, bo, ol);
    k_up    <<<(BATCH * HIGH * HIGH) / 256, 256, 0, stream>>>(ol, (float*)d_out);
}

// Round 8
// 278.709 us; speedup vs baseline: 1.5744x; 1.0762x over previous
//
#include <hip/hip_runtime.h>
#include <math.h>
#include <float.h>

#define BATCH 8
#define HIGH  256
#define LOWR  64
#define NN    4096          // LOWR*LOWR
#define HIDC  16
#define C1    64
#define NSL   4             // j-slices in kNN scan (1024 j each)

// workspace layout (floats) — footprint identical to the validated layout
#define OFF_XL   0
#define OFF_H1   (OFF_XL  + BATCH*NN)            // 2.097M floats; reused after conv2:
                                                 //   [0 .. 524,287]           cand_i (2 MB, NSL=4)
                                                 //   [1,048,576 .. 1,835,007] bf16 hi/mid/lo splits
                                                 //   [1,835,008 .. 1,867,775] nsq (= -sq)
#define OFF_H    (OFF_H1  + BATCH*C1*NN)         // node-major [B*N][16]
#define OFF_SQ   (OFF_H   + BATCH*NN*HIDC)       // 0.5*|h|^2 per node
#define OFF_XP   (OFF_SQ  + BATCH*NN)
#define OFF_ASR  (OFF_XP  + BATCH*NN*HIDC)
#define OFF_ADT  (OFF_ASR + BATCH*NN*4)
#define OFF_P    (OFF_ADT + BATCH*NN*4)
#define OFF_OL   (OFF_P   + BATCH*NN*HIDC)

typedef __attribute__((ext_vector_type(8)))  short bf16x8;
typedef __attribute__((ext_vector_type(16))) float f32x16;

// identical-arithmetic dot used by k_gat2 (exact fp32 re-score of the pool —
// final selection semantics unchanged from the validated kernel)
__device__ __forceinline__ float dot16m(const float ni[16], float4 a0, float4 a1,
                                        float4 a2, float4 a3, float hs) {
    return ni[0]*a0.x + ni[1]*a0.y + ni[2]*a0.z + ni[3]*a0.w
         + ni[4]*a1.x + ni[5]*a1.y + ni[6]*a1.z + ni[7]*a1.w
         + ni[8]*a2.x + ni[9]*a2.y + ni[10]*a2.z + ni[11]*a2.w
         + ni[12]*a3.x + ni[13]*a3.y + ni[14]*a3.z + ni[15]*a3.w
         - hs;
}

// ---------------- bilinear downsample 256 -> 64 (antialiased triangle) -------
__global__ void k_down(const float* __restrict__ x, float* __restrict__ xl) {
    int t = blockIdx.x * 128 + threadIdx.x;
    if (t >= BATCH * NN) return;
    int b = t >> 12, oy = (t >> 6) & 63, ox = t & 63;
    const float* xb = x + b * HIGH * HIGH;
    float cy = 4.f * oy + 1.5f, cx = 4.f * ox + 1.5f;
    float wy[8], wx[8], sy = 0.f, sx = 0.f;
#pragma unroll
    for (int k = 0; k < 8; k++) {
        int iy = 4 * oy - 2 + k;
        float w = 1.f - fabsf((float)iy - cy) * 0.25f;
        if (iy < 0 || iy >= HIGH) w = 0.f;
        wy[k] = w; sy += w;
        int ix = 4 * ox - 2 + k;
        float v = 1.f - fabsf((float)ix - cx) * 0.25f;
        if (ix < 0 || ix >= HIGH) v = 0.f;
        wx[k] = v; sx += v;
    }
    float acc = 0.f;
#pragma unroll
    for (int ky = 0; ky < 8; ky++) {
        if (wy[ky] == 0.f) continue;
        int iy = 4 * oy - 2 + ky;
        float rowacc = 0.f;
#pragma unroll
        for (int kx = 0; kx < 8; kx++) {
            if (wx[kx] == 0.f) continue;
            int ix = 4 * ox - 2 + kx;
            rowacc += wx[kx] * xb[iy * HIGH + ix];
        }
        acc += wy[ky] * rowacc;
    }
    xl[t] = acc / (sy * sx);
}

// ---------------- conv3x3 1->64 + BN + relu ---------------------------------
__global__ void k_conv1(const float* __restrict__ xl, const float* __restrict__ W1,
                        const float* __restrict__ b1, const float* __restrict__ g1,
                        const float* __restrict__ be1, const float* __restrict__ m1,
                        const float* __restrict__ v1, float* __restrict__ h1) {
    int t = blockIdx.x * 256 + threadIdx.x;
    if (t >= BATCH * C1 * NN) return;
    int b = t >> 18, co = (t >> 12) & 63, y = (t >> 6) & 63, x = t & 63;
    const float* src = xl + b * NN;
    const float* w = W1 + co * 9;
    float acc = 0.f;
#pragma unroll
    for (int dy = -1; dy <= 1; dy++) {
        int yy = y + dy; if (yy < 0 || yy >= 64) continue;
#pragma unroll
        for (int dx = -1; dx <= 1; dx++) {
            int xx = x + dx; if (xx < 0 || xx >= 64) continue;
            acc += w[(dy + 1) * 3 + (dx + 1)] * src[yy * 64 + xx];
        }
    }
    acc += b1[co];
    float sc = g1[co] / sqrtf(v1[co] + 1e-5f);
    acc = (acc - m1[co]) * sc + be1[co];
    h1[t] = fmaxf(acc, 0.f);
}

// ------- conv3x3 64->16 + BN + relu, fused: h (node-major), sq, xp, asr, adt -
// 512 threads, 4-way ci-split (16 ci per thread) -> 8 waves/CU on all 4
// SIMDs. Quarters 1-3 write partials to LDS, quarter 0 reduces + epilogue.
__launch_bounds__(512)
__global__ void k_conv2(const float* __restrict__ h1, const float* __restrict__ W2,
                        const float* __restrict__ b2, const float* __restrict__ g2,
                        const float* __restrict__ be2, const float* __restrict__ m2,
                        const float* __restrict__ v2, const float* __restrict__ Wg,
                        const float* __restrict__ a_src, const float* __restrict__ a_dst,
                        float* __restrict__ h, float* __restrict__ sq,
                        float* __restrict__ xp, float* __restrict__ asr,
                        float* __restrict__ adt) {
    __shared__ float sW2t[576 * 16];    // [ci*9+tap][o]
    __shared__ float sWg[256];
    __shared__ float sA[32];
    __shared__ float accH[3][128][17];  // partials from quarters 1..3 (17-pad)
    int tid = threadIdx.x;
    for (int k = tid; k < 9216; k += 512) {          // coalesced global read, scatter to LDS
        int o = k / 576, ct = k - o * 576;
        sW2t[ct * 16 + o] = W2[k];
    }
    if (tid < 256) sWg[tid] = Wg[tid];
    if (tid < 16) { sA[tid] = a_src[tid]; sA[16 + tid] = a_dst[tid]; }
    __syncthreads();
    int blk = blockIdx.x;                 // 8 batches * 32 y-tiles
    int b = blk >> 5, ytile = blk & 31;
    int q = tid >> 7;                     // ci quarter 0..3
    int sub = tid & 127;
    int ty = sub >> 6, x = sub & 63, y = ytile * 2 + ty;
    float acc[16];
#pragma unroll
    for (int o = 0; o < 16; o++) acc[o] = 0.f;
    const float* hb = h1 + (long)b * C1 * NN + (long)q * 16 * NN;
    for (int ci = 0; ci < 16; ci++) {
        const float* plane = hb + ci * NN;
#pragma unroll
        for (int dy = -1; dy <= 1; dy++) {
            int yy = y + dy; bool oky = (yy >= 0 && yy < 64);
#pragma unroll
            for (int dx = -1; dx <= 1; dx++) {
                int xx = x + dx;
                float v = (oky && xx >= 0 && xx < 64) ? plane[yy * 64 + xx] : 0.f;
                int ct = (q * 16 + ci) * 9 + (dy + 1) * 3 + (dx + 1);
                const float4* wr = (const float4*)&sW2t[ct * 16];
                float4 w0 = wr[0], w1 = wr[1], w2 = wr[2], w3 = wr[3];
                acc[0] += v * w0.x; acc[1] += v * w0.y; acc[2] += v * w0.z; acc[3] += v * w0.w;
                acc[4] += v * w1.x; acc[5] += v * w1.y; acc[6] += v * w1.z; acc[7] += v * w1.w;
                acc[8] += v * w2.x; acc[9] += v * w2.y; acc[10]+= v * w2.z; acc[11]+= v * w2.w;
                acc[12]+= v * w3.x; acc[13]+= v * w3.y; acc[14]+= v * w3.z; acc[15]+= v * w3.w;
            }
        }
    }
    if (q != 0) {
        float* dst = &accH[q - 1][sub][0];
#pragma unroll
        for (int o = 0; o < 16; o++) dst[o] = acc[o];
    }
    __syncthreads();
    if (q != 0) return;
#pragma unroll
    for (int qq = 0; qq < 3; qq++) {
        const float* src = &accH[qq][sub][0];
#pragma unroll
        for (int o = 0; o < 16; o++) acc[o] += src[o];
    }
    int n = y * 64 + x;
    long node = (long)b * NN + n;
    float nodev[16], sqv = 0.f;
#pragma unroll
    for (int o = 0; o < 16; o++) {
        float a = acc[o] + b2[o];
        float sc = g2[o] / sqrtf(v2[o] + 1e-5f);
        a = (a - m2[o]) * sc + be2[o];
        a = fmaxf(a, 0.f);
        nodev[o] = a; sqv += a * a;
        h[node * 16 + o] = a;
    }
    sq[node] = 0.5f * sqv;                // pre-scaled: scan/merge use dot - 0.5|j|^2
    float xpv[16];
#pragma unroll
    for (int o = 0; o < 16; o++) {
        float a = 0.f;
#pragma unroll
        for (int c = 0; c < 16; c++) a += sWg[o * 16 + c] * nodev[c];
        xpv[o] = a;
        xp[node * 16 + o] = a;
    }
#pragma unroll
    for (int hh = 0; hh < 4; hh++) {
        float as = 0.f, ad = 0.f;
#pragma unroll
        for (int f = 0; f < 4; f++) {
            as += xpv[hh * 4 + f] * sA[hh * 4 + f];
            ad += xpv[hh * 4 + f] * sA[16 + hh * 4 + f];
        }
        asr[node * 4 + hh] = as;
        adt[node * 4 + hh] = ad;
    }
}

// ------- error-free 3-way bf16 split of h: h = hi + mid + lo + O(2^-27) -----
// (NOT fused into conv2: split outputs live inside the h1 region that other
// conv2 blocks still read — fusing would race. Kept as a cheap separate pass.)
__device__ __forceinline__ ushort f2bf(float f) {
    unsigned u = __float_as_uint(f);
    return (ushort)((u + 0x7FFFu + ((u >> 16) & 1u)) >> 16);
}
__device__ __forceinline__ float bf2f(ushort h) {
    return __uint_as_float(((unsigned)h) << 16);
}
__global__ void k_split(const float* __restrict__ h, const float* __restrict__ sq,
                        ushort* __restrict__ hHi, ushort* __restrict__ hMid,
                        ushort* __restrict__ hLo, float* __restrict__ nsq) {
    long t = (long)blockIdx.x * 64 + threadIdx.x;    // node 0..32767
    nsq[t] = -sq[t];                                  // negated for MFMA C-init
    const float4* hp = (const float4*)&h[t * 16];
    float4 v0 = hp[0], v1 = hp[1], v2 = hp[2], v3 = hp[3];
    float v[16] = { v0.x,v0.y,v0.z,v0.w, v1.x,v1.y,v1.z,v1.w,
                    v2.x,v2.y,v2.z,v2.w, v3.x,v3.y,v3.z,v3.w };
    unsigned wh[8], wm[8], wl[8];
#pragma unroll
    for (int p = 0; p < 8; p++) {
        unsigned packh = 0, packm = 0, packl = 0;
#pragma unroll
        for (int e = 0; e < 2; e++) {
            float f = v[p * 2 + e];
            ushort hi = f2bf(f);
            float t1 = f - bf2f(hi);
            ushort mi = f2bf(t1);
            float t2 = t1 - bf2f(mi);
            ushort lo = f2bf(t2);
            packh |= ((unsigned)hi) << (16 * e);
            packm |= ((unsigned)mi) << (16 * e);
            packl |= ((unsigned)lo) << (16 * e);
        }
        wh[p] = packh; wm[p] = packm; wl[p] = packl;
    }
    uint4* dh = (uint4*)&hHi[t * 16];
    uint4* dm = (uint4*)&hMid[t * 16];
    uint4* dl = (uint4*)&hLo[t * 16];
    dh[0] = make_uint4(wh[0], wh[1], wh[2], wh[3]);
    dh[1] = make_uint4(wh[4], wh[5], wh[6], wh[7]);
    dm[0] = make_uint4(wm[0], wm[1], wm[2], wm[3]);
    dm[1] = make_uint4(wm[4], wm[5], wm[6], wm[7]);
    dl[0] = make_uint4(wl[0], wl[1], wl[2], wl[3]);
    dl[1] = make_uint4(wl[4], wl[5], wl[6], wl[7]);
}

// --- shared tile-score routine: MUST be bit-identical between pass 1/2 ------
__device__ __forceinline__ void tile_scores(const ushort* __restrict__ hHi,
        const ushort* __restrict__ hMid, const ushort* __restrict__ hLo,
        const float* __restrict__ nsq, long bN, int j0, int ln31, int koff,
        int rbase, int i0w, bf16x8 bi_h, bf16x8 bi_m, bf16x8 bi_l,
        float scv[16]) {
    int jr = j0 + ln31;
    bf16x8 aj_h = *(const bf16x8*)&hHi [(bN + jr) * 16 + koff];
    bf16x8 aj_m = *(const bf16x8*)&hMid[(bN + jr) * 16 + koff];
    bf16x8 aj_l = *(const bf16x8*)&hLo [(bN + jr) * 16 + koff];
    float4 q0 = *(const float4*)&nsq[bN + j0 +  0 + rbase];
    float4 q1 = *(const float4*)&nsq[bN + j0 +  8 + rbase];
    float4 q2 = *(const float4*)&nsq[bN + j0 + 16 + rbase];
    float4 q3 = *(const float4*)&nsq[bN + j0 + 24 + rbase];
    f32x16 acc;
    acc[0]  = q0.x; acc[1]  = q0.y; acc[2]  = q0.z; acc[3]  = q0.w;
    acc[4]  = q1.x; acc[5]  = q1.y; acc[6]  = q1.z; acc[7]  = q1.w;
    acc[8]  = q2.x; acc[9]  = q2.y; acc[10] = q2.z; acc[11] = q2.w;
    acc[12] = q3.x; acc[13] = q3.y; acc[14] = q3.z; acc[15] = q3.w;
    acc = __builtin_amdgcn_mfma_f32_32x32x16_bf16(aj_h, bi_h, acc, 0, 0, 0);
    acc = __builtin_amdgcn_mfma_f32_32x32x16_bf16(aj_h, bi_m, acc, 0, 0, 0);
    acc = __builtin_amdgcn_mfma_f32_32x32x16_bf16(aj_m, bi_h, acc, 0, 0, 0);
    acc = __builtin_amdgcn_mfma_f32_32x32x16_bf16(aj_h, bi_l, acc, 0, 0, 0);
    acc = __builtin_amdgcn_mfma_f32_32x32x16_bf16(aj_l, bi_h, acc, 0, 0, 0);
    acc = __builtin_amdgcn_mfma_f32_32x32x16_bf16(aj_m, bi_m, acc, 0, 0, 0);
#pragma unroll
    for (int rr = 0; rr < 16; rr++) scv[rr] = acc[rr];
    if (j0 == i0w) {                       // wave-uniform: diagonal tile, mask self
#pragma unroll
        for (int rr = 0; rr < 16; rr++) {
            int r = (rr & 3) + 8 * (rr >> 2) + rbase;
            if (r == ln31) scv[rr] = -FLT_MAX;
        }
    }
}

// --- sorting-network primitives (compare-exchange = max/min pair: exact
// multiset preservation, fully unrolled constant indexing) ------------------
#define CEX(a, b) { float ce_hi = fmaxf(a, b), ce_lo = fminf(a, b); (a) = ce_hi; (b) = ce_lo; }
// Batcher odd-even mergesort, 8 values descending (19 CE)
__device__ __forceinline__ void sort8d(float v[8]) {
    CEX(v[0],v[1]); CEX(v[2],v[3]); CEX(v[4],v[5]); CEX(v[6],v[7]);
    CEX(v[0],v[2]); CEX(v[1],v[3]); CEX(v[4],v[6]); CEX(v[5],v[7]);
    CEX(v[1],v[2]); CEX(v[5],v[6]);
    CEX(v[0],v[4]); CEX(v[1],v[5]); CEX(v[2],v[6]); CEX(v[3],v[7]);
    CEX(v[2],v[4]); CEX(v[3],v[5]);
    CEX(v[1],v[2]); CEX(v[3],v[4]); CEX(v[5],v[6]);
}
// bitonic 8-sequence -> sorted descending (12 CE)
__device__ __forceinline__ void bsort8d(float v[8]) {
    CEX(v[0],v[4]); CEX(v[1],v[5]); CEX(v[2],v[6]); CEX(v[3],v[7]);
    CEX(v[0],v[2]); CEX(v[1],v[3]); CEX(v[4],v[6]); CEX(v[5],v[7]);
    CEX(v[0],v[1]); CEX(v[2],v[3]); CEX(v[4],v[5]); CEX(v[6],v[7]);
}

// --------- kNN scan, two-pass scores-only selection (validated R6/R7) --------
__global__ __attribute__((amdgpu_waves_per_eu(4, 4))) __launch_bounds__(256)
void k_scan(const ushort* __restrict__ hHi, const ushort* __restrict__ hMid,
            const ushort* __restrict__ hLo, const float* __restrict__ nsq,
            uint4* __restrict__ cand_i) {
    __shared__ unsigned lists[256][17];  // [tid][0..7]=A ids, [8..15]=B ids, [16]=trash
    __shared__ ushort outl[256][8];
    int tid = threadIdx.x, blk = blockIdx.x;
    int b  = blk >> 7;                   // 128 blocks per batch (32 ig x 4 sl)
    int ig = (blk >> 2) & 31;
    int sl = blk & 3;
    int wid = tid >> 6, lane = tid & 63;
    int ln31 = lane & 31, l5 = lane >> 5;
    int koff = l5 * 8;
    int i0w = ig * 128 + wid * 32;       // this wave's 32-aligned i-tile base
    int i   = i0w + ln31;
    long bN = (long)b * NN;
    int rbase = l5 * 4;
    int jbase = sl * 1024;

    bf16x8 bi_h = *(const bf16x8*)&hHi [(bN + i) * 16 + koff];
    bf16x8 bi_m = *(const bf16x8*)&hMid[(bN + i) * 16 + koff];
    bf16x8 bi_l = *(const bf16x8*)&hLo [(bN + i) * 16 + koff];

    // ---- pass 1: top-8 scores only (sorted descending invariant) ----
    float s[8];
#pragma unroll
    for (int k = 0; k < 8; k++) s[k] = -FLT_MAX;
#pragma unroll 2
    for (int t = 0; t < 32; t++) {
        int j0 = jbase + t * 32;
        float scv[16];
        tile_scores(hHi, hMid, hLo, nsq, bN, j0, ln31, koff, rbase, i0w,
                    bi_h, bi_m, bi_l, scv);
        float va[8] = { scv[0], scv[1], scv[2], scv[3], scv[4], scv[5], scv[6], scv[7] };
        float vb[8] = { scv[8], scv[9], scv[10], scv[11], scv[12], scv[13], scv[14], scv[15] };
        sort8d(va); sort8d(vb);
        float mg[8];
#pragma unroll
        for (int k = 0; k < 8; k++) mg[k] = fmaxf(va[k], vb[7 - k]);  // top-8 of 16, bitonic
        bsort8d(mg);
#pragma unroll
        for (int k = 0; k < 8; k++) s[k] = fmaxf(s[k], mg[7 - k]);    // top-8 of (s ∪ mg), bitonic
        bsort8d(s);
    }
    // pair-merge: top-8 of union(lane, lane^32) as a multiset; theta = its min.
    float mv[8];
#pragma unroll
    for (int k = 0; k < 8; k++) mv[k] = fmaxf(s[k], __shfl_xor(s[7 - k], 32));
    float theta = mv[0];
#pragma unroll
    for (int k = 1; k < 8; k++) theta = fminf(theta, mv[k]);

    // ---- pass 2: id recovery via bitmask + ffs ----
    unsigned* ldsw = &lists[0][0];
    int baseA = tid * 17, baseB = baseA + 8, trash = baseA + 16;
    int nA = 0, nB = 0;
#pragma unroll 2
    for (int t = 0; t < 32; t++) {
        int j0 = jbase + t * 32;
        float scv[16];
        tile_scores(hHi, hMid, hLo, nsq, bN, j0, ln31, koff, rbase, i0w,
                    bi_h, bi_m, bi_l, scv);
        unsigned gm = 0, em = 0;
#pragma unroll
        for (int rr = 0; rr < 16; rr++) {
            gm |= (scv[rr] >  theta) ? (1u << rr) : 0u;
            em |= (scv[rr] == theta) ? (1u << rr) : 0u;
        }
        unsigned m = gm | em;
        while (__any(m != 0u)) {
            if (m) {
                int rr = __ffs(m) - 1;
                m &= m - 1u;
                int r = (rr & 3) + ((rr >> 2) << 3) + rbase;
                int j = j0 + r;
                bool isGt = (gm >> rr) & 1u;
                bool cA = isGt && (nA < 8);   // <=7 by math; insurance
                bool cB = (!isGt) && (nB < 8);
                int ia = cA ? (baseA + nA) : (cB ? (baseB + nB) : trash);
                ldsw[ia] = (unsigned)j;       // single predicated write
                nA += cA;
                nB += cB;
            }
        }
    }
    int pA = __shfl_xor(nA, 32);
    int pB = __shfl_xor(nB, 32);
    __syncthreads();
    // ---- assembly (per column, lane<32): A ids + smallest-j ties to fill 8 ----
    if (lane < 32) {
        int tp = tid + 32;
        int n = 0;
        for (int k = 0; k < nA && n < 8; k++) outl[tid][n++] = (ushort)lists[tid][k];
        for (int k = 0; k < pA && n < 8; k++) outl[tid][n++] = (ushort)lists[tp][k];
        int p0 = 0, p1 = 0;
        while (n < 8) {                  // two-pointer merge of j-ascending tie lists
            unsigned a = (p0 < nB) ? lists[tid][8 + p0] : 0xFFFFFFFFu;
            unsigned c = (p1 < pB) ? lists[tp][8 + p1] : 0xFFFFFFFFu;
            bool t0 = a < c;
            outl[tid][n++] = (ushort)(t0 ? a : c);
            p0 += t0 ? 1 : 0; p1 += t0 ? 0 : 1;
        }
        uint4 pk = *(const uint4*)&outl[tid][0];
        cand_i[(long)(b * NSL + sl) * NN + i] = pk;
    }
}

// --- merge 4 slice-lists (recompute scores in exact fp32) + GAT -> p --------
// R8: 2 threads/node — lane l and l+32 of one wave each handle 2 slices
// (16 candidates, exact insertion top-8), then a shfl_xor(32) bitonic merge
// (max(L[k],R[7-k]) under (score desc, id asc) — same validated trick as
// k_scan's theta merge) yields the exact top-8 SET; half 0 runs the GAT.
// Halves the serial per-candidate chain and doubles waves (512 -> 1024).
// Neighbor accumulation order changes (set identical) — fp32 reorder class.
__launch_bounds__(64)
__global__ void k_gat2(const uint4* __restrict__ cand_i, const float* __restrict__ h,
                       const float* __restrict__ sq,
                       const float* __restrict__ xp, const float* __restrict__ asr,
                       const float* __restrict__ adt, const float* __restrict__ bg,
                       float* __restrict__ p) {
    int lane = threadIdx.x;                       // one wave per block
    int ln31 = lane & 31, half = lane >> 5;
    int t = blockIdx.x * 32 + ln31;               // node 0..32767
    int b = t >> 12, i = t & 4095;
    long bN = (long)b * NN;
    const float4* ip = (const float4*)&h[(bN + i) * 16];
    float4 r0 = ip[0], r1 = ip[1], r2 = ip[2], r3 = ip[3];
    float ni[16] = { r0.x,r0.y,r0.z,r0.w, r1.x,r1.y,r1.z,r1.w,
                     r2.x,r2.y,r2.z,r2.w, r3.x,r3.y,r3.z,r3.w };
    float fS[8]; int fI[8];
#pragma unroll
    for (int k = 0; k < 8; k++) { fS[k] = -FLT_MAX; fI[k] = 65535; }
#pragma unroll
    for (int ss = 0; ss < 2; ss++) {
        int sl = half * 2 + ss;
        uint4 pk = cand_i[(long)(b * NSL + sl) * NN + i];
        unsigned idx8[8] = { pk.x & 0xFFFF, pk.x >> 16, pk.y & 0xFFFF, pk.y >> 16,
                             pk.z & 0xFFFF, pk.z >> 16, pk.w & 0xFFFF, pk.w >> 16 };
#pragma unroll
        for (int k = 0; k < 8; k++) {
            int j = (int)idx8[k];
            const float4* np = (const float4*)&h[(bN + j) * 16];
            float4 a0 = np[0], a1 = np[1], a2 = np[2], a3 = np[3];
            float d = dot16m(ni, a0, a1, a2, a3, sq[bN + j]);
            bool bt = (d > fS[7]) || (d == fS[7] && j < fI[7]);
            if (bt) {
                fS[7] = d; fI[7] = j;
#pragma unroll
                for (int q = 7; q > 0; q--) {
                    bool sw = (fS[q] > fS[q - 1]) || (fS[q] == fS[q - 1] && fI[q] < fI[q - 1]);
                    if (sw) {
                        float td = fS[q]; fS[q] = fS[q - 1]; fS[q - 1] = td;
                        int tj = fI[q]; fI[q] = fI[q - 1]; fI[q - 1] = tj;
                    }
                }
            }
        }
    }
    // cross-half merge: exact top-8 of the 16 (both lists sorted by
    // (score desc, id asc); ids distinct across slices)
    float oS[8]; int oI[8];
#pragma unroll
    for (int k = 0; k < 8; k++) {
        oS[k] = __shfl_xor(fS[k], 32);
        oI[k] = __shfl_xor(fI[k], 32);
    }
    int mI[8];
#pragma unroll
    for (int k = 0; k < 8; k++) {
        bool mine = (fS[k] > oS[7 - k]) || (fS[k] == oS[7 - k] && fI[k] < oI[7 - k]);
        mI[k] = mine ? fI[k] : oI[7 - k];
    }
    if (half != 0) return;
    int nbrs[9];
#pragma unroll
    for (int e = 0; e < 8; e++) nbrs[e] = mI[e];
    nbrs[8] = i;                                   // self-loop
    float adtv[4];
#pragma unroll
    for (int hh = 0; hh < 4; hh++) adtv[hh] = adt[(bN + i) * 4 + hh];
    float mx[4] = { -FLT_MAX, -FLT_MAX, -FLT_MAX, -FLT_MAX };
    float lg[9][4];
#pragma unroll
    for (int e = 0; e < 9; e++) {
        long nb = bN + nbrs[e];
#pragma unroll
        for (int hh = 0; hh < 4; hh++) {
            float l = asr[nb * 4 + hh] + adtv[hh];
            l = (l > 0.f) ? l : 0.2f * l;          // leaky_relu 0.2
            lg[e][hh] = l;
            mx[hh] = fmaxf(mx[hh], l);
        }
    }
    float sum[4] = { 0, 0, 0, 0 };
    float acc[16];
#pragma unroll
    for (int c = 0; c < 16; c++) acc[c] = 0.f;
#pragma unroll
    for (int e = 0; e < 9; e++) {
        long nb = bN + nbrs[e];
        const float4* xpn = (const float4*)&xp[nb * 16];
        float4 x0 = xpn[0], x1 = xpn[1], x2 = xpn[2], x3 = xpn[3];
        float xv[16] = { x0.x,x0.y,x0.z,x0.w, x1.x,x1.y,x1.z,x1.w,
                         x2.x,x2.y,x2.z,x2.w, x3.x,x3.y,x3.z,x3.w };
        float wv[4];
#pragma unroll
        for (int hh = 0; hh < 4; hh++) {
            float w = expf(lg[e][hh] - mx[hh]);
            sum[hh] += w; wv[hh] = w;
        }
#pragma unroll
        for (int hh = 0; hh < 4; hh++)
#pragma unroll
            for (int f = 0; f < 4; f++)
                acc[hh * 4 + f] += wv[hh] * xv[hh * 4 + f];
    }
#pragma unroll
    for (int hh = 0; hh < 4; hh++) {
        float inv = 1.f / sum[hh];
#pragma unroll
        for (int f = 0; f < 4; f++) {
            float o = acc[hh * 4 + f] * inv + bg[hh * 4 + f];
            p[(bN + i) * 16 + hh * 4 + f] = fmaxf(o, 0.f);
        }
    }
}

// ------- 1x1 MLP 16->128->16, fire mask, h += mask*u, 1x1->1 + sigmoid ------
// R8: 4 threads/node (quarters of the 128-hd loop). Quarters 1-3 drop
// partials in LDS ([3][64][17], stride-17 -> 2-way bank aliasing = free),
// quarter 0 reduces + epilogue. 512 blocks x 256 thr = 2048 waves = 8/CU
// (was 4/CU with a 2400-inst serial chain). Partial-sum association changes
// (fp32 reorder class, same as conv2's R7 split).
__launch_bounds__(256)
__global__ void k_update(const float* __restrict__ p, const float* __restrict__ h,
                         const float* __restrict__ fire, const float* __restrict__ Wu1,
                         const float* __restrict__ bu1, const float* __restrict__ Wu2,
                         const float* __restrict__ bu2, const float* __restrict__ Wo,
                         const float* __restrict__ bo, float* __restrict__ out_low) {
    __shared__ float sU1[128 * 16];
    __shared__ float sU2t[128 * 16];      // [hd][c] = Wu2[c][hd]
    __shared__ float sb1[128];
    __shared__ float upart[3][64][17];
    int tid = threadIdx.x;
    for (int k = tid; k < 2048; k += 256) {
        sU1[k] = Wu1[k];
        sU2t[(k & 127) * 16 + (k >> 7)] = Wu2[k];   // coalesced read, scatter to LDS
    }
    if (tid < 128) sb1[tid] = bu1[tid];
    __syncthreads();
    int lnode = tid & 63, q = tid >> 6;   // wave-uniform q (lanes 0..63 = one wave)
    long n = (long)blockIdx.x * 64 + lnode;          // 0..32767
    const float4* pp = (const float4*)&p[n * 16];
    float4 p0 = pp[0], p1 = pp[1], p2 = pp[2], p3 = pp[3];
    float pv[16] = { p0.x,p0.y,p0.z,p0.w, p1.x,p1.y,p1.z,p1.w,
                     p2.x,p2.y,p2.z,p2.w, p3.x,p3.y,p3.z,p3.w };
    float u[16];
#pragma unroll
    for (int c = 0; c < 16; c++) u[c] = 0.f;
    int hd0 = q * 32;
    for (int hd = hd0; hd < hd0 + 32; hd++) {        // sU1/sU2t reads: wave-uniform
        const float4* r = (const float4*)&sU1[hd * 16];   // addr -> LDS broadcast, free
        float4 r0 = r[0], r1 = r[1], r2 = r[2], r3 = r[3];
        float a = sb1[hd]
            + r0.x*pv[0] + r0.y*pv[1] + r0.z*pv[2] + r0.w*pv[3]
            + r1.x*pv[4] + r1.y*pv[5] + r1.z*pv[6] + r1.w*pv[7]
            + r2.x*pv[8] + r2.y*pv[9] + r2.z*pv[10]+ r2.w*pv[11]
            + r3.x*pv[12]+ r3.y*pv[13]+ r3.z*pv[14]+ r3.w*pv[15];
        a = fmaxf(a, 0.f);
        const float4* tt = (const float4*)&sU2t[hd * 16];
        float4 t0 = tt[0], t1 = tt[1], t2 = tt[2], t3 = tt[3];
        u[0] += t0.x*a; u[1] += t0.y*a; u[2] += t0.z*a; u[3] += t0.w*a;
        u[4] += t1.x*a; u[5] += t1.y*a; u[6] += t1.z*a; u[7] += t1.w*a;
        u[8] += t2.x*a; u[9] += t2.y*a; u[10]+= t2.z*a; u[11]+= t2.w*a;
        u[12]+= t3.x*a; u[13]+= t3.y*a; u[14]+= t3.z*a; u[15]+= t3.w*a;
    }
    if (q != 0) {
        float* dst = &upart[q - 1][lnode][0];
#pragma unroll
        for (int c = 0; c < 16; c++) dst[c] = u[c];
    }
    __syncthreads();
    if (q != 0) return;
#pragma unroll
    for (int qq = 0; qq < 3; qq++) {
        const float* src = &upart[qq][lnode][0];
#pragma unroll
        for (int c = 0; c < 16; c++) u[c] += src[c];
    }
    float mask = (fire[n] < 0.5f) ? 1.f : 0.f;
    const float4* hp = (const float4*)&h[n * 16];
    float4 h0 = hp[0], h1v = hp[1], h2 = hp[2], h3 = hp[3];
    float hv[16] = { h0.x,h0.y,h0.z,h0.w, h1v.x,h1v.y,h1v.z,h1v.w,
                     h2.x,h2.y,h2.z,h2.w, h3.x,h3.y,h3.z,h3.w };
    float o = bo[0];
#pragma unroll
    for (int c = 0; c < 16; c++)
        o += Wo[c] * (hv[c] + mask * (u[c] + bu2[c]));
    out_low[n] = 1.f / (1.f + expf(-o));
}

// ---------------- bilinear upsample 64 -> 256 (half-pixel, clamp) -----------
__global__ void k_up(const float* __restrict__ ol, float* __restrict__ out) {
    int t = blockIdx.x * 256 + threadIdx.x;
    if (t >= BATCH * HIGH * HIGH) return;
    int b = t >> 16, oy = (t >> 8) & 255, ox = t & 255;
    float cy = (oy + 0.5f) * 0.25f - 0.5f;
    float cx = (ox + 0.5f) * 0.25f - 0.5f;
    int iy0 = (int)floorf(cy); float fy = cy - (float)iy0;
    int ix0 = (int)floorf(cx); float fx = cx - (float)ix0;
    int y0 = min(max(iy0, 0), 63), y1 = min(max(iy0 + 1, 0), 63);
    int x0 = min(max(ix0, 0), 63), x1 = min(max(ix0 + 1, 0), 63);
    const float* s = ol + b * NN;
    float v = (1.f - fy) * ((1.f - fx) * s[y0 * 64 + x0] + fx * s[y0 * 64 + x1])
            + fy * ((1.f - fx) * s[y1 * 64 + x0] + fx * s[y1 * 64 + x1]);
    out[t] = v;
}

extern "C" void kernel_launch(void* const* d_in, const int* in_sizes, int n_in,
                              void* d_out, int out_size, void* d_ws, size_t ws_size,
                              hipStream_t stream) {
    const float* x    = (const float*)d_in[0];
    const float* fire = (const float*)d_in[1];
    const float* W1   = (const float*)d_in[2];
    const float* b1   = (const float*)d_in[3];
    const float* g1   = (const float*)d_in[4];
    const float* be1  = (const float*)d_in[5];
    const float* m1   = (const float*)d_in[6];
    const float* v1   = (const float*)d_in[7];
    const float* W2   = (const float*)d_in[8];
    const float* b2   = (const float*)d_in[9];
    const float* g2   = (const float*)d_in[10];
    const float* be2  = (const float*)d_in[11];
    const float* m2   = (const float*)d_in[12];
    const float* v2   = (const float*)d_in[13];
    const float* Wg   = (const float*)d_in[14];
    const float* a_src= (const float*)d_in[15];
    const float* a_dst= (const float*)d_in[16];
    const float* bg   = (const float*)d_in[17];
    const float* Wu1  = (const float*)d_in[18];
    const float* bu1  = (const float*)d_in[19];
    const float* Wu2  = (const float*)d_in[20];
    const float* bu2  = (const float*)d_in[21];
    const float* Wo   = (const float*)d_in[22];
    const float* bo   = (const float*)d_in[23];

    float* ws  = (float*)d_ws;
    float* xl  = ws + OFF_XL;
    float* h1  = ws + OFF_H1;
    float* h   = ws + OFF_H;
    float* sq  = ws + OFF_SQ;
    float* xp  = ws + OFF_XP;
    float* asr = ws + OFF_ASR;
    float* adt = ws + OFF_ADT;
    float* p   = ws + OFF_P;
    float* ol  = ws + OFF_OL;
    // H1 region reuse (dead after conv2): cand_i 2 MB (NSL=4), bf16 splits,
    // nsq. Total 1,867,776 of 2,097,152 floats — no footprint growth.
    uint4*  cand_i = (uint4*)(ws + OFF_H1);
    ushort* hHi    = (ushort*)(ws + OFF_H1 + 1048576);
    ushort* hMid   = (ushort*)(ws + OFF_H1 + 1310720);
    ushort* hLo    = (ushort*)(ws + OFF_H1 + 1572864);
    float*  nsq    = ws + OFF_H1 + 1835008;

    k_down  <<<(BATCH * NN + 127) / 128, 128, 0, stream>>>(x, xl);
    k_conv1 <<<(BATCH * C1 * NN) / 256, 256, 0, stream>>>(xl, W1, b1, g1, be1, m1, v1, h1);
    k_conv2 <<<BATCH * 32, 512, 0, stream>>>(h1, W2, b2, g2, be2, m2, v2, Wg, a_src, a_dst,
                                             h, sq, xp, asr, adt);
    k_split <<<BATCH * NN / 64, 64, 0, stream>>>(h, sq, hHi, hMid, hLo, nsq);
    k_scan  <<<BATCH * 32 * NSL, 256, 0, stream>>>(hHi, hMid, hLo, nsq, cand_i);
    k_gat2  <<<BATCH * NN / 32, 64, 0, stream>>>(cand_i, h, sq, xp, asr, adt, bg, p);
    k_update<<<BATCH * NN / 64, 256, 0, stream>>>(p, h, fire, Wu1, bu1, Wu2, bu2, Wo, bo, ol);
    k_up    <<<(BATCH * HIGH * HIGH) / 256, 256, 0, stream>>>(ol, (float*)d_out);
}

// Round 9
// 277.062 us; speedup vs baseline: 1.5838x; 1.0059x over previous
//
#include <hip/hip_runtime.h>
#include <math.h>
#include <float.h>

#define BATCH 8
#define HIGH  256
#define LOWR  64
#define NN    4096          // LOWR*LOWR
#define HIDC  16
#define C1    64
#define NSL   8             // j-slices in kNN scan (512 j each)

// workspace layout (floats) — footprint identical to the validated layout
#define OFF_XL   0
#define OFF_H1   (OFF_XL  + BATCH*NN)            // 2.097M floats; reused after conv2:
                                                 //   [0 .. 1,048,575]         cand_i (4 MB, NSL=8)
                                                 //   [1,048,576 .. 1,835,007] bf16 hi/mid/lo splits
                                                 //   [1,835,008 .. 1,867,775] nsq (= -sq)
#define OFF_H    (OFF_H1  + BATCH*C1*NN)         // node-major [B*N][16]
#define OFF_SQ   (OFF_H   + BATCH*NN*HIDC)       // 0.5*|h|^2 per node
#define OFF_XP   (OFF_SQ  + BATCH*NN)
#define OFF_ASR  (OFF_XP  + BATCH*NN*HIDC)
#define OFF_ADT  (OFF_ASR + BATCH*NN*4)
#define OFF_P    (OFF_ADT + BATCH*NN*4)
#define OFF_OL   (OFF_P   + BATCH*NN*HIDC)

typedef __attribute__((ext_vector_type(8)))  short bf16x8;
typedef __attribute__((ext_vector_type(16))) float f32x16;

// identical-arithmetic dot used by k_gat2 (exact fp32 re-score of the pool —
// final selection semantics unchanged from the validated kernel)
__device__ __forceinline__ float dot16m(const float ni[16], float4 a0, float4 a1,
                                        float4 a2, float4 a3, float hs) {
    return ni[0]*a0.x + ni[1]*a0.y + ni[2]*a0.z + ni[3]*a0.w
         + ni[4]*a1.x + ni[5]*a1.y + ni[6]*a1.z + ni[7]*a1.w
         + ni[8]*a2.x + ni[9]*a2.y + ni[10]*a2.z + ni[11]*a2.w
         + ni[12]*a3.x + ni[13]*a3.y + ni[14]*a3.z + ni[15]*a3.w
         - hs;
}

// ---------------- bilinear downsample 256 -> 64 (antialiased triangle) -------
__global__ void k_down(const float* __restrict__ x, float* __restrict__ xl) {
    int t = blockIdx.x * 128 + threadIdx.x;
    if (t >= BATCH * NN) return;
    int b = t >> 12, oy = (t >> 6) & 63, ox = t & 63;
    const float* xb = x + b * HIGH * HIGH;
    float cy = 4.f * oy + 1.5f, cx = 4.f * ox + 1.5f;
    float wy[8], wx[8], sy = 0.f, sx = 0.f;
#pragma unroll
    for (int k = 0; k < 8; k++) {
        int iy = 4 * oy - 2 + k;
        float w = 1.f - fabsf((float)iy - cy) * 0.25f;
        if (iy < 0 || iy >= HIGH) w = 0.f;
        wy[k] = w; sy += w;
        int ix = 4 * ox - 2 + k;
        float v = 1.f - fabsf((float)ix - cx) * 0.25f;
        if (ix < 0 || ix >= HIGH) v = 0.f;
        wx[k] = v; sx += v;
    }
    float acc = 0.f;
#pragma unroll
    for (int ky = 0; ky < 8; ky++) {
        if (wy[ky] == 0.f) continue;
        int iy = 4 * oy - 2 + ky;
        float rowacc = 0.f;
#pragma unroll
        for (int kx = 0; kx < 8; kx++) {
            if (wx[kx] == 0.f) continue;
            int ix = 4 * ox - 2 + kx;
            rowacc += wx[kx] * xb[iy * HIGH + ix];
        }
        acc += wy[ky] * rowacc;
    }
    xl[t] = acc / (sy * sx);
}

// ---------------- conv3x3 1->64 + BN + relu ---------------------------------
__global__ void k_conv1(const float* __restrict__ xl, const float* __restrict__ W1,
                        const float* __restrict__ b1, const float* __restrict__ g1,
                        const float* __restrict__ be1, const float* __restrict__ m1,
                        const float* __restrict__ v1, float* __restrict__ h1) {
    int t = blockIdx.x * 256 + threadIdx.x;
    if (t >= BATCH * C1 * NN) return;
    int b = t >> 18, co = (t >> 12) & 63, y = (t >> 6) & 63, x = t & 63;
    const float* src = xl + b * NN;
    const float* w = W1 + co * 9;
    float acc = 0.f;
#pragma unroll
    for (int dy = -1; dy <= 1; dy++) {
        int yy = y + dy; if (yy < 0 || yy >= 64) continue;
#pragma unroll
        for (int dx = -1; dx <= 1; dx++) {
            int xx = x + dx; if (xx < 0 || xx >= 64) continue;
            acc += w[(dy + 1) * 3 + (dx + 1)] * src[yy * 64 + xx];
        }
    }
    acc += b1[co];
    float sc = g1[co] / sqrtf(v1[co] + 1e-5f);
    acc = (acc - m1[co]) * sc + be1[co];
    h1[t] = fmaxf(acc, 0.f);
}

// ------- conv3x3 64->16 + BN + relu, fused: h (node-major), sq, xp, asr, adt -
// 512 threads, 4-way ci-split (16 ci per thread) -> 8 waves/CU on all 4
// SIMDs. Quarters 1-3 write partials to LDS, quarter 0 reduces + epilogue.
__launch_bounds__(512)
__global__ void k_conv2(const float* __restrict__ h1, const float* __restrict__ W2,
                        const float* __restrict__ b2, const float* __restrict__ g2,
                        const float* __restrict__ be2, const float* __restrict__ m2,
                        const float* __restrict__ v2, const float* __restrict__ Wg,
                        const float* __restrict__ a_src, const float* __restrict__ a_dst,
                        float* __restrict__ h, float* __restrict__ sq,
                        float* __restrict__ xp, float* __restrict__ asr,
                        float* __restrict__ adt) {
    __shared__ float sW2t[576 * 16];    // [ci*9+tap][o]
    __shared__ float sWg[256];
    __shared__ float sA[32];
    __shared__ float accH[3][128][17];  // partials from quarters 1..3 (17-pad)
    int tid = threadIdx.x;
    for (int k = tid; k < 9216; k += 512) {          // coalesced global read, scatter to LDS
        int o = k / 576, ct = k - o * 576;
        sW2t[ct * 16 + o] = W2[k];
    }
    if (tid < 256) sWg[tid] = Wg[tid];
    if (tid < 16) { sA[tid] = a_src[tid]; sA[16 + tid] = a_dst[tid]; }
    __syncthreads();
    int blk = blockIdx.x;                 // 8 batches * 32 y-tiles
    int b = blk >> 5, ytile = blk & 31;
    int q = tid >> 7;                     // ci quarter 0..3
    int sub = tid & 127;
    int ty = sub >> 6, x = sub & 63, y = ytile * 2 + ty;
    float acc[16];
#pragma unroll
    for (int o = 0; o < 16; o++) acc[o] = 0.f;
    const float* hb = h1 + (long)b * C1 * NN + (long)q * 16 * NN;
    for (int ci = 0; ci < 16; ci++) {
        const float* plane = hb + ci * NN;
#pragma unroll
        for (int dy = -1; dy <= 1; dy++) {
            int yy = y + dy; bool oky = (yy >= 0 && yy < 64);
#pragma unroll
            for (int dx = -1; dx <= 1; dx++) {
                int xx = x + dx;
                float v = (oky && xx >= 0 && xx < 64) ? plane[yy * 64 + xx] : 0.f;
                int ct = (q * 16 + ci) * 9 + (dy + 1) * 3 + (dx + 1);
                const float4* wr = (const float4*)&sW2t[ct * 16];
                float4 w0 = wr[0], w1 = wr[1], w2 = wr[2], w3 = wr[3];
                acc[0] += v * w0.x; acc[1] += v * w0.y; acc[2] += v * w0.z; acc[3] += v * w0.w;
                acc[4] += v * w1.x; acc[5] += v * w1.y; acc[6] += v * w1.z; acc[7] += v * w1.w;
                acc[8] += v * w2.x; acc[9] += v * w2.y; acc[10]+= v * w2.z; acc[11]+= v * w2.w;
                acc[12]+= v * w3.x; acc[13]+= v * w3.y; acc[14]+= v * w3.z; acc[15]+= v * w3.w;
            }
        }
    }
    if (q != 0) {
        float* dst = &accH[q - 1][sub][0];
#pragma unroll
        for (int o = 0; o < 16; o++) dst[o] = acc[o];
    }
    __syncthreads();
    if (q != 0) return;
#pragma unroll
    for (int qq = 0; qq < 3; qq++) {
        const float* src = &accH[qq][sub][0];
#pragma unroll
        for (int o = 0; o < 16; o++) acc[o] += src[o];
    }
    int n = y * 64 + x;
    long node = (long)b * NN + n;
    float nodev[16], sqv = 0.f;
#pragma unroll
    for (int o = 0; o < 16; o++) {
        float a = acc[o] + b2[o];
        float sc = g2[o] / sqrtf(v2[o] + 1e-5f);
        a = (a - m2[o]) * sc + be2[o];
        a = fmaxf(a, 0.f);
        nodev[o] = a; sqv += a * a;
        h[node * 16 + o] = a;
    }
    sq[node] = 0.5f * sqv;                // pre-scaled: scan/merge use dot - 0.5|j|^2
    float xpv[16];
#pragma unroll
    for (int o = 0; o < 16; o++) {
        float a = 0.f;
#pragma unroll
        for (int c = 0; c < 16; c++) a += sWg[o * 16 + c] * nodev[c];
        xpv[o] = a;
        xp[node * 16 + o] = a;
    }
#pragma unroll
    for (int hh = 0; hh < 4; hh++) {
        float as = 0.f, ad = 0.f;
#pragma unroll
        for (int f = 0; f < 4; f++) {
            as += xpv[hh * 4 + f] * sA[hh * 4 + f];
            ad += xpv[hh * 4 + f] * sA[16 + hh * 4 + f];
        }
        asr[node * 4 + hh] = as;
        adt[node * 4 + hh] = ad;
    }
}

// ------- error-free 3-way bf16 split of h: h = hi + mid + lo + O(2^-27) -----
__device__ __forceinline__ ushort f2bf(float f) {
    unsigned u = __float_as_uint(f);
    return (ushort)((u + 0x7FFFu + ((u >> 16) & 1u)) >> 16);
}
__device__ __forceinline__ float bf2f(ushort h) {
    return __uint_as_float(((unsigned)h) << 16);
}
__global__ void k_split(const float* __restrict__ h, const float* __restrict__ sq,
                        ushort* __restrict__ hHi, ushort* __restrict__ hMid,
                        ushort* __restrict__ hLo, float* __restrict__ nsq) {
    long t = (long)blockIdx.x * 64 + threadIdx.x;    // node 0..32767
    nsq[t] = -sq[t];                                  // negated for MFMA C-init
    const float4* hp = (const float4*)&h[t * 16];
    float4 v0 = hp[0], v1 = hp[1], v2 = hp[2], v3 = hp[3];
    float v[16] = { v0.x,v0.y,v0.z,v0.w, v1.x,v1.y,v1.z,v1.w,
                    v2.x,v2.y,v2.z,v2.w, v3.x,v3.y,v3.z,v3.w };
    unsigned wh[8], wm[8], wl[8];
#pragma unroll
    for (int p = 0; p < 8; p++) {
        unsigned packh = 0, packm = 0, packl = 0;
#pragma unroll
        for (int e = 0; e < 2; e++) {
            float f = v[p * 2 + e];
            ushort hi = f2bf(f);
            float t1 = f - bf2f(hi);
            ushort mi = f2bf(t1);
            float t2 = t1 - bf2f(mi);
            ushort lo = f2bf(t2);
            packh |= ((unsigned)hi) << (16 * e);
            packm |= ((unsigned)mi) << (16 * e);
            packl |= ((unsigned)lo) << (16 * e);
        }
        wh[p] = packh; wm[p] = packm; wl[p] = packl;
    }
    uint4* dh = (uint4*)&hHi[t * 16];
    uint4* dm = (uint4*)&hMid[t * 16];
    uint4* dl = (uint4*)&hLo[t * 16];
    dh[0] = make_uint4(wh[0], wh[1], wh[2], wh[3]);
    dh[1] = make_uint4(wh[4], wh[5], wh[6], wh[7]);
    dm[0] = make_uint4(wm[0], wm[1], wm[2], wm[3]);
    dm[1] = make_uint4(wm[4], wm[5], wm[6], wm[7]);
    dl[0] = make_uint4(wl[0], wl[1], wl[2], wl[3]);
    dl[1] = make_uint4(wl[4], wl[5], wl[6], wl[7]);
}

// --- shared tile-score routine: MUST be bit-identical between pass 1/2 ------
__device__ __forceinline__ void tile_scores(const ushort* __restrict__ hHi,
        const ushort* __restrict__ hMid, const ushort* __restrict__ hLo,
        const float* __restrict__ nsq, long bN, int j0, int ln31, int koff,
        int rbase, int i0w, bf16x8 bi_h, bf16x8 bi_m, bf16x8 bi_l,
        float scv[16]) {
    int jr = j0 + ln31;
    bf16x8 aj_h = *(const bf16x8*)&hHi [(bN + jr) * 16 + koff];
    bf16x8 aj_m = *(const bf16x8*)&hMid[(bN + jr) * 16 + koff];
    bf16x8 aj_l = *(const bf16x8*)&hLo [(bN + jr) * 16 + koff];
    float4 q0 = *(const float4*)&nsq[bN + j0 +  0 + rbase];
    float4 q1 = *(const float4*)&nsq[bN + j0 +  8 + rbase];
    float4 q2 = *(const float4*)&nsq[bN + j0 + 16 + rbase];
    float4 q3 = *(const float4*)&nsq[bN + j0 + 24 + rbase];
    f32x16 acc;
    acc[0]  = q0.x; acc[1]  = q0.y; acc[2]  = q0.z; acc[3]  = q0.w;
    acc[4]  = q1.x; acc[5]  = q1.y; acc[6]  = q1.z; acc[7]  = q1.w;
    acc[8]  = q2.x; acc[9]  = q2.y; acc[10] = q2.z; acc[11] = q2.w;
    acc[12] = q3.x; acc[13] = q3.y; acc[14] = q3.z; acc[15] = q3.w;
    acc = __builtin_amdgcn_mfma_f32_32x32x16_bf16(aj_h, bi_h, acc, 0, 0, 0);
    acc = __builtin_amdgcn_mfma_f32_32x32x16_bf16(aj_h, bi_m, acc, 0, 0, 0);
    acc = __builtin_amdgcn_mfma_f32_32x32x16_bf16(aj_m, bi_h, acc, 0, 0, 0);
    acc = __builtin_amdgcn_mfma_f32_32x32x16_bf16(aj_h, bi_l, acc, 0, 0, 0);
    acc = __builtin_amdgcn_mfma_f32_32x32x16_bf16(aj_l, bi_h, acc, 0, 0, 0);
    acc = __builtin_amdgcn_mfma_f32_32x32x16_bf16(aj_m, bi_m, acc, 0, 0, 0);
#pragma unroll
    for (int rr = 0; rr < 16; rr++) scv[rr] = acc[rr];
    if (j0 == i0w) {                       // wave-uniform: diagonal tile, mask self
#pragma unroll
        for (int rr = 0; rr < 16; rr++) {
            int r = (rr & 3) + 8 * (rr >> 2) + rbase;
            if (r == ln31) scv[rr] = -FLT_MAX;
        }
    }
}

// --- sorting-network primitives (compare-exchange = max/min pair: exact
// multiset preservation, fully unrolled constant indexing) ------------------
#define CEX(a, b) { float ce_hi = fmaxf(a, b), ce_lo = fminf(a, b); (a) = ce_hi; (b) = ce_lo; }
// Batcher odd-even mergesort, 8 values descending (19 CE)
__device__ __forceinline__ void sort8d(float v[8]) {
    CEX(v[0],v[1]); CEX(v[2],v[3]); CEX(v[4],v[5]); CEX(v[6],v[7]);
    CEX(v[0],v[2]); CEX(v[1],v[3]); CEX(v[4],v[6]); CEX(v[5],v[7]);
    CEX(v[1],v[2]); CEX(v[5],v[6]);
    CEX(v[0],v[4]); CEX(v[1],v[5]); CEX(v[2],v[6]); CEX(v[3],v[7]);
    CEX(v[2],v[4]); CEX(v[3],v[5]);
    CEX(v[1],v[2]); CEX(v[3],v[4]); CEX(v[5],v[6]);
}
// bitonic 8-sequence -> sorted descending (12 CE)
__device__ __forceinline__ void bsort8d(float v[8]) {
    CEX(v[0],v[4]); CEX(v[1],v[5]); CEX(v[2],v[6]); CEX(v[3],v[7]);
    CEX(v[0],v[2]); CEX(v[1],v[3]); CEX(v[4],v[6]); CEX(v[5],v[7]);
    CEX(v[0],v[1]); CEX(v[2],v[3]); CEX(v[4],v[5]); CEX(v[6],v[7]);
}
// compare-exchange with carried id under (score desc, id asc) total order
#define CEX2(sa, ia, sb, ib) { \
    bool sw2 = ((sb) > (sa)) || ((sb) == (sa) && (ib) < (ia)); \
    float th2 = sw2 ? (sb) : (sa); float tl2 = sw2 ? (sa) : (sb); \
    int   ih2 = sw2 ? (ib) : (ia); int   il2 = sw2 ? (ia) : (ib); \
    (sa) = th2; (sb) = tl2; (ia) = ih2; (ib) = il2; }
// bitonic 8 -> sorted by (score desc, id asc), ids carried (12 CE2)
__device__ __forceinline__ void bsort8d_id(float v[8], int id[8]) {
    CEX2(v[0],id[0],v[4],id[4]); CEX2(v[1],id[1],v[5],id[5]);
    CEX2(v[2],id[2],v[6],id[6]); CEX2(v[3],id[3],v[7],id[7]);
    CEX2(v[0],id[0],v[2],id[2]); CEX2(v[1],id[1],v[3],id[3]);
    CEX2(v[4],id[4],v[6],id[6]); CEX2(v[5],id[5],v[7],id[7]);
    CEX2(v[0],id[0],v[1],id[1]); CEX2(v[2],id[2],v[3],id[3]);
    CEX2(v[4],id[4],v[5],id[5]); CEX2(v[6],id[6],v[7],id[7]);
}

// --------- kNN scan, two-pass scores-only selection (validated R6-R8) --------
// R9: NSL 4->8 (512-j slices): grid 1024->2048 blocks = 8 blocks/CU; ushort
// id-lists shrink LDS 21.5->13.3 KB/block so 8 blocks fit -> 8 waves/SIMD
// (was pinned 4). Same total instructions, double the latency-hiding pool.
__global__ __attribute__((amdgpu_waves_per_eu(4, 8))) __launch_bounds__(256)
void k_scan(const ushort* __restrict__ hHi, const ushort* __restrict__ hMid,
            const ushort* __restrict__ hLo, const float* __restrict__ nsq,
            uint4* __restrict__ cand_i) {
    __shared__ ushort lists[256][18];    // [tid][0..7]=A ids, [8..15]=B ids, [16]=trash, [17]=pad
    __shared__ ushort outl[256][8];
    int tid = threadIdx.x, blk = blockIdx.x;
    int b  = blk >> 8;                   // 256 blocks per batch (32 ig x 8 sl)
    int ig = (blk >> 3) & 31;
    int sl = blk & 7;
    int wid = tid >> 6, lane = tid & 63;
    int ln31 = lane & 31, l5 = lane >> 5;
    int koff = l5 * 8;
    int i0w = ig * 128 + wid * 32;       // this wave's 32-aligned i-tile base
    int i   = i0w + ln31;
    long bN = (long)b * NN;
    int rbase = l5 * 4;
    int jbase = sl * 512;

    bf16x8 bi_h = *(const bf16x8*)&hHi [(bN + i) * 16 + koff];
    bf16x8 bi_m = *(const bf16x8*)&hMid[(bN + i) * 16 + koff];
    bf16x8 bi_l = *(const bf16x8*)&hLo [(bN + i) * 16 + koff];

    // ---- pass 1: top-8 scores only (sorted descending invariant) ----
    float s[8];
#pragma unroll
    for (int k = 0; k < 8; k++) s[k] = -FLT_MAX;
#pragma unroll 2
    for (int t = 0; t < 16; t++) {
        int j0 = jbase + t * 32;
        float scv[16];
        tile_scores(hHi, hMid, hLo, nsq, bN, j0, ln31, koff, rbase, i0w,
                    bi_h, bi_m, bi_l, scv);
        float va[8] = { scv[0], scv[1], scv[2], scv[3], scv[4], scv[5], scv[6], scv[7] };
        float vb[8] = { scv[8], scv[9], scv[10], scv[11], scv[12], scv[13], scv[14], scv[15] };
        sort8d(va); sort8d(vb);
        float mg[8];
#pragma unroll
        for (int k = 0; k < 8; k++) mg[k] = fmaxf(va[k], vb[7 - k]);  // top-8 of 16, bitonic
        bsort8d(mg);
#pragma unroll
        for (int k = 0; k < 8; k++) s[k] = fmaxf(s[k], mg[7 - k]);    // top-8 of (s ∪ mg), bitonic
        bsort8d(s);
    }
    // pair-merge: top-8 of union(lane, lane^32) as a multiset; theta = its min.
    float mv[8];
#pragma unroll
    for (int k = 0; k < 8; k++) mv[k] = fmaxf(s[k], __shfl_xor(s[7 - k], 32));
    float theta = mv[0];
#pragma unroll
    for (int k = 1; k < 8; k++) theta = fminf(theta, mv[k]);

    // ---- pass 2: id recovery via bitmask + ffs ----
    ushort* ldsw = &lists[0][0];
    int baseA = tid * 18, baseB = baseA + 8, trash = baseA + 16;
    int nA = 0, nB = 0;
#pragma unroll 2
    for (int t = 0; t < 16; t++) {
        int j0 = jbase + t * 32;
        float scv[16];
        tile_scores(hHi, hMid, hLo, nsq, bN, j0, ln31, koff, rbase, i0w,
                    bi_h, bi_m, bi_l, scv);
        unsigned gm = 0, em = 0;
#pragma unroll
        for (int rr = 0; rr < 16; rr++) {
            gm |= (scv[rr] >  theta) ? (1u << rr) : 0u;
            em |= (scv[rr] == theta) ? (1u << rr) : 0u;
        }
        unsigned m = gm | em;
        while (__any(m != 0u)) {
            if (m) {
                int rr = __ffs(m) - 1;
                m &= m - 1u;
                int r = (rr & 3) + ((rr >> 2) << 3) + rbase;
                int j = j0 + r;
                bool isGt = (gm >> rr) & 1u;
                bool cA = isGt && (nA < 8);   // <=7 by math; insurance
                bool cB = (!isGt) && (nB < 8);
                int ia = cA ? (baseA + nA) : (cB ? (baseB + nB) : trash);
                ldsw[ia] = (ushort)j;         // single predicated write
                nA += cA;
                nB += cB;
            }
        }
    }
    int pA = __shfl_xor(nA, 32);
    int pB = __shfl_xor(nB, 32);
    __syncthreads();
    // ---- assembly (per column, lane<32): A ids + smallest-j ties to fill 8 ----
    if (lane < 32) {
        int tp = tid + 32;
        int n = 0;
        for (int k = 0; k < nA && n < 8; k++) outl[tid][n++] = lists[tid][k];
        for (int k = 0; k < pA && n < 8; k++) outl[tid][n++] = lists[tp][k];
        int p0 = 0, p1 = 0;
        while (n < 8) {                  // two-pointer merge of j-ascending tie lists
            unsigned a = (p0 < nB) ? (unsigned)lists[tid][8 + p0] : 0xFFFFFFFFu;
            unsigned c = (p1 < pB) ? (unsigned)lists[tp][8 + p1] : 0xFFFFFFFFu;
            bool t0 = a < c;
            outl[tid][n++] = (ushort)(t0 ? a : c);
            p0 += t0 ? 1 : 0; p1 += t0 ? 0 : 1;
        }
        uint4 pk = *(const uint4*)&outl[tid][0];
        cand_i[(long)(b * NSL + sl) * NN + i] = pk;
    }
}

// --- merge 8 slice-lists (recompute scores in exact fp32) + GAT -> p --------
// R9: 4 threads/node (quarters q=0..3, lanes ln15 / ln15+16 / +32 / +48 of
// one wave). Each quarter: 2 slices = 16 candidates, exact insertion top-8
// sorted by (score desc, id asc). Two-level shfl_xor(16)/(32) bitonic
// max-merge with carried ids (ids distinct across slices) -> exact top-8 of
// the 64-candidate pool under the reference total order. Quarter 0 runs GAT.
// 131072 threads = 2048 waves = 8 waves/CU (was 4) for gather-latency hiding.
__launch_bounds__(64)
__global__ void k_gat2(const uint4* __restrict__ cand_i, const float* __restrict__ h,
                       const float* __restrict__ sq,
                       const float* __restrict__ xp, const float* __restrict__ asr,
                       const float* __restrict__ adt, const float* __restrict__ bg,
                       float* __restrict__ p) {
    int lane = threadIdx.x;                       // one wave per block
    int ln15 = lane & 15, q = lane >> 4;
    int t = blockIdx.x * 16 + ln15;               // node 0..32767
    int b = t >> 12, i = t & 4095;
    long bN = (long)b * NN;
    const float4* ip = (const float4*)&h[(bN + i) * 16];
    float4 r0 = ip[0], r1 = ip[1], r2 = ip[2], r3 = ip[3];
    float ni[16] = { r0.x,r0.y,r0.z,r0.w, r1.x,r1.y,r1.z,r1.w,
                     r2.x,r2.y,r2.z,r2.w, r3.x,r3.y,r3.z,r3.w };
    float fS[8]; int fI[8];
#pragma unroll
    for (int k = 0; k < 8; k++) { fS[k] = -FLT_MAX; fI[k] = 65535; }
#pragma unroll
    for (int ss = 0; ss < 2; ss++) {
        int sl = q * 2 + ss;
        uint4 pk = cand_i[(long)(b * NSL + sl) * NN + i];
        unsigned idx8[8] = { pk.x & 0xFFFF, pk.x >> 16, pk.y & 0xFFFF, pk.y >> 16,
                             pk.z & 0xFFFF, pk.z >> 16, pk.w & 0xFFFF, pk.w >> 16 };
#pragma unroll
        for (int k = 0; k < 8; k++) {
            int j = (int)idx8[k];
            const float4* np = (const float4*)&h[(bN + j) * 16];
            float4 a0 = np[0], a1 = np[1], a2 = np[2], a3 = np[3];
            float d = dot16m(ni, a0, a1, a2, a3, sq[bN + j]);
            bool bt = (d > fS[7]) || (d == fS[7] && j < fI[7]);
            if (bt) {
                fS[7] = d; fI[7] = j;
#pragma unroll
                for (int qq = 7; qq > 0; qq--) {
                    bool sw = (fS[qq] > fS[qq - 1]) || (fS[qq] == fS[qq - 1] && fI[qq] < fI[qq - 1]);
                    if (sw) {
                        float td = fS[qq]; fS[qq] = fS[qq - 1]; fS[qq - 1] = td;
                        int tj = fI[qq]; fI[qq] = fI[qq - 1]; fI[qq - 1] = tj;
                    }
                }
            }
        }
    }
    // level 1: merge quarter pairs (0<->1, 2<->3) — top-8 of 32, then re-sort
    float oS[8]; int oI[8];
#pragma unroll
    for (int k = 0; k < 8; k++) {
        oS[k] = __shfl_xor(fS[k], 16);
        oI[k] = __shfl_xor(fI[k], 16);
    }
    float mS[8]; int mI[8];
#pragma unroll
    for (int k = 0; k < 8; k++) {
        bool mine = (fS[k] > oS[7 - k]) || (fS[k] == oS[7 - k] && fI[k] < oI[7 - k]);
        mS[k] = mine ? fS[k] : oS[7 - k];
        mI[k] = mine ? fI[k] : oI[7 - k];
    }
    bsort8d_id(mS, mI);
    // level 2: merge across (01)<->(23) — top-8 of 64
#pragma unroll
    for (int k = 0; k < 8; k++) {
        oS[k] = __shfl_xor(mS[k], 32);
        oI[k] = __shfl_xor(mI[k], 32);
    }
    int nI[8];
#pragma unroll
    for (int k = 0; k < 8; k++) {
        bool mine = (mS[k] > oS[7 - k]) || (mS[k] == oS[7 - k] && mI[k] < oI[7 - k]);
        nI[k] = mine ? mI[k] : oI[7 - k];
    }
    if (q != 0) return;
    int nbrs[9];
#pragma unroll
    for (int e = 0; e < 8; e++) nbrs[e] = nI[e];
    nbrs[8] = i;                                   // self-loop
    float adtv[4];
#pragma unroll
    for (int hh = 0; hh < 4; hh++) adtv[hh] = adt[(bN + i) * 4 + hh];
    float mx[4] = { -FLT_MAX, -FLT_MAX, -FLT_MAX, -FLT_MAX };
    float lg[9][4];
#pragma unroll
    for (int e = 0; e < 9; e++) {
        long nb = bN + nbrs[e];
#pragma unroll
        for (int hh = 0; hh < 4; hh++) {
            float l = asr[nb * 4 + hh] + adtv[hh];
            l = (l > 0.f) ? l : 0.2f * l;          // leaky_relu 0.2
            lg[e][hh] = l;
            mx[hh] = fmaxf(mx[hh], l);
        }
    }
    float sum[4] = { 0, 0, 0, 0 };
    float acc[16];
#pragma unroll
    for (int c = 0; c < 16; c++) acc[c] = 0.f;
#pragma unroll
    for (int e = 0; e < 9; e++) {
        long nb = bN + nbrs[e];
        const float4* xpn = (const float4*)&xp[nb * 16];
        float4 x0 = xpn[0], x1 = xpn[1], x2 = xpn[2], x3 = xpn[3];
        float xv[16] = { x0.x,x0.y,x0.z,x0.w, x1.x,x1.y,x1.z,x1.w,
                         x2.x,x2.y,x2.z,x2.w, x3.x,x3.y,x3.z,x3.w };
        float wv[4];
#pragma unroll
        for (int hh = 0; hh < 4; hh++) {
            float w = expf(lg[e][hh] - mx[hh]);
            sum[hh] += w; wv[hh] = w;
        }
#pragma unroll
        for (int hh = 0; hh < 4; hh++)
#pragma unroll
            for (int f = 0; f < 4; f++)
                acc[hh * 4 + f] += wv[hh] * xv[hh * 4 + f];
    }
#pragma unroll
    for (int hh = 0; hh < 4; hh++) {
        float inv = 1.f / sum[hh];
#pragma unroll
        for (int f = 0; f < 4; f++) {
            float o = acc[hh * 4 + f] * inv + bg[hh * 4 + f];
            p[(bN + i) * 16 + hh * 4 + f] = fmaxf(o, 0.f);
        }
    }
}

// ------- 1x1 MLP 16->128->16, fire mask, h += mask*u, 1x1->1 + sigmoid ------
// 4 threads/node (quarters of the 128-hd loop); quarters 1-3 partials in LDS,
// quarter 0 reduces + epilogue. 8 waves/CU.
__launch_bounds__(256)
__global__ void k_update(const float* __restrict__ p, const float* __restrict__ h,
                         const float* __restrict__ fire, const float* __restrict__ Wu1,
                         const float* __restrict__ bu1, const float* __restrict__ Wu2,
                         const float* __restrict__ bu2, const float* __restrict__ Wo,
                         const float* __restrict__ bo, float* __restrict__ out_low) {
    __shared__ float sU1[128 * 16];
    __shared__ float sU2t[128 * 16];      // [hd][c] = Wu2[c][hd]
    __shared__ float sb1[128];
    __shared__ float upart[3][64][17];
    int tid = threadIdx.x;
    for (int k = tid; k < 2048; k += 256) {
        sU1[k] = Wu1[k];
        sU2t[(k & 127) * 16 + (k >> 7)] = Wu2[k];   // coalesced read, scatter to LDS
    }
    if (tid < 128) sb1[tid] = bu1[tid];
    __syncthreads();
    int lnode = tid & 63, q = tid >> 6;   // wave-uniform q (lanes 0..63 = one wave)
    long n = (long)blockIdx.x * 64 + lnode;          // 0..32767
    const float4* pp = (const float4*)&p[n * 16];
    float4 p0 = pp[0], p1 = pp[1], p2 = pp[2], p3 = pp[3];
    float pv[16] = { p0.x,p0.y,p0.z,p0.w, p1.x,p1.y,p1.z,p1.w,
                     p2.x,p2.y,p2.z,p2.w, p3.x,p3.y,p3.z,p3.w };
    float u[16];
#pragma unroll
    for (int c = 0; c < 16; c++) u[c] = 0.f;
    int hd0 = q * 32;
    for (int hd = hd0; hd < hd0 + 32; hd++) {        // sU1/sU2t reads: wave-uniform
        const float4* r = (const float4*)&sU1[hd * 16];   // addr -> LDS broadcast, free
        float4 r0 = r[0], r1 = r[1], r2 = r[2], r3 = r[3];
        float a = sb1[hd]
            + r0.x*pv[0] + r0.y*pv[1] + r0.z*pv[2] + r0.w*pv[3]
            + r1.x*pv[4] + r1.y*pv[5] + r1.z*pv[6] + r1.w*pv[7]
            + r2.x*pv[8] + r2.y*pv[9] + r2.z*pv[10]+ r2.w*pv[11]
            + r3.x*pv[12]+ r3.y*pv[13]+ r3.z*pv[14]+ r3.w*pv[15];
        a = fmaxf(a, 0.f);
        const float4* tt = (const float4*)&sU2t[hd * 16];
        float4 t0 = tt[0], t1 = tt[1], t2 = tt[2], t3 = tt[3];
        u[0] += t0.x*a; u[1] += t0.y*a; u[2] += t0.z*a; u[3] += t0.w*a;
        u[4] += t1.x*a; u[5] += t1.y*a; u[6] += t1.z*a; u[7] += t1.w*a;
        u[8] += t2.x*a; u[9] += t2.y*a; u[10]+= t2.z*a; u[11]+= t2.w*a;
        u[12]+= t3.x*a; u[13]+= t3.y*a; u[14]+= t3.z*a; u[15]+= t3.w*a;
    }
    if (q != 0) {
        float* dst = &upart[q - 1][lnode][0];
#pragma unroll
        for (int c = 0; c < 16; c++) dst[c] = u[c];
    }
    __syncthreads();
    if (q != 0) return;
#pragma unroll
    for (int qq = 0; qq < 3; qq++) {
        const float* src = &upart[qq][lnode][0];
#pragma unroll
        for (int c = 0; c < 16; c++) u[c] += src[c];
    }
    float mask = (fire[n] < 0.5f) ? 1.f : 0.f;
    const float4* hp = (const float4*)&h[n * 16];
    float4 h0 = hp[0], h1v = hp[1], h2 = hp[2], h3 = hp[3];
    float hv[16] = { h0.x,h0.y,h0.z,h0.w, h1v.x,h1v.y,h1v.z,h1v.w,
                     h2.x,h2.y,h2.z,h2.w, h3.x,h3.y,h3.z,h3.w };
    float o = bo[0];
#pragma unroll
    for (int c = 0; c < 16; c++)
        o += Wo[c] * (hv[c] + mask * (u[c] + bu2[c]));
    out_low[n] = 1.f / (1.f + expf(-o));
}

// ---------------- bilinear upsample 64 -> 256 (half-pixel, clamp) -----------
__global__ void k_up(const float* __restrict__ ol, float* __restrict__ out) {
    int t = blockIdx.x * 256 + threadIdx.x;
    if (t >= BATCH * HIGH * HIGH) return;
    int b = t >> 16, oy = (t >> 8) & 255, ox = t & 255;
    float cy = (oy + 0.5f) * 0.25f - 0.5f;
    float cx = (ox + 0.5f) * 0.25f - 0.5f;
    int iy0 = (int)floorf(cy); float fy = cy - (float)iy0;
    int ix0 = (int)floorf(cx); float fx = cx - (float)ix0;
    int y0 = min(max(iy0, 0), 63), y1 = min(max(iy0 + 1, 0), 63);
    int x0 = min(max(ix0, 0), 63), x1 = min(max(ix0 + 1, 0), 63);
    const float* s = ol + b * NN;
    float v = (1.f - fy) * ((1.f - fx) * s[y0 * 64 + x0] + fx * s[y0 * 64 + x1])
            + fy * ((1.f - fx) * s[y1 * 64 + x0] + fx * s[y1 * 64 + x1]);
    out[t] = v;
}

extern "C" void kernel_launch(void* const* d_in, const int* in_sizes, int n_in,
                              void* d_out, int out_size, void* d_ws, size_t ws_size,
                              hipStream_t stream) {
    const float* x    = (const float*)d_in[0];
    const float* fire = (const float*)d_in[1];
    const float* W1   = (const float*)d_in[2];
    const float* b1   = (const float*)d_in[3];
    const float* g1   = (const float*)d_in[4];
    const float* be1  = (const float*)d_in[5];
    const float* m1   = (const float*)d_in[6];
    const float* v1   = (const float*)d_in[7];
    const float* W2   = (const float*)d_in[8];
    const float* b2   = (const float*)d_in[9];
    const float* g2   = (const float*)d_in[10];
    const float* be2  = (const float*)d_in[11];
    const float* m2   = (const float*)d_in[12];
    const float* v2   = (const float*)d_in[13];
    const float* Wg   = (const float*)d_in[14];
    const float* a_src= (const float*)d_in[15];
    const float* a_dst= (const float*)d_in[16];
    const float* bg   = (const float*)d_in[17];
    const float* Wu1  = (const float*)d_in[18];
    const float* bu1  = (const float*)d_in[19];
    const float* Wu2  = (const float*)d_in[20];
    const float* bu2  = (const float*)d_in[21];
    const float* Wo   = (const float*)d_in[22];
    const float* bo   = (const float*)d_in[23];

    float* ws  = (float*)d_ws;
    float* xl  = ws + OFF_XL;
    float* h1  = ws + OFF_H1;
    float* h   = ws + OFF_H;
    float* sq  = ws + OFF_SQ;
    float* xp  = ws + OFF_XP;
    float* asr = ws + OFF_ASR;
    float* adt = ws + OFF_ADT;
    float* p   = ws + OFF_P;
    float* ol  = ws + OFF_OL;
    // H1 region reuse (dead after conv2): cand_i 4 MB (NSL=8), bf16 splits,
    // nsq. Total 1,867,776 of 2,097,152 floats — no footprint growth.
    uint4*  cand_i = (uint4*)(ws + OFF_H1);
    ushort* hHi    = (ushort*)(ws + OFF_H1 + 1048576);
    ushort* hMid   = (ushort*)(ws + OFF_H1 + 1310720);
    ushort* hLo    = (ushort*)(ws + OFF_H1 + 1572864);
    float*  nsq    = ws + OFF_H1 + 1835008;

    k_down  <<<(BATCH * NN + 127) / 128, 128, 0, stream>>>(x, xl);
    k_conv1 <<<(BATCH * C1 * NN) / 256, 256, 0, stream>>>(xl, W1, b1, g1, be1, m1, v1, h1);
    k_conv2 <<<BATCH * 32, 512, 0, stream>>>(h1, W2, b2, g2, be2, m2, v2, Wg, a_src, a_dst,
                                             h, sq, xp, asr, adt);
    k_split <<<BATCH * NN / 64, 64, 0, stream>>>(h, sq, hHi, hMid, hLo, nsq);
    k_scan  <<<BATCH * 32 * NSL, 256, 0, stream>>>(hHi, hMid, hLo, nsq, cand_i);
    k_gat2  <<<BATCH * NN / 16, 64, 0, stream>>>(cand_i, h, sq, xp, asr, adt, bg, p);
    k_update<<<BATCH * NN / 64, 256, 0, stream>>>(p, h, fire, Wu1, bu1, Wu2, bu2, Wo, bo, ol);
    k_up    <<<(BATCH * HIGH * HIGH) / 256, 256, 0, stream>>>(ol, (float*)d_out);
}

// Round 10
// 271.194 us; speedup vs baseline: 1.6180x; 1.0216x over previous
//
#include <hip/hip_runtime.h>
#include <math.h>
#include <float.h>

#define BATCH 8
#define HIGH  256
#define LOWR  64
#define NN    4096          // LOWR*LOWR
#define HIDC  16
#define C1    64
#define NSL   8             // j-slices in kNN scan (512 j each)

// workspace layout (floats) — footprint identical to the validated layout
#define OFF_XL   0
#define OFF_H1   (OFF_XL  + BATCH*NN)            // 2.097M floats; reused after conv2:
                                                 //   [0 .. 1,048,575]         cand_i (4 MB, NSL=8)
                                                 //   [1,048,576 .. 1,835,007] bf16 hi/mid/lo splits
                                                 //   [1,835,008 .. 1,867,775] nsq (= -sq)
#define OFF_H    (OFF_H1  + BATCH*C1*NN)         // node-major [B*N][16]
#define OFF_SQ   (OFF_H   + BATCH*NN*HIDC)       // 0.5*|h|^2 per node
#define OFF_XP   (OFF_SQ  + BATCH*NN)
#define OFF_ASR  (OFF_XP  + BATCH*NN*HIDC)
#define OFF_ADT  (OFF_ASR + BATCH*NN*4)
#define OFF_P    (OFF_ADT + BATCH*NN*4)          // DEAD after R10 (update fused into gat2)
#define OFF_OL   (OFF_P   + BATCH*NN*HIDC)

typedef __attribute__((ext_vector_type(8)))  short bf16x8;
typedef __attribute__((ext_vector_type(16))) float f32x16;

// identical-arithmetic dot used by k_gat2 (exact fp32 re-score of the pool —
// final selection semantics unchanged from the validated kernel)
__device__ __forceinline__ float dot16m(const float ni[16], float4 a0, float4 a1,
                                        float4 a2, float4 a3, float hs) {
    return ni[0]*a0.x + ni[1]*a0.y + ni[2]*a0.z + ni[3]*a0.w
         + ni[4]*a1.x + ni[5]*a1.y + ni[6]*a1.z + ni[7]*a1.w
         + ni[8]*a2.x + ni[9]*a2.y + ni[10]*a2.z + ni[11]*a2.w
         + ni[12]*a3.x + ni[13]*a3.y + ni[14]*a3.z + ni[15]*a3.w
         - hs;
}

// ---------------- bilinear downsample 256 -> 64 (antialiased triangle) -------
__global__ void k_down(const float* __restrict__ x, float* __restrict__ xl) {
    int t = blockIdx.x * 128 + threadIdx.x;
    if (t >= BATCH * NN) return;
    int b = t >> 12, oy = (t >> 6) & 63, ox = t & 63;
    const float* xb = x + b * HIGH * HIGH;
    float cy = 4.f * oy + 1.5f, cx = 4.f * ox + 1.5f;
    float wy[8], wx[8], sy = 0.f, sx = 0.f;
#pragma unroll
    for (int k = 0; k < 8; k++) {
        int iy = 4 * oy - 2 + k;
        float w = 1.f - fabsf((float)iy - cy) * 0.25f;
        if (iy < 0 || iy >= HIGH) w = 0.f;
        wy[k] = w; sy += w;
        int ix = 4 * ox - 2 + k;
        float v = 1.f - fabsf((float)ix - cx) * 0.25f;
        if (ix < 0 || ix >= HIGH) v = 0.f;
        wx[k] = v; sx += v;
    }
    float acc = 0.f;
#pragma unroll
    for (int ky = 0; ky < 8; ky++) {
        if (wy[ky] == 0.f) continue;
        int iy = 4 * oy - 2 + ky;
        float rowacc = 0.f;
#pragma unroll
        for (int kx = 0; kx < 8; kx++) {
            if (wx[kx] == 0.f) continue;
            int ix = 4 * ox - 2 + kx;
            rowacc += wx[kx] * xb[iy * HIGH + ix];
        }
        acc += wy[ky] * rowacc;
    }
    xl[t] = acc / (sy * sx);
}

// ---------------- conv3x3 1->64 + BN + relu ---------------------------------
__global__ void k_conv1(const float* __restrict__ xl, const float* __restrict__ W1,
                        const float* __restrict__ b1, const float* __restrict__ g1,
                        const float* __restrict__ be1, const float* __restrict__ m1,
                        const float* __restrict__ v1, float* __restrict__ h1) {
    int t = blockIdx.x * 256 + threadIdx.x;
    if (t >= BATCH * C1 * NN) return;
    int b = t >> 18, co = (t >> 12) & 63, y = (t >> 6) & 63, x = t & 63;
    const float* src = xl + b * NN;
    const float* w = W1 + co * 9;
    float acc = 0.f;
#pragma unroll
    for (int dy = -1; dy <= 1; dy++) {
        int yy = y + dy; if (yy < 0 || yy >= 64) continue;
#pragma unroll
        for (int dx = -1; dx <= 1; dx++) {
            int xx = x + dx; if (xx < 0 || xx >= 64) continue;
            acc += w[(dy + 1) * 3 + (dx + 1)] * src[yy * 64 + xx];
        }
    }
    acc += b1[co];
    float sc = g1[co] / sqrtf(v1[co] + 1e-5f);
    acc = (acc - m1[co]) * sc + be1[co];
    h1[t] = fmaxf(acc, 0.f);
}

// ------- conv3x3 64->16 + BN + relu, fused: h (node-major), sq, xp, asr, adt -
// 512 threads, 4-way ci-split (16 ci per thread) -> 8 waves/CU on all 4
// SIMDs. Quarters 1-3 write partials to LDS, quarter 0 reduces + epilogue.
__launch_bounds__(512)
__global__ void k_conv2(const float* __restrict__ h1, const float* __restrict__ W2,
                        const float* __restrict__ b2, const float* __restrict__ g2,
                        const float* __restrict__ be2, const float* __restrict__ m2,
                        const float* __restrict__ v2, const float* __restrict__ Wg,
                        const float* __restrict__ a_src, const float* __restrict__ a_dst,
                        float* __restrict__ h, float* __restrict__ sq,
                        float* __restrict__ xp, float* __restrict__ asr,
                        float* __restrict__ adt) {
    __shared__ float sW2t[576 * 16];    // [ci*9+tap][o]
    __shared__ float sWg[256];
    __shared__ float sA[32];
    __shared__ float accH[3][128][17];  // partials from quarters 1..3 (17-pad)
    int tid = threadIdx.x;
    for (int k = tid; k < 9216; k += 512) {          // coalesced global read, scatter to LDS
        int o = k / 576, ct = k - o * 576;
        sW2t[ct * 16 + o] = W2[k];
    }
    if (tid < 256) sWg[tid] = Wg[tid];
    if (tid < 16) { sA[tid] = a_src[tid]; sA[16 + tid] = a_dst[tid]; }
    __syncthreads();
    int blk = blockIdx.x;                 // 8 batches * 32 y-tiles
    int b = blk >> 5, ytile = blk & 31;
    int q = tid >> 7;                     // ci quarter 0..3
    int sub = tid & 127;
    int ty = sub >> 6, x = sub & 63, y = ytile * 2 + ty;
    float acc[16];
#pragma unroll
    for (int o = 0; o < 16; o++) acc[o] = 0.f;
    const float* hb = h1 + (long)b * C1 * NN + (long)q * 16 * NN;
    for (int ci = 0; ci < 16; ci++) {
        const float* plane = hb + ci * NN;
#pragma unroll
        for (int dy = -1; dy <= 1; dy++) {
            int yy = y + dy; bool oky = (yy >= 0 && yy < 64);
#pragma unroll
            for (int dx = -1; dx <= 1; dx++) {
                int xx = x + dx;
                float v = (oky && xx >= 0 && xx < 64) ? plane[yy * 64 + xx] : 0.f;
                int ct = (q * 16 + ci) * 9 + (dy + 1) * 3 + (dx + 1);
                const float4* wr = (const float4*)&sW2t[ct * 16];
                float4 w0 = wr[0], w1 = wr[1], w2 = wr[2], w3 = wr[3];
                acc[0] += v * w0.x; acc[1] += v * w0.y; acc[2] += v * w0.z; acc[3] += v * w0.w;
                acc[4] += v * w1.x; acc[5] += v * w1.y; acc[6] += v * w1.z; acc[7] += v * w1.w;
                acc[8] += v * w2.x; acc[9] += v * w2.y; acc[10]+= v * w2.z; acc[11]+= v * w2.w;
                acc[12]+= v * w3.x; acc[13]+= v * w3.y; acc[14]+= v * w3.z; acc[15]+= v * w3.w;
            }
        }
    }
    if (q != 0) {
        float* dst = &accH[q - 1][sub][0];
#pragma unroll
        for (int o = 0; o < 16; o++) dst[o] = acc[o];
    }
    __syncthreads();
    if (q != 0) return;
#pragma unroll
    for (int qq = 0; qq < 3; qq++) {
        const float* src = &accH[qq][sub][0];
#pragma unroll
        for (int o = 0; o < 16; o++) acc[o] += src[o];
    }
    int n = y * 64 + x;
    long node = (long)b * NN + n;
    float nodev[16], sqv = 0.f;
#pragma unroll
    for (int o = 0; o < 16; o++) {
        float a = acc[o] + b2[o];
        float sc = g2[o] / sqrtf(v2[o] + 1e-5f);
        a = (a - m2[o]) * sc + be2[o];
        a = fmaxf(a, 0.f);
        nodev[o] = a; sqv += a * a;
        h[node * 16 + o] = a;
    }
    sq[node] = 0.5f * sqv;                // pre-scaled: scan/merge use dot - 0.5|j|^2
    float xpv[16];
#pragma unroll
    for (int o = 0; o < 16; o++) {
        float a = 0.f;
#pragma unroll
        for (int c = 0; c < 16; c++) a += sWg[o * 16 + c] * nodev[c];
        xpv[o] = a;
        xp[node * 16 + o] = a;
    }
#pragma unroll
    for (int hh = 0; hh < 4; hh++) {
        float as = 0.f, ad = 0.f;
#pragma unroll
        for (int f = 0; f < 4; f++) {
            as += xpv[hh * 4 + f] * sA[hh * 4 + f];
            ad += xpv[hh * 4 + f] * sA[16 + hh * 4 + f];
        }
        asr[node * 4 + hh] = as;
        adt[node * 4 + hh] = ad;
    }
}

// ------- error-free 3-way bf16 split of h: h = hi + mid + lo + O(2^-27) -----
__device__ __forceinline__ ushort f2bf(float f) {
    unsigned u = __float_as_uint(f);
    return (ushort)((u + 0x7FFFu + ((u >> 16) & 1u)) >> 16);
}
__device__ __forceinline__ float bf2f(ushort h) {
    return __uint_as_float(((unsigned)h) << 16);
}
__global__ void k_split(const float* __restrict__ h, const float* __restrict__ sq,
                        ushort* __restrict__ hHi, ushort* __restrict__ hMid,
                        ushort* __restrict__ hLo, float* __restrict__ nsq) {
    long t = (long)blockIdx.x * 64 + threadIdx.x;    // node 0..32767
    nsq[t] = -sq[t];                                  // negated for MFMA C-init
    const float4* hp = (const float4*)&h[t * 16];
    float4 v0 = hp[0], v1 = hp[1], v2 = hp[2], v3 = hp[3];
    float v[16] = { v0.x,v0.y,v0.z,v0.w, v1.x,v1.y,v1.z,v1.w,
                    v2.x,v2.y,v2.z,v2.w, v3.x,v3.y,v3.z,v3.w };
    unsigned wh[8], wm[8], wl[8];
#pragma unroll
    for (int p = 0; p < 8; p++) {
        unsigned packh = 0, packm = 0, packl = 0;
#pragma unroll
        for (int e = 0; e < 2; e++) {
            float f = v[p * 2 + e];
            ushort hi = f2bf(f);
            float t1 = f - bf2f(hi);
            ushort mi = f2bf(t1);
            float t2 = t1 - bf2f(mi);
            ushort lo = f2bf(t2);
            packh |= ((unsigned)hi) << (16 * e);
            packm |= ((unsigned)mi) << (16 * e);
            packl |= ((unsigned)lo) << (16 * e);
        }
        wh[p] = packh; wm[p] = packm; wl[p] = packl;
    }
    uint4* dh = (uint4*)&hHi[t * 16];
    uint4* dm = (uint4*)&hMid[t * 16];
    uint4* dl = (uint4*)&hLo[t * 16];
    dh[0] = make_uint4(wh[0], wh[1], wh[2], wh[3]);
    dh[1] = make_uint4(wh[4], wh[5], wh[6], wh[7]);
    dm[0] = make_uint4(wm[0], wm[1], wm[2], wm[3]);
    dm[1] = make_uint4(wm[4], wm[5], wm[6], wm[7]);
    dl[0] = make_uint4(wl[0], wl[1], wl[2], wl[3]);
    dl[1] = make_uint4(wl[4], wl[5], wl[6], wl[7]);
}

// --- shared tile-score routine: MUST be bit-identical between pass 1/2 ------
__device__ __forceinline__ void tile_scores(const ushort* __restrict__ hHi,
        const ushort* __restrict__ hMid, const ushort* __restrict__ hLo,
        const float* __restrict__ nsq, long bN, int j0, int ln31, int koff,
        int rbase, int i0w, bf16x8 bi_h, bf16x8 bi_m, bf16x8 bi_l,
        float scv[16]) {
    int jr = j0 + ln31;
    bf16x8 aj_h = *(const bf16x8*)&hHi [(bN + jr) * 16 + koff];
    bf16x8 aj_m = *(const bf16x8*)&hMid[(bN + jr) * 16 + koff];
    bf16x8 aj_l = *(const bf16x8*)&hLo [(bN + jr) * 16 + koff];
    float4 q0 = *(const float4*)&nsq[bN + j0 +  0 + rbase];
    float4 q1 = *(const float4*)&nsq[bN + j0 +  8 + rbase];
    float4 q2 = *(const float4*)&nsq[bN + j0 + 16 + rbase];
    float4 q3 = *(const float4*)&nsq[bN + j0 + 24 + rbase];
    f32x16 acc;
    acc[0]  = q0.x; acc[1]  = q0.y; acc[2]  = q0.z; acc[3]  = q0.w;
    acc[4]  = q1.x; acc[5]  = q1.y; acc[6]  = q1.z; acc[7]  = q1.w;
    acc[8]  = q2.x; acc[9]  = q2.y; acc[10] = q2.z; acc[11] = q2.w;
    acc[12] = q3.x; acc[13] = q3.y; acc[14] = q3.z; acc[15] = q3.w;
    acc = __builtin_amdgcn_mfma_f32_32x32x16_bf16(aj_h, bi_h, acc, 0, 0, 0);
    acc = __builtin_amdgcn_mfma_f32_32x32x16_bf16(aj_h, bi_m, acc, 0, 0, 0);
    acc = __builtin_amdgcn_mfma_f32_32x32x16_bf16(aj_m, bi_h, acc, 0, 0, 0);
    acc = __builtin_amdgcn_mfma_f32_32x32x16_bf16(aj_h, bi_l, acc, 0, 0, 0);
    acc = __builtin_amdgcn_mfma_f32_32x32x16_bf16(aj_l, bi_h, acc, 0, 0, 0);
    acc = __builtin_amdgcn_mfma_f32_32x32x16_bf16(aj_m, bi_m, acc, 0, 0, 0);
#pragma unroll
    for (int rr = 0; rr < 16; rr++) scv[rr] = acc[rr];
    if (j0 == i0w) {                       // wave-uniform: diagonal tile, mask self
#pragma unroll
        for (int rr = 0; rr < 16; rr++) {
            int r = (rr & 3) + 8 * (rr >> 2) + rbase;
            if (r == ln31) scv[rr] = -FLT_MAX;
        }
    }
}

// --- sorting-network primitives (compare-exchange = max/min pair: exact
// multiset preservation, fully unrolled constant indexing) ------------------
#define CEX(a, b) { float ce_hi = fmaxf(a, b), ce_lo = fminf(a, b); (a) = ce_hi; (b) = ce_lo; }
// Batcher odd-even mergesort, 8 values descending (19 CE)
__device__ __forceinline__ void sort8d(float v[8]) {
    CEX(v[0],v[1]); CEX(v[2],v[3]); CEX(v[4],v[5]); CEX(v[6],v[7]);
    CEX(v[0],v[2]); CEX(v[1],v[3]); CEX(v[4],v[6]); CEX(v[5],v[7]);
    CEX(v[1],v[2]); CEX(v[5],v[6]);
    CEX(v[0],v[4]); CEX(v[1],v[5]); CEX(v[2],v[6]); CEX(v[3],v[7]);
    CEX(v[2],v[4]); CEX(v[3],v[5]);
    CEX(v[1],v[2]); CEX(v[3],v[4]); CEX(v[5],v[6]);
}
// bitonic 8-sequence -> sorted descending (12 CE)
__device__ __forceinline__ void bsort8d(float v[8]) {
    CEX(v[0],v[4]); CEX(v[1],v[5]); CEX(v[2],v[6]); CEX(v[3],v[7]);
    CEX(v[0],v[2]); CEX(v[1],v[3]); CEX(v[4],v[6]); CEX(v[5],v[7]);
    CEX(v[0],v[1]); CEX(v[2],v[3]); CEX(v[4],v[5]); CEX(v[6],v[7]);
}
// compare-exchange with carried id under (score desc, id asc) total order
#define CEX2(sa, ia, sb, ib) { \
    bool sw2 = ((sb) > (sa)) || ((sb) == (sa) && (ib) < (ia)); \
    float th2 = sw2 ? (sb) : (sa); float tl2 = sw2 ? (sa) : (sb); \
    int   ih2 = sw2 ? (ib) : (ia); int   il2 = sw2 ? (ia) : (ib); \
    (sa) = th2; (sb) = tl2; (ia) = ih2; (ib) = il2; }
// bitonic 8 -> sorted by (score desc, id asc), ids carried (12 CE2)
__device__ __forceinline__ void bsort8d_id(float v[8], int id[8]) {
    CEX2(v[0],id[0],v[4],id[4]); CEX2(v[1],id[1],v[5],id[5]);
    CEX2(v[2],id[2],v[6],id[6]); CEX2(v[3],id[3],v[7],id[7]);
    CEX2(v[0],id[0],v[2],id[2]); CEX2(v[1],id[1],v[3],id[3]);
    CEX2(v[4],id[4],v[6],id[6]); CEX2(v[5],id[5],v[7],id[7]);
    CEX2(v[0],id[0],v[1],id[1]); CEX2(v[2],id[2],v[3],id[3]);
    CEX2(v[4],id[4],v[5],id[5]); CEX2(v[6],id[6],v[7],id[7]);
}

// --------- kNN scan, two-pass scores-only selection (validated R6-R9) --------
// At structural floor per R9 falsifier: 89% pipe-busy, selection networks at
// the CE lower bound, occupancy lever exhausted. NOT touched in R10.
__global__ __attribute__((amdgpu_waves_per_eu(4, 8))) __launch_bounds__(256)
void k_scan(const ushort* __restrict__ hHi, const ushort* __restrict__ hMid,
            const ushort* __restrict__ hLo, const float* __restrict__ nsq,
            uint4* __restrict__ cand_i) {
    __shared__ ushort lists[256][18];    // [tid][0..7]=A ids, [8..15]=B ids, [16]=trash, [17]=pad
    __shared__ ushort outl[256][8];
    int tid = threadIdx.x, blk = blockIdx.x;
    int b  = blk >> 8;                   // 256 blocks per batch (32 ig x 8 sl)
    int ig = (blk >> 3) & 31;
    int sl = blk & 7;
    int wid = tid >> 6, lane = tid & 63;
    int ln31 = lane & 31, l5 = lane >> 5;
    int koff = l5 * 8;
    int i0w = ig * 128 + wid * 32;       // this wave's 32-aligned i-tile base
    int i   = i0w + ln31;
    long bN = (long)b * NN;
    int rbase = l5 * 4;
    int jbase = sl * 512;

    bf16x8 bi_h = *(const bf16x8*)&hHi [(bN + i) * 16 + koff];
    bf16x8 bi_m = *(const bf16x8*)&hMid[(bN + i) * 16 + koff];
    bf16x8 bi_l = *(const bf16x8*)&hLo [(bN + i) * 16 + koff];

    // ---- pass 1: top-8 scores only (sorted descending invariant) ----
    float s[8];
#pragma unroll
    for (int k = 0; k < 8; k++) s[k] = -FLT_MAX;
#pragma unroll 2
    for (int t = 0; t < 16; t++) {
        int j0 = jbase + t * 32;
        float scv[16];
        tile_scores(hHi, hMid, hLo, nsq, bN, j0, ln31, koff, rbase, i0w,
                    bi_h, bi_m, bi_l, scv);
        float va[8] = { scv[0], scv[1], scv[2], scv[3], scv[4], scv[5], scv[6], scv[7] };
        float vb[8] = { scv[8], scv[9], scv[10], scv[11], scv[12], scv[13], scv[14], scv[15] };
        sort8d(va); sort8d(vb);
        float mg[8];
#pragma unroll
        for (int k = 0; k < 8; k++) mg[k] = fmaxf(va[k], vb[7 - k]);  // top-8 of 16, bitonic
        bsort8d(mg);
#pragma unroll
        for (int k = 0; k < 8; k++) s[k] = fmaxf(s[k], mg[7 - k]);    // top-8 of (s ∪ mg), bitonic
        bsort8d(s);
    }
    // pair-merge: top-8 of union(lane, lane^32) as a multiset; theta = its min.
    float mv[8];
#pragma unroll
    for (int k = 0; k < 8; k++) mv[k] = fmaxf(s[k], __shfl_xor(s[7 - k], 32));
    float theta = mv[0];
#pragma unroll
    for (int k = 1; k < 8; k++) theta = fminf(theta, mv[k]);

    // ---- pass 2: id recovery via bitmask + ffs ----
    ushort* ldsw = &lists[0][0];
    int baseA = tid * 18, baseB = baseA + 8, trash = baseA + 16;
    int nA = 0, nB = 0;
#pragma unroll 2
    for (int t = 0; t < 16; t++) {
        int j0 = jbase + t * 32;
        float scv[16];
        tile_scores(hHi, hMid, hLo, nsq, bN, j0, ln31, koff, rbase, i0w,
                    bi_h, bi_m, bi_l, scv);
        unsigned gm = 0, em = 0;
#pragma unroll
        for (int rr = 0; rr < 16; rr++) {
            gm |= (scv[rr] >  theta) ? (1u << rr) : 0u;
            em |= (scv[rr] == theta) ? (1u << rr) : 0u;
        }
        unsigned m = gm | em;
        while (__any(m != 0u)) {
            if (m) {
                int rr = __ffs(m) - 1;
                m &= m - 1u;
                int r = (rr & 3) + ((rr >> 2) << 3) + rbase;
                int j = j0 + r;
                bool isGt = (gm >> rr) & 1u;
                bool cA = isGt && (nA < 8);   // <=7 by math; insurance
                bool cB = (!isGt) && (nB < 8);
                int ia = cA ? (baseA + nA) : (cB ? (baseB + nB) : trash);
                ldsw[ia] = (ushort)j;         // single predicated write
                nA += cA;
                nB += cB;
            }
        }
    }
    int pA = __shfl_xor(nA, 32);
    int pB = __shfl_xor(nB, 32);
    __syncthreads();
    // ---- assembly (per column, lane<32): A ids + smallest-j ties to fill 8 ----
    if (lane < 32) {
        int tp = tid + 32;
        int n = 0;
        for (int k = 0; k < nA && n < 8; k++) outl[tid][n++] = lists[tid][k];
        for (int k = 0; k < pA && n < 8; k++) outl[tid][n++] = lists[tp][k];
        int p0 = 0, p1 = 0;
        while (n < 8) {                  // two-pointer merge of j-ascending tie lists
            unsigned a = (p0 < nB) ? (unsigned)lists[tid][8 + p0] : 0xFFFFFFFFu;
            unsigned c = (p1 < pB) ? (unsigned)lists[tp][8 + p1] : 0xFFFFFFFFu;
            bool t0 = a < c;
            outl[tid][n++] = (ushort)(t0 ? a : c);
            p0 += t0 ? 1 : 0; p1 += t0 ? 0 : 1;
        }
        uint4 pk = *(const uint4*)&outl[tid][0];
        cand_i[(long)(b * NSL + sl) * NN + i] = pk;
    }
}

// --- merge 8 slice-lists + GAT + update-MLP + fire + 1x1->1 + sigmoid -------
// R10: k_update FUSED in. After the (validated R9) 4-quarter candidate merge,
// q0 lanes compute the GAT output po[16] (registers, p array now dead), share
// it via 1KB LDS; then ALL 64 lanes run the validated 4-quarters-of-32-hd MLP
// (lane (ln15,q) = node ln15, quarter q) with weights staged to LDS at block
// start (loads hide under the candidate-gather latency). Quarter reduction via
// shfl_xor(16/32) butterfly (fp32 reorder class, same as R8/R9 splits).
// q0 lanes run the fire/Wo/sigmoid epilogue using ni (== h[node], in regs).
// Eliminates one dispatch + drain and the 4MB p round-trip.
__launch_bounds__(64)
__global__ void k_gat2(const uint4* __restrict__ cand_i, const float* __restrict__ h,
                       const float* __restrict__ sq,
                       const float* __restrict__ xp, const float* __restrict__ asr,
                       const float* __restrict__ adt, const float* __restrict__ bg,
                       const float* __restrict__ fire, const float* __restrict__ Wu1,
                       const float* __restrict__ bu1, const float* __restrict__ Wu2,
                       const float* __restrict__ bu2, const float* __restrict__ Wo,
                       const float* __restrict__ bo, float* __restrict__ out_low) {
    __shared__ float sU1[128 * 16];
    __shared__ float sU2t[128 * 16];      // [hd][c] = Wu2[c][hd]
    __shared__ float sb1[128];
    __shared__ float pshare[16][17];
    int lane = threadIdx.x;                       // one wave per block
    for (int k = lane; k < 2048; k += 64) {       // stage MLP weights (hide under gathers)
        sU1[k] = Wu1[k];
        sU2t[(k & 127) * 16 + (k >> 7)] = Wu2[k];
    }
    sb1[lane] = bu1[lane];
    sb1[lane + 64] = bu1[lane + 64];
    int ln15 = lane & 15, q = lane >> 4;
    int t = blockIdx.x * 16 + ln15;               // node 0..32767 (== bN + i)
    int b = t >> 12, i = t & 4095;
    long bN = (long)b * NN;
    const float4* ip = (const float4*)&h[(bN + i) * 16];
    float4 r0 = ip[0], r1 = ip[1], r2 = ip[2], r3 = ip[3];
    float ni[16] = { r0.x,r0.y,r0.z,r0.w, r1.x,r1.y,r1.z,r1.w,
                     r2.x,r2.y,r2.z,r2.w, r3.x,r3.y,r3.z,r3.w };
    float fS[8]; int fI[8];
#pragma unroll
    for (int k = 0; k < 8; k++) { fS[k] = -FLT_MAX; fI[k] = 65535; }
#pragma unroll
    for (int ss = 0; ss < 2; ss++) {
        int sl = q * 2 + ss;
        uint4 pk = cand_i[(long)(b * NSL + sl) * NN + i];
        unsigned idx8[8] = { pk.x & 0xFFFF, pk.x >> 16, pk.y & 0xFFFF, pk.y >> 16,
                             pk.z & 0xFFFF, pk.z >> 16, pk.w & 0xFFFF, pk.w >> 16 };
#pragma unroll
        for (int k = 0; k < 8; k++) {
            int j = (int)idx8[k];
            const float4* np = (const float4*)&h[(bN + j) * 16];
            float4 a0 = np[0], a1 = np[1], a2 = np[2], a3 = np[3];
            float d = dot16m(ni, a0, a1, a2, a3, sq[bN + j]);
            bool bt = (d > fS[7]) || (d == fS[7] && j < fI[7]);
            if (bt) {
                fS[7] = d; fI[7] = j;
#pragma unroll
                for (int qq = 7; qq > 0; qq--) {
                    bool sw = (fS[qq] > fS[qq - 1]) || (fS[qq] == fS[qq - 1] && fI[qq] < fI[qq - 1]);
                    if (sw) {
                        float td = fS[qq]; fS[qq] = fS[qq - 1]; fS[qq - 1] = td;
                        int tj = fI[qq]; fI[qq] = fI[qq - 1]; fI[qq - 1] = tj;
                    }
                }
            }
        }
    }
    // level 1: merge quarter pairs (0<->1, 2<->3) — top-8 of 32, then re-sort
    float oS[8]; int oI[8];
#pragma unroll
    for (int k = 0; k < 8; k++) {
        oS[k] = __shfl_xor(fS[k], 16);
        oI[k] = __shfl_xor(fI[k], 16);
    }
    float mS[8]; int mI[8];
#pragma unroll
    for (int k = 0; k < 8; k++) {
        bool mine = (fS[k] > oS[7 - k]) || (fS[k] == oS[7 - k] && fI[k] < oI[7 - k]);
        mS[k] = mine ? fS[k] : oS[7 - k];
        mI[k] = mine ? fI[k] : oI[7 - k];
    }
    bsort8d_id(mS, mI);
    // level 2: merge across (01)<->(23) — top-8 of 64
#pragma unroll
    for (int k = 0; k < 8; k++) {
        oS[k] = __shfl_xor(mS[k], 32);
        oI[k] = __shfl_xor(mI[k], 32);
    }
    int nI[8];
#pragma unroll
    for (int k = 0; k < 8; k++) {
        bool mine = (mS[k] > oS[7 - k]) || (mS[k] == oS[7 - k] && mI[k] < oI[7 - k]);
        nI[k] = mine ? mI[k] : oI[7 - k];
    }
    if (q == 0) {
        int nbrs[9];
#pragma unroll
        for (int e = 0; e < 8; e++) nbrs[e] = nI[e];
        nbrs[8] = i;                                   // self-loop
        float adtv[4];
#pragma unroll
        for (int hh = 0; hh < 4; hh++) adtv[hh] = adt[(bN + i) * 4 + hh];
        float mx[4] = { -FLT_MAX, -FLT_MAX, -FLT_MAX, -FLT_MAX };
        float lg[9][4];
#pragma unroll
        for (int e = 0; e < 9; e++) {
            long nb = bN + nbrs[e];
#pragma unroll
            for (int hh = 0; hh < 4; hh++) {
                float l = asr[nb * 4 + hh] + adtv[hh];
                l = (l > 0.f) ? l : 0.2f * l;          // leaky_relu 0.2
                lg[e][hh] = l;
                mx[hh] = fmaxf(mx[hh], l);
            }
        }
        float sum[4] = { 0, 0, 0, 0 };
        float acc[16];
#pragma unroll
        for (int c = 0; c < 16; c++) acc[c] = 0.f;
#pragma unroll
        for (int e = 0; e < 9; e++) {
            long nb = bN + nbrs[e];
            const float4* xpn = (const float4*)&xp[nb * 16];
            float4 x0 = xpn[0], x1 = xpn[1], x2 = xpn[2], x3 = xpn[3];
            float xv[16] = { x0.x,x0.y,x0.z,x0.w, x1.x,x1.y,x1.z,x1.w,
                             x2.x,x2.y,x2.z,x2.w, x3.x,x3.y,x3.z,x3.w };
            float wv[4];
#pragma unroll
            for (int hh = 0; hh < 4; hh++) {
                float w = expf(lg[e][hh] - mx[hh]);
                sum[hh] += w; wv[hh] = w;
            }
#pragma unroll
            for (int hh = 0; hh < 4; hh++)
#pragma unroll
                for (int f = 0; f < 4; f++)
                    acc[hh * 4 + f] += wv[hh] * xv[hh * 4 + f];
        }
#pragma unroll
        for (int hh = 0; hh < 4; hh++) {
            float inv = 1.f / sum[hh];
#pragma unroll
            for (int f = 0; f < 4; f++) {
                float o = acc[hh * 4 + f] * inv + bg[hh * 4 + f];
                pshare[ln15][hh * 4 + f] = fmaxf(o, 0.f);   // GAT relu -> LDS (p dead)
            }
        }
    }
    __syncthreads();
    // ---- fused update-MLP: all 64 lanes; lane (ln15, q) = node ln15, hd quarter q
    float pv[16];
#pragma unroll
    for (int c = 0; c < 16; c++) pv[c] = pshare[ln15][c];
    float u[16];
#pragma unroll
    for (int c = 0; c < 16; c++) u[c] = 0.f;
    int hd0 = q * 32;
    for (int hd = hd0; hd < hd0 + 32; hd++) {        // wave-uniform LDS addrs: broadcast
        const float4* r = (const float4*)&sU1[hd * 16];
        float4 w0 = r[0], w1 = r[1], w2 = r[2], w3 = r[3];
        float a = sb1[hd]
            + w0.x*pv[0] + w0.y*pv[1] + w0.z*pv[2] + w0.w*pv[3]
            + w1.x*pv[4] + w1.y*pv[5] + w1.z*pv[6] + w1.w*pv[7]
            + w2.x*pv[8] + w2.y*pv[9] + w2.z*pv[10]+ w2.w*pv[11]
            + w3.x*pv[12]+ w3.y*pv[13]+ w3.z*pv[14]+ w3.w*pv[15];
        a = fmaxf(a, 0.f);
        const float4* tt = (const float4*)&sU2t[hd * 16];
        float4 t0 = tt[0], t1 = tt[1], t2 = tt[2], t3 = tt[3];
        u[0] += t0.x*a; u[1] += t0.y*a; u[2] += t0.z*a; u[3] += t0.w*a;
        u[4] += t1.x*a; u[5] += t1.y*a; u[6] += t1.z*a; u[7] += t1.w*a;
        u[8] += t2.x*a; u[9] += t2.y*a; u[10]+= t2.z*a; u[11]+= t2.w*a;
        u[12]+= t3.x*a; u[13]+= t3.y*a; u[14]+= t3.z*a; u[15]+= t3.w*a;
    }
    // butterfly-reduce the 4 quarter-partials (fp32 reorder class)
#pragma unroll
    for (int c = 0; c < 16; c++) {
        u[c] += __shfl_xor(u[c], 16);
        u[c] += __shfl_xor(u[c], 32);
    }
    if (q == 0) {
        float mask = (fire[t] < 0.5f) ? 1.f : 0.f;
        float o = bo[0];
#pragma unroll
        for (int c = 0; c < 16; c++)
            o += Wo[c] * (ni[c] + mask * (u[c] + bu2[c]));   // ni == h[t]
        out_low[t] = 1.f / (1.f + expf(-o));
    }
}

// ---------------- bilinear upsample 64 -> 256 (half-pixel, clamp) -----------
__global__ void k_up(const float* __restrict__ ol, float* __restrict__ out) {
    int t = blockIdx.x * 256 + threadIdx.x;
    if (t >= BATCH * HIGH * HIGH) return;
    int b = t >> 16, oy = (t >> 8) & 255, ox = t & 255;
    float cy = (oy + 0.5f) * 0.25f - 0.5f;
    float cx = (ox + 0.5f) * 0.25f - 0.5f;
    int iy0 = (int)floorf(cy); float fy = cy - (float)iy0;
    int ix0 = (int)floorf(cx); float fx = cx - (float)ix0;
    int y0 = min(max(iy0, 0), 63), y1 = min(max(iy0 + 1, 0), 63);
    int x0 = min(max(ix0, 0), 63), x1 = min(max(ix0 + 1, 0), 63);
    const float* s = ol + b * NN;
    float v = (1.f - fy) * ((1.f - fx) * s[y0 * 64 + x0] + fx * s[y0 * 64 + x1])
            + fy * ((1.f - fx) * s[y1 * 64 + x0] + fx * s[y1 * 64 + x1]);
    out[t] = v;
}

extern "C" void kernel_launch(void* const* d_in, const int* in_sizes, int n_in,
                              void* d_out, int out_size, void* d_ws, size_t ws_size,
                              hipStream_t stream) {
    const float* x    = (const float*)d_in[0];
    const float* fire = (const float*)d_in[1];
    const float* W1   = (const float*)d_in[2];
    const float* b1   = (const float*)d_in[3];
    const float* g1   = (const float*)d_in[4];
    const float* be1  = (const float*)d_in[5];
    const float* m1   = (const float*)d_in[6];
    const float* v1   = (const float*)d_in[7];
    const float* W2   = (const float*)d_in[8];
    const float* b2   = (const float*)d_in[9];
    const float* g2   = (const float*)d_in[10];
    const float* be2  = (const float*)d_in[11];
    const float* m2   = (const float*)d_in[12];
    const float* v2   = (const float*)d_in[13];
    const float* Wg   = (const float*)d_in[14];
    const float* a_src= (const float*)d_in[15];
    const float* a_dst= (const float*)d_in[16];
    const float* bg   = (const float*)d_in[17];
    const float* Wu1  = (const float*)d_in[18];
    const float* bu1  = (const float*)d_in[19];
    const float* Wu2  = (const float*)d_in[20];
    const float* bu2  = (const float*)d_in[21];
    const float* Wo   = (const float*)d_in[22];
    const float* bo   = (const float*)d_in[23];

    float* ws  = (float*)d_ws;
    float* xl  = ws + OFF_XL;
    float* h1  = ws + OFF_H1;
    float* h   = ws + OFF_H;
    float* sq  = ws + OFF_SQ;
    float* xp  = ws + OFF_XP;
    float* asr = ws + OFF_ASR;
    float* adt = ws + OFF_ADT;
    float* ol  = ws + OFF_OL;
    // H1 region reuse (dead after conv2): cand_i 4 MB (NSL=8), bf16 splits,
    // nsq. Total 1,867,776 of 2,097,152 floats — no footprint growth.
    uint4*  cand_i = (uint4*)(ws + OFF_H1);
    ushort* hHi    = (ushort*)(ws + OFF_H1 + 1048576);
    ushort* hMid   = (ushort*)(ws + OFF_H1 + 1310720);
    ushort* hLo    = (ushort*)(ws + OFF_H1 + 1572864);
    float*  nsq    = ws + OFF_H1 + 1835008;

    k_down  <<<(BATCH * NN + 127) / 128, 128, 0, stream>>>(x, xl);
    k_conv1 <<<(BATCH * C1 * NN) / 256, 256, 0, stream>>>(xl, W1, b1, g1, be1, m1, v1, h1);
    k_conv2 <<<BATCH * 32, 512, 0, stream>>>(h1, W2, b2, g2, be2, m2, v2, Wg, a_src, a_dst,
                                             h, sq, xp, asr, adt);
    k_split <<<BATCH * NN / 64, 64, 0, stream>>>(h, sq, hHi, hMid, hLo, nsq);
    k_scan  <<<BATCH * 32 * NSL, 256, 0, stream>>>(hHi, hMid, hLo, nsq, cand_i);
    k_gat2  <<<BATCH * NN / 16, 64, 0, stream>>>(cand_i, h, sq, xp, asr, adt, bg,
                                                 fire, Wu1, bu1, Wu2, bu2, Wo, bo, ol);
    k_up    <<<(BATCH * HIGH * HIGH) / 256, 256, 0, stream>>>(ol, (float*)d_out);
}

// Round 12
// 267.378 us; speedup vs baseline: 1.6411x; 1.0143x over previous
//
#include <hip/hip_runtime.h>
#include <math.h>
#include <float.h>

#define BATCH 8
#define HIGH  256
#define LOWR  64
#define NN    4096          // LOWR*LOWR
#define HIDC  16
#define C1    64
#define NSL   8             // j-slices in kNN scan (512 j each)

// workspace layout (floats) — footprint identical to the validated layout
#define OFF_XL   0                               // DEAD (down fused into conv1)
#define OFF_H1   (OFF_XL  + BATCH*NN)            // 2.097M floats; reused after conv2:
                                                 //   [0 .. 1,048,575]         cand_i (4 MB, NSL=8)
                                                 //   [1,048,576 .. 1,835,007] bf16 hi/mid/lo splits
                                                 //   [1,835,008 .. 1,867,775] nsq (= -sq)
#define OFF_H    (OFF_H1  + BATCH*C1*NN)         // node-major [B*N][16]
#define OFF_SQ   (OFF_H   + BATCH*NN*HIDC)       // 0.5*|h|^2 per node
#define OFF_XP   (OFF_SQ  + BATCH*NN)
#define OFF_ASR  (OFF_XP  + BATCH*NN*HIDC)
#define OFF_ADT  (OFF_ASR + BATCH*NN*4)
#define OFF_P    (OFF_ADT + BATCH*NN*4)          // DEAD (update fused into gat2, R10)
#define OFF_OL   (OFF_P   + BATCH*NN*HIDC)

typedef __attribute__((ext_vector_type(8)))  short bf16x8;
typedef __attribute__((ext_vector_type(16))) float f32x16;

// identical-arithmetic dot used by k_gat2 (exact fp32 re-score of the pool —
// final selection semantics unchanged from the validated kernel)
__device__ __forceinline__ float dot16m(const float ni[16], float4 a0, float4 a1,
                                        float4 a2, float4 a3, float hs) {
    return ni[0]*a0.x + ni[1]*a0.y + ni[2]*a0.z + ni[3]*a0.w
         + ni[4]*a1.x + ni[5]*a1.y + ni[6]*a1.z + ni[7]*a1.w
         + ni[8]*a2.x + ni[9]*a2.y + ni[10]*a2.z + ni[11]*a2.w
         + ni[12]*a3.x + ni[13]*a3.y + ni[14]*a3.z + ni[15]*a3.w
         - hs;
}

// ---- fused: bilinear downsample 256->64 (tile+halo in LDS) + conv3x3 1->64 --
// Block (b, ytile) computes its 4x66 xl tile (rows ytile*2-1..+2, cols -1..64)
// cooperatively with the EXACT k_down arithmetic (halo recomputed by neighbor
// blocks -> identical values; out-of-range = 0, and FMA(w,0,acc)==acc exactly,
// so conv outputs are bit-identical to the unfused version). Each thread loads
// its 9-tap stencil once and emits 16 co-outputs. 256 blocks x 512 thr.
// R12 FIX: W1 staging was `if (tid < 576)` with only 512 threads — sW[512..575]
// (channels 56..63) was uninitialized LDS -> absmax 3.3e-2 fail. Strided loop.
__launch_bounds__(512)
__global__ void k_dconv1(const float* __restrict__ x, const float* __restrict__ W1,
                         const float* __restrict__ b1, const float* __restrict__ g1,
                         const float* __restrict__ be1, const float* __restrict__ m1,
                         const float* __restrict__ v1, float* __restrict__ h1) {
    __shared__ float sW[576];
    __shared__ float sb[64], sg[64], sbe[64], sm[64], sv[64];
    __shared__ float sxl[4][66];
    int tid = threadIdx.x;
    for (int k = tid; k < 576; k += 512) sW[k] = W1[k];   // R12 fix: full 576 staged
    if (tid < 64) {
        sb[tid] = b1[tid]; sg[tid] = g1[tid]; sbe[tid] = be1[tid];
        sm[tid] = m1[tid]; sv[tid] = v1[tid];
    }
    int blk = blockIdx.x;                 // 8 batches * 32 y-tiles
    int b = blk >> 5, ytile = blk & 31;
    if (tid < 264) {                      // 4 rows x 66 cols (incl. halo)
        int tr = tid / 66, tc = tid - tr * 66;
        int oy = ytile * 2 - 1 + tr, ox = tc - 1;
        float val = 0.f;
        if (oy >= 0 && oy < 64 && ox >= 0 && ox < 64) {
            const float* xb = x + b * HIGH * HIGH;
            float cy = 4.f * oy + 1.5f, cx = 4.f * ox + 1.5f;
            float wy[8], wx[8], sy = 0.f, sx = 0.f;
#pragma unroll
            for (int k = 0; k < 8; k++) {
                int iy = 4 * oy - 2 + k;
                float w = 1.f - fabsf((float)iy - cy) * 0.25f;
                if (iy < 0 || iy >= HIGH) w = 0.f;
                wy[k] = w; sy += w;
                int ix = 4 * ox - 2 + k;
                float v = 1.f - fabsf((float)ix - cx) * 0.25f;
                if (ix < 0 || ix >= HIGH) v = 0.f;
                wx[k] = v; sx += v;
            }
            float acc = 0.f;
#pragma unroll
            for (int ky = 0; ky < 8; ky++) {
                if (wy[ky] == 0.f) continue;
                int iy = 4 * oy - 2 + ky;
                float rowacc = 0.f;
#pragma unroll
                for (int kx = 0; kx < 8; kx++) {
                    if (wx[kx] == 0.f) continue;
                    int ix = 4 * ox - 2 + kx;
                    rowacc += wx[kx] * xb[iy * HIGH + ix];
                }
                acc += wy[ky] * rowacc;
            }
            val = acc / (sy * sx);
        }
        sxl[tr][tc] = val;
    }
    __syncthreads();
    int pix = tid & 127, row = pix >> 6, col = pix & 63;
    float t00 = sxl[row    ][col], t01 = sxl[row    ][col + 1], t02 = sxl[row    ][col + 2];
    float t10 = sxl[row + 1][col], t11 = sxl[row + 1][col + 1], t12 = sxl[row + 1][col + 2];
    float t20 = sxl[row + 2][col], t21 = sxl[row + 2][col + 1], t22 = sxl[row + 2][col + 2];
    int y = ytile * 2 + row;
    long base = (long)b * C1 * NN + (long)y * 64 + col;
#pragma unroll
    for (int it = 0; it < 16; it++) {
        int co = it * 4 + (tid >> 7);     // wave-uniform
        const float* w = &sW[co * 9];
        float acc = 0.f;                  // tap order identical to unfused conv1
        acc += w[0] * t00; acc += w[1] * t01; acc += w[2] * t02;
        acc += w[3] * t10; acc += w[4] * t11; acc += w[5] * t12;
        acc += w[6] * t20; acc += w[7] * t21; acc += w[8] * t22;
        acc += sb[co];
        float sc = sg[co] / sqrtf(sv[co] + 1e-5f);
        acc = (acc - sm[co]) * sc + sbe[co];
        h1[base + (long)co * NN] = fmaxf(acc, 0.f);
    }
}

// ------- conv3x3 64->16 + BN + relu, fused: h (node-major), sq, xp, asr, adt -
// 512 threads, 4-way ci-split (16 ci per thread) -> 8 waves/CU on all 4
// SIMDs. Quarters 1-3 write partials to LDS, quarter 0 reduces + epilogue.
__launch_bounds__(512)
__global__ void k_conv2(const float* __restrict__ h1, const float* __restrict__ W2,
                        const float* __restrict__ b2, const float* __restrict__ g2,
                        const float* __restrict__ be2, const float* __restrict__ m2,
                        const float* __restrict__ v2, const float* __restrict__ Wg,
                        const float* __restrict__ a_src, const float* __restrict__ a_dst,
                        float* __restrict__ h, float* __restrict__ sq,
                        float* __restrict__ xp, float* __restrict__ asr,
                        float* __restrict__ adt) {
    __shared__ float sW2t[576 * 16];    // [ci*9+tap][o]
    __shared__ float sWg[256];
    __shared__ float sA[32];
    __shared__ float accH[3][128][17];  // partials from quarters 1..3 (17-pad)
    int tid = threadIdx.x;
    for (int k = tid; k < 9216; k += 512) {          // coalesced global read, scatter to LDS
        int o = k / 576, ct = k - o * 576;
        sW2t[ct * 16 + o] = W2[k];
    }
    if (tid < 256) sWg[tid] = Wg[tid];
    if (tid < 16) { sA[tid] = a_src[tid]; sA[16 + tid] = a_dst[tid]; }
    __syncthreads();
    int blk = blockIdx.x;                 // 8 batches * 32 y-tiles
    int b = blk >> 5, ytile = blk & 31;
    int q = tid >> 7;                     // ci quarter 0..3
    int sub = tid & 127;
    int ty = sub >> 6, x = sub & 63, y = ytile * 2 + ty;
    float acc[16];
#pragma unroll
    for (int o = 0; o < 16; o++) acc[o] = 0.f;
    const float* hb = h1 + (long)b * C1 * NN + (long)q * 16 * NN;
    for (int ci = 0; ci < 16; ci++) {
        const float* plane = hb + ci * NN;
#pragma unroll
        for (int dy = -1; dy <= 1; dy++) {
            int yy = y + dy; bool oky = (yy >= 0 && yy < 64);
#pragma unroll
            for (int dx = -1; dx <= 1; dx++) {
                int xx = x + dx;
                float v = (oky && xx >= 0 && xx < 64) ? plane[yy * 64 + xx] : 0.f;
                int ct = (q * 16 + ci) * 9 + (dy + 1) * 3 + (dx + 1);
                const float4* wr = (const float4*)&sW2t[ct * 16];
                float4 w0 = wr[0], w1 = wr[1], w2 = wr[2], w3 = wr[3];
                acc[0] += v * w0.x; acc[1] += v * w0.y; acc[2] += v * w0.z; acc[3] += v * w0.w;
                acc[4] += v * w1.x; acc[5] += v * w1.y; acc[6] += v * w1.z; acc[7] += v * w1.w;
                acc[8] += v * w2.x; acc[9] += v * w2.y; acc[10]+= v * w2.z; acc[11]+= v * w2.w;
                acc[12]+= v * w3.x; acc[13]+= v * w3.y; acc[14]+= v * w3.z; acc[15]+= v * w3.w;
            }
        }
    }
    if (q != 0) {
        float* dst = &accH[q - 1][sub][0];
#pragma unroll
        for (int o = 0; o < 16; o++) dst[o] = acc[o];
    }
    __syncthreads();
    if (q != 0) return;
#pragma unroll
    for (int qq = 0; qq < 3; qq++) {
        const float* src = &accH[qq][sub][0];
#pragma unroll
        for (int o = 0; o < 16; o++) acc[o] += src[o];
    }
    int n = y * 64 + x;
    long node = (long)b * NN + n;
    float nodev[16], sqv = 0.f;
#pragma unroll
    for (int o = 0; o < 16; o++) {
        float a = acc[o] + b2[o];
        float sc = g2[o] / sqrtf(v2[o] + 1e-5f);
        a = (a - m2[o]) * sc + be2[o];
        a = fmaxf(a, 0.f);
        nodev[o] = a; sqv += a * a;
        h[node * 16 + o] = a;
    }
    sq[node] = 0.5f * sqv;                // pre-scaled: scan/merge use dot - 0.5|j|^2
    float xpv[16];
#pragma unroll
    for (int o = 0; o < 16; o++) {
        float a = 0.f;
#pragma unroll
        for (int c = 0; c < 16; c++) a += sWg[o * 16 + c] * nodev[c];
        xpv[o] = a;
        xp[node * 16 + o] = a;
    }
#pragma unroll
    for (int hh = 0; hh < 4; hh++) {
        float as = 0.f, ad = 0.f;
#pragma unroll
        for (int f = 0; f < 4; f++) {
            as += xpv[hh * 4 + f] * sA[hh * 4 + f];
            ad += xpv[hh * 4 + f] * sA[16 + hh * 4 + f];
        }
        asr[node * 4 + hh] = as;
        adt[node * 4 + hh] = ad;
    }
}

// ------- error-free 3-way bf16 split of h: h = hi + mid + lo + O(2^-27) -----
__device__ __forceinline__ ushort f2bf(float f) {
    unsigned u = __float_as_uint(f);
    return (ushort)((u + 0x7FFFu + ((u >> 16) & 1u)) >> 16);
}
__device__ __forceinline__ float bf2f(ushort h) {
    return __uint_as_float(((unsigned)h) << 16);
}
__global__ void k_split(const float* __restrict__ h, const float* __restrict__ sq,
                        ushort* __restrict__ hHi, ushort* __restrict__ hMid,
                        ushort* __restrict__ hLo, float* __restrict__ nsq) {
    long t = (long)blockIdx.x * 64 + threadIdx.x;    // node 0..32767
    nsq[t] = -sq[t];                                  // negated for MFMA C-init
    const float4* hp = (const float4*)&h[t * 16];
    float4 v0 = hp[0], v1 = hp[1], v2 = hp[2], v3 = hp[3];
    float v[16] = { v0.x,v0.y,v0.z,v0.w, v1.x,v1.y,v1.z,v1.w,
                    v2.x,v2.y,v2.z,v2.w, v3.x,v3.y,v3.z,v3.w };
    unsigned wh[8], wm[8], wl[8];
#pragma unroll
    for (int p = 0; p < 8; p++) {
        unsigned packh = 0, packm = 0, packl = 0;
#pragma unroll
        for (int e = 0; e < 2; e++) {
            float f = v[p * 2 + e];
            ushort hi = f2bf(f);
            float t1 = f - bf2f(hi);
            ushort mi = f2bf(t1);
            float t2 = t1 - bf2f(mi);
            ushort lo = f2bf(t2);
            packh |= ((unsigned)hi) << (16 * e);
            packm |= ((unsigned)mi) << (16 * e);
            packl |= ((unsigned)lo) << (16 * e);
        }
        wh[p] = packh; wm[p] = packm; wl[p] = packl;
    }
    uint4* dh = (uint4*)&hHi[t * 16];
    uint4* dm = (uint4*)&hMid[t * 16];
    uint4* dl = (uint4*)&hLo[t * 16];
    dh[0] = make_uint4(wh[0], wh[1], wh[2], wh[3]);
    dh[1] = make_uint4(wh[4], wh[5], wh[6], wh[7]);
    dm[0] = make_uint4(wm[0], wm[1], wm[2], wm[3]);
    dm[1] = make_uint4(wm[4], wm[5], wm[6], wm[7]);
    dl[0] = make_uint4(wl[0], wl[1], wl[2], wl[3]);
    dl[1] = make_uint4(wl[4], wl[5], wl[6], wl[7]);
}

// --- shared tile-score routine: MUST be bit-identical between pass 1/2 ------
__device__ __forceinline__ void tile_scores(const ushort* __restrict__ hHi,
        const ushort* __restrict__ hMid, const ushort* __restrict__ hLo,
        const float* __restrict__ nsq, long bN, int j0, int ln31, int koff,
        int rbase, int i0w, bf16x8 bi_h, bf16x8 bi_m, bf16x8 bi_l,
        float scv[16]) {
    int jr = j0 + ln31;
    bf16x8 aj_h = *(const bf16x8*)&hHi [(bN + jr) * 16 + koff];
    bf16x8 aj_m = *(const bf16x8*)&hMid[(bN + jr) * 16 + koff];
    bf16x8 aj_l = *(const bf16x8*)&hLo [(bN + jr) * 16 + koff];
    float4 q0 = *(const float4*)&nsq[bN + j0 +  0 + rbase];
    float4 q1 = *(const float4*)&nsq[bN + j0 +  8 + rbase];
    float4 q2 = *(const float4*)&nsq[bN + j0 + 16 + rbase];
    float4 q3 = *(const float4*)&nsq[bN + j0 + 24 + rbase];
    f32x16 acc;
    acc[0]  = q0.x; acc[1]  = q0.y; acc[2]  = q0.z; acc[3]  = q0.w;
    acc[4]  = q1.x; acc[5]  = q1.y; acc[6]  = q1.z; acc[7]  = q1.w;
    acc[8]  = q2.x; acc[9]  = q2.y; acc[10] = q2.z; acc[11] = q2.w;
    acc[12] = q3.x; acc[13] = q3.y; acc[14] = q3.z; acc[15] = q3.w;
    acc = __builtin_amdgcn_mfma_f32_32x32x16_bf16(aj_h, bi_h, acc, 0, 0, 0);
    acc = __builtin_amdgcn_mfma_f32_32x32x16_bf16(aj_h, bi_m, acc, 0, 0, 0);
    acc = __builtin_amdgcn_mfma_f32_32x32x16_bf16(aj_m, bi_h, acc, 0, 0, 0);
    acc = __builtin_amdgcn_mfma_f32_32x32x16_bf16(aj_h, bi_l, acc, 0, 0, 0);
    acc = __builtin_amdgcn_mfma_f32_32x32x16_bf16(aj_l, bi_h, acc, 0, 0, 0);
    acc = __builtin_amdgcn_mfma_f32_32x32x16_bf16(aj_m, bi_m, acc, 0, 0, 0);
#pragma unroll
    for (int rr = 0; rr < 16; rr++) scv[rr] = acc[rr];
    if (j0 == i0w) {                       // wave-uniform: diagonal tile, mask self
#pragma unroll
        for (int rr = 0; rr < 16; rr++) {
            int r = (rr & 3) + 8 * (rr >> 2) + rbase;
            if (r == ln31) scv[rr] = -FLT_MAX;
        }
    }
}

// --- sorting-network primitives (compare-exchange = max/min pair: exact
// multiset preservation, fully unrolled constant indexing) ------------------
#define CEX(a, b) { float ce_hi = fmaxf(a, b), ce_lo = fminf(a, b); (a) = ce_hi; (b) = ce_lo; }
// Batcher odd-even mergesort, 8 values descending (19 CE)
__device__ __forceinline__ void sort8d(float v[8]) {
    CEX(v[0],v[1]); CEX(v[2],v[3]); CEX(v[4],v[5]); CEX(v[6],v[7]);
    CEX(v[0],v[2]); CEX(v[1],v[3]); CEX(v[4],v[6]); CEX(v[5],v[7]);
    CEX(v[1],v[2]); CEX(v[5],v[6]);
    CEX(v[0],v[4]); CEX(v[1],v[5]); CEX(v[2],v[6]); CEX(v[3],v[7]);
    CEX(v[2],v[4]); CEX(v[3],v[5]);
    CEX(v[1],v[2]); CEX(v[3],v[4]); CEX(v[5],v[6]);
}
// bitonic 8-sequence -> sorted descending (12 CE)
__device__ __forceinline__ void bsort8d(float v[8]) {
    CEX(v[0],v[4]); CEX(v[1],v[5]); CEX(v[2],v[6]); CEX(v[3],v[7]);
    CEX(v[0],v[2]); CEX(v[1],v[3]); CEX(v[4],v[6]); CEX(v[5],v[7]);
    CEX(v[0],v[1]); CEX(v[2],v[3]); CEX(v[4],v[5]); CEX(v[6],v[7]);
}
// compare-exchange with carried id under (score desc, id asc) total order
#define CEX2(sa, ia, sb, ib) { \
    bool sw2 = ((sb) > (sa)) || ((sb) == (sa) && (ib) < (ia)); \
    float th2 = sw2 ? (sb) : (sa); float tl2 = sw2 ? (sa) : (sb); \
    int   ih2 = sw2 ? (ib) : (ia); int   il2 = sw2 ? (ia) : (ib); \
    (sa) = th2; (sb) = tl2; (ia) = ih2; (ib) = il2; }
// bitonic 8 -> sorted by (score desc, id asc), ids carried (12 CE2)
__device__ __forceinline__ void bsort8d_id(float v[8], int id[8]) {
    CEX2(v[0],id[0],v[4],id[4]); CEX2(v[1],id[1],v[5],id[5]);
    CEX2(v[2],id[2],v[6],id[6]); CEX2(v[3],id[3],v[7],id[7]);
    CEX2(v[0],id[0],v[2],id[2]); CEX2(v[1],id[1],v[3],id[3]);
    CEX2(v[4],id[4],v[6],id[6]); CEX2(v[5],id[5],v[7],id[7]);
    CEX2(v[0],id[0],v[1],id[1]); CEX2(v[2],id[2],v[3],id[3]);
    CEX2(v[4],id[4],v[5],id[5]); CEX2(v[6],id[6],v[7],id[7]);
}

// --------- kNN scan, two-pass scores-only selection (validated R6-R9) --------
// At structural floor per R9 falsifier: 89% pipe-busy, selection networks at
// the CE lower bound, occupancy lever exhausted. NOT touched since R9.
__global__ __attribute__((amdgpu_waves_per_eu(4, 8))) __launch_bounds__(256)
void k_scan(const ushort* __restrict__ hHi, const ushort* __restrict__ hMid,
            const ushort* __restrict__ hLo, const float* __restrict__ nsq,
            uint4* __restrict__ cand_i) {
    __shared__ ushort lists[256][18];    // [tid][0..7]=A ids, [8..15]=B ids, [16]=trash, [17]=pad
    __shared__ ushort outl[256][8];
    int tid = threadIdx.x, blk = blockIdx.x;
    int b  = blk >> 8;                   // 256 blocks per batch (32 ig x 8 sl)
    int ig = (blk >> 3) & 31;
    int sl = blk & 7;
    int wid = tid >> 6, lane = tid & 63;
    int ln31 = lane & 31, l5 = lane >> 5;
    int koff = l5 * 8;
    int i0w = ig * 128 + wid * 32;       // this wave's 32-aligned i-tile base
    int i   = i0w + ln31;
    long bN = (long)b * NN;
    int rbase = l5 * 4;
    int jbase = sl * 512;

    bf16x8 bi_h = *(const bf16x8*)&hHi [(bN + i) * 16 + koff];
    bf16x8 bi_m = *(const bf16x8*)&hMid[(bN + i) * 16 + koff];
    bf16x8 bi_l = *(const bf16x8*)&hLo [(bN + i) * 16 + koff];

    // ---- pass 1: top-8 scores only (sorted descending invariant) ----
    float s[8];
#pragma unroll
    for (int k = 0; k < 8; k++) s[k] = -FLT_MAX;
#pragma unroll 2
    for (int t = 0; t < 16; t++) {
        int j0 = jbase + t * 32;
        float scv[16];
        tile_scores(hHi, hMid, hLo, nsq, bN, j0, ln31, koff, rbase, i0w,
                    bi_h, bi_m, bi_l, scv);
        float va[8] = { scv[0], scv[1], scv[2], scv[3], scv[4], scv[5], scv[6], scv[7] };
        float vb[8] = { scv[8], scv[9], scv[10], scv[11], scv[12], scv[13], scv[14], scv[15] };
        sort8d(va); sort8d(vb);
        float mg[8];
#pragma unroll
        for (int k = 0; k < 8; k++) mg[k] = fmaxf(va[k], vb[7 - k]);  // top-8 of 16, bitonic
        bsort8d(mg);
#pragma unroll
        for (int k = 0; k < 8; k++) s[k] = fmaxf(s[k], mg[7 - k]);    // top-8 of (s ∪ mg), bitonic
        bsort8d(s);
    }
    // pair-merge: top-8 of union(lane, lane^32) as a multiset; theta = its min.
    float mv[8];
#pragma unroll
    for (int k = 0; k < 8; k++) mv[k] = fmaxf(s[k], __shfl_xor(s[7 - k], 32));
    float theta = mv[0];
#pragma unroll
    for (int k = 1; k < 8; k++) theta = fminf(theta, mv[k]);

    // ---- pass 2: id recovery via bitmask + ffs ----
    ushort* ldsw = &lists[0][0];
    int baseA = tid * 18, baseB = baseA + 8, trash = baseA + 16;
    int nA = 0, nB = 0;
#pragma unroll 2
    for (int t = 0; t < 16; t++) {
        int j0 = jbase + t * 32;
        float scv[16];
        tile_scores(hHi, hMid, hLo, nsq, bN, j0, ln31, koff, rbase, i0w,
                    bi_h, bi_m, bi_l, scv);
        unsigned gm = 0, em = 0;
#pragma unroll
        for (int rr = 0; rr < 16; rr++) {
            gm |= (scv[rr] >  theta) ? (1u << rr) : 0u;
            em |= (scv[rr] == theta) ? (1u << rr) : 0u;
        }
        unsigned m = gm | em;
        while (__any(m != 0u)) {
            if (m) {
                int rr = __ffs(m) - 1;
                m &= m - 1u;
                int r = (rr & 3) + ((rr >> 2) << 3) + rbase;
                int j = j0 + r;
                bool isGt = (gm >> rr) & 1u;
                bool cA = isGt && (nA < 8);   // <=7 by math; insurance
                bool cB = (!isGt) && (nB < 8);
                int ia = cA ? (baseA + nA) : (cB ? (baseB + nB) : trash);
                ldsw[ia] = (ushort)j;         // single predicated write
                nA += cA;
                nB += cB;
            }
        }
    }
    int pA = __shfl_xor(nA, 32);
    int pB = __shfl_xor(nB, 32);
    __syncthreads();
    // ---- assembly (per column, lane<32): A ids + smallest-j ties to fill 8 ----
    if (lane < 32) {
        int tp = tid + 32;
        int n = 0;
        for (int k = 0; k < nA && n < 8; k++) outl[tid][n++] = lists[tid][k];
        for (int k = 0; k < pA && n < 8; k++) outl[tid][n++] = lists[tp][k];
        int p0 = 0, p1 = 0;
        while (n < 8) {                  // two-pointer merge of j-ascending tie lists
            unsigned a = (p0 < nB) ? (unsigned)lists[tid][8 + p0] : 0xFFFFFFFFu;
            unsigned c = (p1 < pB) ? (unsigned)lists[tp][8 + p1] : 0xFFFFFFFFu;
            bool t0 = a < c;
            outl[tid][n++] = (ushort)(t0 ? a : c);
            p0 += t0 ? 1 : 0; p1 += t0 ? 0 : 1;
        }
        uint4 pk = *(const uint4*)&outl[tid][0];
        cand_i[(long)(b * NSL + sl) * NN + i] = pk;
    }
}

// --- merge 8 slice-lists + GAT + update-MLP + fire + 1x1->1 + sigmoid -------
// (validated R10 fusion; unchanged)
__launch_bounds__(64)
__global__ void k_gat2(const uint4* __restrict__ cand_i, const float* __restrict__ h,
                       const float* __restrict__ sq,
                       const float* __restrict__ xp, const float* __restrict__ asr,
                       const float* __restrict__ adt, const float* __restrict__ bg,
                       const float* __restrict__ fire, const float* __restrict__ Wu1,
                       const float* __restrict__ bu1, const float* __restrict__ Wu2,
                       const float* __restrict__ bu2, const float* __restrict__ Wo,
                       const float* __restrict__ bo, float* __restrict__ out_low) {
    __shared__ float sU1[128 * 16];
    __shared__ float sU2t[128 * 16];      // [hd][c] = Wu2[c][hd]
    __shared__ float sb1[128];
    __shared__ float pshare[16][17];
    int lane = threadIdx.x;                       // one wave per block
    for (int k = lane; k < 2048; k += 64) {       // stage MLP weights (hide under gathers)
        sU1[k] = Wu1[k];
        sU2t[(k & 127) * 16 + (k >> 7)] = Wu2[k];
    }
    sb1[lane] = bu1[lane];
    sb1[lane + 64] = bu1[lane + 64];
    int ln15 = lane & 15, q = lane >> 4;
    int t = blockIdx.x * 16 + ln15;               // node 0..32767 (== bN + i)
    int b = t >> 12, i = t & 4095;
    long bN = (long)b * NN;
    const float4* ip = (const float4*)&h[(bN + i) * 16];
    float4 r0 = ip[0], r1 = ip[1], r2 = ip[2], r3 = ip[3];
    float ni[16] = { r0.x,r0.y,r0.z,r0.w, r1.x,r1.y,r1.z,r1.w,
                     r2.x,r2.y,r2.z,r2.w, r3.x,r3.y,r3.z,r3.w };
    float fS[8]; int fI[8];
#pragma unroll
    for (int k = 0; k < 8; k++) { fS[k] = -FLT_MAX; fI[k] = 65535; }
#pragma unroll
    for (int ss = 0; ss < 2; ss++) {
        int sl = q * 2 + ss;
        uint4 pk = cand_i[(long)(b * NSL + sl) * NN + i];
        unsigned idx8[8] = { pk.x & 0xFFFF, pk.x >> 16, pk.y & 0xFFFF, pk.y >> 16,
                             pk.z & 0xFFFF, pk.z >> 16, pk.w & 0xFFFF, pk.w >> 16 };
#pragma unroll
        for (int k = 0; k < 8; k++) {
            int j = (int)idx8[k];
            const float4* np = (const float4*)&h[(bN + j) * 16];
            float4 a0 = np[0], a1 = np[1], a2 = np[2], a3 = np[3];
            float d = dot16m(ni, a0, a1, a2, a3, sq[bN + j]);
            bool bt = (d > fS[7]) || (d == fS[7] && j < fI[7]);
            if (bt) {
                fS[7] = d; fI[7] = j;
#pragma unroll
                for (int qq = 7; qq > 0; qq--) {
                    bool sw = (fS[qq] > fS[qq - 1]) || (fS[qq] == fS[qq - 1] && fI[qq] < fI[qq - 1]);
                    if (sw) {
                        float td = fS[qq]; fS[qq] = fS[qq - 1]; fS[qq - 1] = td;
                        int tj = fI[qq]; fI[qq] = fI[qq - 1]; fI[qq - 1] = tj;
                    }
                }
            }
        }
    }
    // level 1: merge quarter pairs (0<->1, 2<->3) — top-8 of 32, then re-sort
    float oS[8]; int oI[8];
#pragma unroll
    for (int k = 0; k < 8; k++) {
        oS[k] = __shfl_xor(fS[k], 16);
        oI[k] = __shfl_xor(fI[k], 16);
    }
    float mS[8]; int mI[8];
#pragma unroll
    for (int k = 0; k < 8; k++) {
        bool mine = (fS[k] > oS[7 - k]) || (fS[k] == oS[7 - k] && fI[k] < oI[7 - k]);
        mS[k] = mine ? fS[k] : oS[7 - k];
        mI[k] = mine ? fI[k] : oI[7 - k];
    }
    bsort8d_id(mS, mI);
    // level 2: merge across (01)<->(23) — top-8 of 64
#pragma unroll
    for (int k = 0; k < 8; k++) {
        oS[k] = __shfl_xor(mS[k], 32);
        oI[k] = __shfl_xor(mI[k], 32);
    }
    int nI[8];
#pragma unroll
    for (int k = 0; k < 8; k++) {
        bool mine = (mS[k] > oS[7 - k]) || (mS[k] == oS[7 - k] && mI[k] < oI[7 - k]);
        nI[k] = mine ? mI[k] : oI[7 - k];
    }
    if (q == 0) {
        int nbrs[9];
#pragma unroll
        for (int e = 0; e < 8; e++) nbrs[e] = nI[e];
        nbrs[8] = i;                                   // self-loop
        float adtv[4];
#pragma unroll
        for (int hh = 0; hh < 4; hh++) adtv[hh] = adt[(bN + i) * 4 + hh];
        float mx[4] = { -FLT_MAX, -FLT_MAX, -FLT_MAX, -FLT_MAX };
        float lg[9][4];
#pragma unroll
        for (int e = 0; e < 9; e++) {
            long nb = bN + nbrs[e];
#pragma unroll
            for (int hh = 0; hh < 4; hh++) {
                float l = asr[nb * 4 + hh] + adtv[hh];
                l = (l > 0.f) ? l : 0.2f * l;          // leaky_relu 0.2
                lg[e][hh] = l;
                mx[hh] = fmaxf(mx[hh], l);
            }
        }
        float sum[4] = { 0, 0, 0, 0 };
        float acc[16];
#pragma unroll
        for (int c = 0; c < 16; c++) acc[c] = 0.f;
#pragma unroll
        for (int e = 0; e < 9; e++) {
            long nb = bN + nbrs[e];
            const float4* xpn = (const float4*)&xp[nb * 16];
            float4 x0 = xpn[0], x1 = xpn[1], x2 = xpn[2], x3 = xpn[3];
            float xv[16] = { x0.x,x0.y,x0.z,x0.w, x1.x,x1.y,x1.z,x1.w,
                             x2.x,x2.y,x2.z,x2.w, x3.x,x3.y,x3.z,x3.w };
            float wv[4];
#pragma unroll
            for (int hh = 0; hh < 4; hh++) {
                float w = expf(lg[e][hh] - mx[hh]);
                sum[hh] += w; wv[hh] = w;
            }
#pragma unroll
            for (int hh = 0; hh < 4; hh++)
#pragma unroll
                for (int f = 0; f < 4; f++)
                    acc[hh * 4 + f] += wv[hh] * xv[hh * 4 + f];
        }
#pragma unroll
        for (int hh = 0; hh < 4; hh++) {
            float inv = 1.f / sum[hh];
#pragma unroll
            for (int f = 0; f < 4; f++) {
                float o = acc[hh * 4 + f] * inv + bg[hh * 4 + f];
                pshare[ln15][hh * 4 + f] = fmaxf(o, 0.f);   // GAT relu -> LDS (p dead)
            }
        }
    }
    __syncthreads();
    // ---- fused update-MLP: all 64 lanes; lane (ln15, q) = node ln15, hd quarter q
    float pv[16];
#pragma unroll
    for (int c = 0; c < 16; c++) pv[c] = pshare[ln15][c];
    float u[16];
#pragma unroll
    for (int c = 0; c < 16; c++) u[c] = 0.f;
    int hd0 = q * 32;
    for (int hd = hd0; hd < hd0 + 32; hd++) {        // wave-uniform LDS addrs: broadcast
        const float4* r = (const float4*)&sU1[hd * 16];
        float4 w0 = r[0], w1 = r[1], w2 = r[2], w3 = r[3];
        float a = sb1[hd]
            + w0.x*pv[0] + w0.y*pv[1] + w0.z*pv[2] + w0.w*pv[3]
            + w1.x*pv[4] + w1.y*pv[5] + w1.z*pv[6] + w1.w*pv[7]
            + w2.x*pv[8] + w2.y*pv[9] + w2.z*pv[10]+ w2.w*pv[11]
            + w3.x*pv[12]+ w3.y*pv[13]+ w3.z*pv[14]+ w3.w*pv[15];
        a = fmaxf(a, 0.f);
        const float4* tt = (const float4*)&sU2t[hd * 16];
        float4 t0 = tt[0], t1 = tt[1], t2 = tt[2], t3 = tt[3];
        u[0] += t0.x*a; u[1] += t0.y*a; u[2] += t0.z*a; u[3] += t0.w*a;
        u[4] += t1.x*a; u[5] += t1.y*a; u[6] += t1.z*a; u[7] += t1.w*a;
        u[8] += t2.x*a; u[9] += t2.y*a; u[10]+= t2.z*a; u[11]+= t2.w*a;
        u[12]+= t3.x*a; u[13]+= t3.y*a; u[14]+= t3.z*a; u[15]+= t3.w*a;
    }
    // butterfly-reduce the 4 quarter-partials (fp32 reorder class)
#pragma unroll
    for (int c = 0; c < 16; c++) {
        u[c] += __shfl_xor(u[c], 16);
        u[c] += __shfl_xor(u[c], 32);
    }
    if (q == 0) {
        float mask = (fire[t] < 0.5f) ? 1.f : 0.f;
        float o = bo[0];
#pragma unroll
        for (int c = 0; c < 16; c++)
            o += Wo[c] * (ni[c] + mask * (u[c] + bu2[c]));   // ni == h[t]
        out_low[t] = 1.f / (1.f + expf(-o));
    }
}

// ---------------- bilinear upsample 64 -> 256 (half-pixel, clamp) -----------
__global__ void k_up(const float* __restrict__ ol, float* __restrict__ out) {
    int t = blockIdx.x * 256 + threadIdx.x;
    if (t >= BATCH * HIGH * HIGH) return;
    int b = t >> 16, oy = (t >> 8) & 255, ox = t & 255;
    float cy = (oy + 0.5f) * 0.25f - 0.5f;
    float cx = (ox + 0.5f) * 0.25f - 0.5f;
    int iy0 = (int)floorf(cy); float fy = cy - (float)iy0;
    int ix0 = (int)floorf(cx); float fx = cx - (float)ix0;
    int y0 = min(max(iy0, 0), 63), y1 = min(max(iy0 + 1, 0), 63);
    int x0 = min(max(ix0, 0), 63), x1 = min(max(ix0 + 1, 0), 63);
    const float* s = ol + b * NN;
    float v = (1.f - fy) * ((1.f - fx) * s[y0 * 64 + x0] + fx * s[y0 * 64 + x1])
            + fy * ((1.f - fx) * s[y1 * 64 + x0] + fx * s[y1 * 64 + x1]);
    out[t] = v;
}

extern "C" void kernel_launch(void* const* d_in, const int* in_sizes, int n_in,
                              void* d_out, int out_size, void* d_ws, size_t ws_size,
                              hipStream_t stream) {
    const float* x    = (const float*)d_in[0];
    const float* fire = (const float*)d_in[1];
    const float* W1   = (const float*)d_in[2];
    const float* b1   = (const float*)d_in[3];
    const float* g1   = (const float*)d_in[4];
    const float* be1  = (const float*)d_in[5];
    const float* m1   = (const float*)d_in[6];
    const float* v1   = (const float*)d_in[7];
    const float* W2   = (const float*)d_in[8];
    const float* b2   = (const float*)d_in[9];
    const float* g2   = (const float*)d_in[10];
    const float* be2  = (const float*)d_in[11];
    const float* m2   = (const float*)d_in[12];
    const float* v2   = (const float*)d_in[13];
    const float* Wg   = (const float*)d_in[14];
    const float* a_src= (const float*)d_in[15];
    const float* a_dst= (const float*)d_in[16];
    const float* bg   = (const float*)d_in[17];
    const float* Wu1  = (const float*)d_in[18];
    const float* bu1  = (const float*)d_in[19];
    const float* Wu2  = (const float*)d_in[20];
    const float* bu2  = (const float*)d_in[21];
    const float* Wo   = (const float*)d_in[22];
    const float* bo   = (const float*)d_in[23];

    float* ws  = (float*)d_ws;
    float* h1  = ws + OFF_H1;
    float* h   = ws + OFF_H;
    float* sq  = ws + OFF_SQ;
    float* xp  = ws + OFF_XP;
    float* asr = ws + OFF_ASR;
    float* adt = ws + OFF_ADT;
    float* ol  = ws + OFF_OL;
    // H1 region reuse (dead after conv2): cand_i 4 MB (NSL=8), bf16 splits,
    // nsq. Total 1,867,776 of 2,097,152 floats — no footprint growth.
    uint4*  cand_i = (uint4*)(ws + OFF_H1);
    ushort* hHi    = (ushort*)(ws + OFF_H1 + 1048576);
    ushort* hMid   = (ushort*)(ws + OFF_H1 + 1310720);
    ushort* hLo    = (ushort*)(ws + OFF_H1 + 1572864);
    float*  nsq    = ws + OFF_H1 + 1835008;

    k_dconv1<<<BATCH * 32, 512, 0, stream>>>(x, W1, b1, g1, be1, m1, v1, h1);
    k_conv2 <<<BATCH * 32, 512, 0, stream>>>(h1, W2, b2, g2, be2, m2, v2, Wg, a_src, a_dst,
                                             h, sq, xp, asr, adt);
    k_split <<<BATCH * NN / 64, 64, 0, stream>>>(h, sq, hHi, hMid, hLo, nsq);
    k_scan  <<<BATCH * 32 * NSL, 256, 0, stream>>>(hHi, hMid, hLo, nsq, cand_i);
    k_gat2  <<<BATCH * NN / 16, 64, 0, stream>>>(cand_i, h, sq, xp, asr, adt, bg,
                                                 fire, Wu1, bu1, Wu2, bu2, Wo, bo, ol);
    k_up    <<<(BATCH * HIGH * HIGH) / 256, 256, 0, stream>>>(ol, (float*)d_out);
}

// Round 13
// 262.884 us; speedup vs baseline: 1.6692x; 1.0171x over previous
//
#include <hip/hip_runtime.h>
#include <math.h>
#include <float.h>

#define BATCH 8
#define HIGH  256
#define LOWR  64
#define NN    4096          // LOWR*LOWR
#define HIDC  16
#define C1    64
#define NSL   8             // j-slices in kNN scan (512 j each)

// workspace layout (floats) — footprint identical to the validated layout
#define OFF_XL   0                               // DEAD (down fused into conv1)
#define OFF_H1   (OFF_XL  + BATCH*NN)            // 2.097M floats; reused after conv2:
                                                 //   [0 .. 1,048,575]         cand_i (4 MB, NSL=8)
                                                 //   [1,048,576 .. 1,835,007] bf16 hi/mid/lo splits
                                                 //   [1,835,008 .. 1,867,775] nsq (= -sq)
#define OFF_H    (OFF_H1  + BATCH*C1*NN)         // node-major [B*N][16]
#define OFF_SQ   (OFF_H   + BATCH*NN*HIDC)       // 0.5*|h|^2 per node
#define OFF_XP   (OFF_SQ  + BATCH*NN)
#define OFF_ASR  (OFF_XP  + BATCH*NN*HIDC)
#define OFF_ADT  (OFF_ASR + BATCH*NN*4)
#define OFF_P    (OFF_ADT + BATCH*NN*4)          // DEAD (update fused into gat2, R10)
#define OFF_OL   (OFF_P   + BATCH*NN*HIDC)

typedef __attribute__((ext_vector_type(8)))  short bf16x8;
typedef __attribute__((ext_vector_type(16))) float f32x16;

// identical-arithmetic dot used by k_gat2 (exact fp32 re-score of the pool —
// final selection semantics unchanged from the validated kernel)
__device__ __forceinline__ float dot16m(const float ni[16], float4 a0, float4 a1,
                                        float4 a2, float4 a3, float hs) {
    return ni[0]*a0.x + ni[1]*a0.y + ni[2]*a0.z + ni[3]*a0.w
         + ni[4]*a1.x + ni[5]*a1.y + ni[6]*a1.z + ni[7]*a1.w
         + ni[8]*a2.x + ni[9]*a2.y + ni[10]*a2.z + ni[11]*a2.w
         + ni[12]*a3.x + ni[13]*a3.y + ni[14]*a3.z + ni[15]*a3.w
         - hs;
}

// ---- fused: bilinear downsample 256->64 (tile+halo in LDS) + conv3x3 1->64 --
// (validated R12; unchanged)
__launch_bounds__(512)
__global__ void k_dconv1(const float* __restrict__ x, const float* __restrict__ W1,
                         const float* __restrict__ b1, const float* __restrict__ g1,
                         const float* __restrict__ be1, const float* __restrict__ m1,
                         const float* __restrict__ v1, float* __restrict__ h1) {
    __shared__ float sW[576];
    __shared__ float sb[64], sg[64], sbe[64], sm[64], sv[64];
    __shared__ float sxl[4][66];
    int tid = threadIdx.x;
    for (int k = tid; k < 576; k += 512) sW[k] = W1[k];
    if (tid < 64) {
        sb[tid] = b1[tid]; sg[tid] = g1[tid]; sbe[tid] = be1[tid];
        sm[tid] = m1[tid]; sv[tid] = v1[tid];
    }
    int blk = blockIdx.x;                 // 8 batches * 32 y-tiles
    int b = blk >> 5, ytile = blk & 31;
    if (tid < 264) {                      // 4 rows x 66 cols (incl. halo)
        int tr = tid / 66, tc = tid - tr * 66;
        int oy = ytile * 2 - 1 + tr, ox = tc - 1;
        float val = 0.f;
        if (oy >= 0 && oy < 64 && ox >= 0 && ox < 64) {
            const float* xb = x + b * HIGH * HIGH;
            float cy = 4.f * oy + 1.5f, cx = 4.f * ox + 1.5f;
            float wy[8], wx[8], sy = 0.f, sx = 0.f;
#pragma unroll
            for (int k = 0; k < 8; k++) {
                int iy = 4 * oy - 2 + k;
                float w = 1.f - fabsf((float)iy - cy) * 0.25f;
                if (iy < 0 || iy >= HIGH) w = 0.f;
                wy[k] = w; sy += w;
                int ix = 4 * ox - 2 + k;
                float v = 1.f - fabsf((float)ix - cx) * 0.25f;
                if (ix < 0 || ix >= HIGH) v = 0.f;
                wx[k] = v; sx += v;
            }
            float acc = 0.f;
#pragma unroll
            for (int ky = 0; ky < 8; ky++) {
                if (wy[ky] == 0.f) continue;
                int iy = 4 * oy - 2 + ky;
                float rowacc = 0.f;
#pragma unroll
                for (int kx = 0; kx < 8; kx++) {
                    if (wx[kx] == 0.f) continue;
                    int ix = 4 * ox - 2 + kx;
                    rowacc += wx[kx] * xb[iy * HIGH + ix];
                }
                acc += wy[ky] * rowacc;
            }
            val = acc / (sy * sx);
        }
        sxl[tr][tc] = val;
    }
    __syncthreads();
    int pix = tid & 127, row = pix >> 6, col = pix & 63;
    float t00 = sxl[row    ][col], t01 = sxl[row    ][col + 1], t02 = sxl[row    ][col + 2];
    float t10 = sxl[row + 1][col], t11 = sxl[row + 1][col + 1], t12 = sxl[row + 1][col + 2];
    float t20 = sxl[row + 2][col], t21 = sxl[row + 2][col + 1], t22 = sxl[row + 2][col + 2];
    int y = ytile * 2 + row;
    long base = (long)b * C1 * NN + (long)y * 64 + col;
#pragma unroll
    for (int it = 0; it < 16; it++) {
        int co = it * 4 + (tid >> 7);     // wave-uniform
        const float* w = &sW[co * 9];
        float acc = 0.f;                  // tap order identical to unfused conv1
        acc += w[0] * t00; acc += w[1] * t01; acc += w[2] * t02;
        acc += w[3] * t10; acc += w[4] * t11; acc += w[5] * t12;
        acc += w[6] * t20; acc += w[7] * t21; acc += w[8] * t22;
        acc += sb[co];
        float sc = sg[co] / sqrtf(sv[co] + 1e-5f);
        acc = (acc - sm[co]) * sc + sbe[co];
        h1[base + (long)co * NN] = fmaxf(acc, 0.f);
    }
}

// ------- conv3x3 64->16 + BN + relu, fused: h (node-major), sq, xp, asr, adt -
// (validated R7; unchanged)
__launch_bounds__(512)
__global__ void k_conv2(const float* __restrict__ h1, const float* __restrict__ W2,
                        const float* __restrict__ b2, const float* __restrict__ g2,
                        const float* __restrict__ be2, const float* __restrict__ m2,
                        const float* __restrict__ v2, const float* __restrict__ Wg,
                        const float* __restrict__ a_src, const float* __restrict__ a_dst,
                        float* __restrict__ h, float* __restrict__ sq,
                        float* __restrict__ xp, float* __restrict__ asr,
                        float* __restrict__ adt) {
    __shared__ float sW2t[576 * 16];    // [ci*9+tap][o]
    __shared__ float sWg[256];
    __shared__ float sA[32];
    __shared__ float accH[3][128][17];  // partials from quarters 1..3 (17-pad)
    int tid = threadIdx.x;
    for (int k = tid; k < 9216; k += 512) {          // coalesced global read, scatter to LDS
        int o = k / 576, ct = k - o * 576;
        sW2t[ct * 16 + o] = W2[k];
    }
    if (tid < 256) sWg[tid] = Wg[tid];
    if (tid < 16) { sA[tid] = a_src[tid]; sA[16 + tid] = a_dst[tid]; }
    __syncthreads();
    int blk = blockIdx.x;                 // 8 batches * 32 y-tiles
    int b = blk >> 5, ytile = blk & 31;
    int q = tid >> 7;                     // ci quarter 0..3
    int sub = tid & 127;
    int ty = sub >> 6, x = sub & 63, y = ytile * 2 + ty;
    float acc[16];
#pragma unroll
    for (int o = 0; o < 16; o++) acc[o] = 0.f;
    const float* hb = h1 + (long)b * C1 * NN + (long)q * 16 * NN;
    for (int ci = 0; ci < 16; ci++) {
        const float* plane = hb + ci * NN;
#pragma unroll
        for (int dy = -1; dy <= 1; dy++) {
            int yy = y + dy; bool oky = (yy >= 0 && yy < 64);
#pragma unroll
            for (int dx = -1; dx <= 1; dx++) {
                int xx = x + dx;
                float v = (oky && xx >= 0 && xx < 64) ? plane[yy * 64 + xx] : 0.f;
                int ct = (q * 16 + ci) * 9 + (dy + 1) * 3 + (dx + 1);
                const float4* wr = (const float4*)&sW2t[ct * 16];
                float4 w0 = wr[0], w1 = wr[1], w2 = wr[2], w3 = wr[3];
                acc[0] += v * w0.x; acc[1] += v * w0.y; acc[2] += v * w0.z; acc[3] += v * w0.w;
                acc[4] += v * w1.x; acc[5] += v * w1.y; acc[6] += v * w1.z; acc[7] += v * w1.w;
                acc[8] += v * w2.x; acc[9] += v * w2.y; acc[10]+= v * w2.z; acc[11]+= v * w2.w;
                acc[12]+= v * w3.x; acc[13]+= v * w3.y; acc[14]+= v * w3.z; acc[15]+= v * w3.w;
            }
        }
    }
    if (q != 0) {
        float* dst = &accH[q - 1][sub][0];
#pragma unroll
        for (int o = 0; o < 16; o++) dst[o] = acc[o];
    }
    __syncthreads();
    if (q != 0) return;
#pragma unroll
    for (int qq = 0; qq < 3; qq++) {
        const float* src = &accH[qq][sub][0];
#pragma unroll
        for (int o = 0; o < 16; o++) acc[o] += src[o];
    }
    int n = y * 64 + x;
    long node = (long)b * NN + n;
    float nodev[16], sqv = 0.f;
#pragma unroll
    for (int o = 0; o < 16; o++) {
        float a = acc[o] + b2[o];
        float sc = g2[o] / sqrtf(v2[o] + 1e-5f);
        a = (a - m2[o]) * sc + be2[o];
        a = fmaxf(a, 0.f);
        nodev[o] = a; sqv += a * a;
        h[node * 16 + o] = a;
    }
    sq[node] = 0.5f * sqv;                // pre-scaled: scan/merge use dot - 0.5|j|^2
    float xpv[16];
#pragma unroll
    for (int o = 0; o < 16; o++) {
        float a = 0.f;
#pragma unroll
        for (int c = 0; c < 16; c++) a += sWg[o * 16 + c] * nodev[c];
        xpv[o] = a;
        xp[node * 16 + o] = a;
    }
#pragma unroll
    for (int hh = 0; hh < 4; hh++) {
        float as = 0.f, ad = 0.f;
#pragma unroll
        for (int f = 0; f < 4; f++) {
            as += xpv[hh * 4 + f] * sA[hh * 4 + f];
            ad += xpv[hh * 4 + f] * sA[16 + hh * 4 + f];
        }
        asr[node * 4 + hh] = as;
        adt[node * 4 + hh] = ad;
    }
}

// ------- error-free 3-way bf16 split of h: h = hi + mid + lo + O(2^-27) -----
// R13: 256-thread blocks (128 vs 512 dispatch packets); body unchanged.
__device__ __forceinline__ ushort f2bf(float f) {
    unsigned u = __float_as_uint(f);
    return (ushort)((u + 0x7FFFu + ((u >> 16) & 1u)) >> 16);
}
__device__ __forceinline__ float bf2f(ushort h) {
    return __uint_as_float(((unsigned)h) << 16);
}
__launch_bounds__(256)
__global__ void k_split(const float* __restrict__ h, const float* __restrict__ sq,
                        ushort* __restrict__ hHi, ushort* __restrict__ hMid,
                        ushort* __restrict__ hLo, float* __restrict__ nsq) {
    long t = (long)blockIdx.x * 256 + threadIdx.x;   // node 0..32767
    nsq[t] = -sq[t];                                  // negated for MFMA C-init
    const float4* hp = (const float4*)&h[t * 16];
    float4 v0 = hp[0], v1 = hp[1], v2 = hp[2], v3 = hp[3];
    float v[16] = { v0.x,v0.y,v0.z,v0.w, v1.x,v1.y,v1.z,v1.w,
                    v2.x,v2.y,v2.z,v2.w, v3.x,v3.y,v3.z,v3.w };
    unsigned wh[8], wm[8], wl[8];
#pragma unroll
    for (int p = 0; p < 8; p++) {
        unsigned packh = 0, packm = 0, packl = 0;
#pragma unroll
        for (int e = 0; e < 2; e++) {
            float f = v[p * 2 + e];
            ushort hi = f2bf(f);
            float t1 = f - bf2f(hi);
            ushort mi = f2bf(t1);
            float t2 = t1 - bf2f(mi);
            ushort lo = f2bf(t2);
            packh |= ((unsigned)hi) << (16 * e);
            packm |= ((unsigned)mi) << (16 * e);
            packl |= ((unsigned)lo) << (16 * e);
        }
        wh[p] = packh; wm[p] = packm; wl[p] = packl;
    }
    uint4* dh = (uint4*)&hHi[t * 16];
    uint4* dm = (uint4*)&hMid[t * 16];
    uint4* dl = (uint4*)&hLo[t * 16];
    dh[0] = make_uint4(wh[0], wh[1], wh[2], wh[3]);
    dh[1] = make_uint4(wh[4], wh[5], wh[6], wh[7]);
    dm[0] = make_uint4(wm[0], wm[1], wm[2], wm[3]);
    dm[1] = make_uint4(wm[4], wm[5], wm[6], wm[7]);
    dl[0] = make_uint4(wl[0], wl[1], wl[2], wl[3]);
    dl[1] = make_uint4(wl[4], wl[5], wl[6], wl[7]);
}

// --- shared tile-score routine: MUST be bit-identical between pass 1/2 ------
__device__ __forceinline__ void tile_scores(const ushort* __restrict__ hHi,
        const ushort* __restrict__ hMid, const ushort* __restrict__ hLo,
        const float* __restrict__ nsq, long bN, int j0, int ln31, int koff,
        int rbase, int i0w, bf16x8 bi_h, bf16x8 bi_m, bf16x8 bi_l,
        float scv[16]) {
    int jr = j0 + ln31;
    bf16x8 aj_h = *(const bf16x8*)&hHi [(bN + jr) * 16 + koff];
    bf16x8 aj_m = *(const bf16x8*)&hMid[(bN + jr) * 16 + koff];
    bf16x8 aj_l = *(const bf16x8*)&hLo [(bN + jr) * 16 + koff];
    float4 q0 = *(const float4*)&nsq[bN + j0 +  0 + rbase];
    float4 q1 = *(const float4*)&nsq[bN + j0 +  8 + rbase];
    float4 q2 = *(const float4*)&nsq[bN + j0 + 16 + rbase];
    float4 q3 = *(const float4*)&nsq[bN + j0 + 24 + rbase];
    f32x16 acc;
    acc[0]  = q0.x; acc[1]  = q0.y; acc[2]  = q0.z; acc[3]  = q0.w;
    acc[4]  = q1.x; acc[5]  = q1.y; acc[6]  = q1.z; acc[7]  = q1.w;
    acc[8]  = q2.x; acc[9]  = q2.y; acc[10] = q2.z; acc[11] = q2.w;
    acc[12] = q3.x; acc[13] = q3.y; acc[14] = q3.z; acc[15] = q3.w;
    acc = __builtin_amdgcn_mfma_f32_32x32x16_bf16(aj_h, bi_h, acc, 0, 0, 0);
    acc = __builtin_amdgcn_mfma_f32_32x32x16_bf16(aj_h, bi_m, acc, 0, 0, 0);
    acc = __builtin_amdgcn_mfma_f32_32x32x16_bf16(aj_m, bi_h, acc, 0, 0, 0);
    acc = __builtin_amdgcn_mfma_f32_32x32x16_bf16(aj_h, bi_l, acc, 0, 0, 0);
    acc = __builtin_amdgcn_mfma_f32_32x32x16_bf16(aj_l, bi_h, acc, 0, 0, 0);
    acc = __builtin_amdgcn_mfma_f32_32x32x16_bf16(aj_m, bi_m, acc, 0, 0, 0);
#pragma unroll
    for (int rr = 0; rr < 16; rr++) scv[rr] = acc[rr];
    if (j0 == i0w) {                       // wave-uniform: diagonal tile, mask self
#pragma unroll
        for (int rr = 0; rr < 16; rr++) {
            int r = (rr & 3) + 8 * (rr >> 2) + rbase;
            if (r == ln31) scv[rr] = -FLT_MAX;
        }
    }
}

// --- sorting-network primitives (compare-exchange = max/min pair: exact
// multiset preservation, fully unrolled constant indexing) ------------------
#define CEX(a, b) { float ce_hi = fmaxf(a, b), ce_lo = fminf(a, b); (a) = ce_hi; (b) = ce_lo; }
// Batcher odd-even mergesort, 8 values descending (19 CE)
__device__ __forceinline__ void sort8d(float v[8]) {
    CEX(v[0],v[1]); CEX(v[2],v[3]); CEX(v[4],v[5]); CEX(v[6],v[7]);
    CEX(v[0],v[2]); CEX(v[1],v[3]); CEX(v[4],v[6]); CEX(v[5],v[7]);
    CEX(v[1],v[2]); CEX(v[5],v[6]);
    CEX(v[0],v[4]); CEX(v[1],v[5]); CEX(v[2],v[6]); CEX(v[3],v[7]);
    CEX(v[2],v[4]); CEX(v[3],v[5]);
    CEX(v[1],v[2]); CEX(v[3],v[4]); CEX(v[5],v[6]);
}
// bitonic 8-sequence -> sorted descending (12 CE)
__device__ __forceinline__ void bsort8d(float v[8]) {
    CEX(v[0],v[4]); CEX(v[1],v[5]); CEX(v[2],v[6]); CEX(v[3],v[7]);
    CEX(v[0],v[2]); CEX(v[1],v[3]); CEX(v[4],v[6]); CEX(v[5],v[7]);
    CEX(v[0],v[1]); CEX(v[2],v[3]); CEX(v[4],v[5]); CEX(v[6],v[7]);
}
// compare-exchange with carried id under (score desc, id asc) total order
#define CEX2(sa, ia, sb, ib) { \
    bool sw2 = ((sb) > (sa)) || ((sb) == (sa) && (ib) < (ia)); \
    float th2 = sw2 ? (sb) : (sa); float tl2 = sw2 ? (sa) : (sb); \
    int   ih2 = sw2 ? (ib) : (ia); int   il2 = sw2 ? (ia) : (ib); \
    (sa) = th2; (sb) = tl2; (ia) = ih2; (ib) = il2; }
// bitonic 8 -> sorted by (score desc, id asc), ids carried (12 CE2)
__device__ __forceinline__ void bsort8d_id(float v[8], int id[8]) {
    CEX2(v[0],id[0],v[4],id[4]); CEX2(v[1],id[1],v[5],id[5]);
    CEX2(v[2],id[2],v[6],id[6]); CEX2(v[3],id[3],v[7],id[7]);
    CEX2(v[0],id[0],v[2],id[2]); CEX2(v[1],id[1],v[3],id[3]);
    CEX2(v[4],id[4],v[6],id[6]); CEX2(v[5],id[5],v[7],id[7]);
    CEX2(v[0],id[0],v[1],id[1]); CEX2(v[2],id[2],v[3],id[3]);
    CEX2(v[4],id[4],v[5],id[5]); CEX2(v[6],id[6],v[7],id[7]);
}

// --------- kNN scan, two-pass scores-only selection (validated R6-R9) --------
// At structural floor per R9 falsifier: ~88% pipe-busy, selection networks at
// the CE lower bound, occupancy lever exhausted. NOT touched since R9.
__global__ __attribute__((amdgpu_waves_per_eu(4, 8))) __launch_bounds__(256)
void k_scan(const ushort* __restrict__ hHi, const ushort* __restrict__ hMid,
            const ushort* __restrict__ hLo, const float* __restrict__ nsq,
            uint4* __restrict__ cand_i) {
    __shared__ ushort lists[256][18];    // [tid][0..7]=A ids, [8..15]=B ids, [16]=trash, [17]=pad
    __shared__ ushort outl[256][8];
    int tid = threadIdx.x, blk = blockIdx.x;
    int b  = blk >> 8;                   // 256 blocks per batch (32 ig x 8 sl)
    int ig = (blk >> 3) & 31;
    int sl = blk & 7;
    int wid = tid >> 6, lane = tid & 63;
    int ln31 = lane & 31, l5 = lane >> 5;
    int koff = l5 * 8;
    int i0w = ig * 128 + wid * 32;       // this wave's 32-aligned i-tile base
    int i   = i0w + ln31;
    long bN = (long)b * NN;
    int rbase = l5 * 4;
    int jbase = sl * 512;

    bf16x8 bi_h = *(const bf16x8*)&hHi [(bN + i) * 16 + koff];
    bf16x8 bi_m = *(const bf16x8*)&hMid[(bN + i) * 16 + koff];
    bf16x8 bi_l = *(const bf16x8*)&hLo [(bN + i) * 16 + koff];

    // ---- pass 1: top-8 scores only (sorted descending invariant) ----
    float s[8];
#pragma unroll
    for (int k = 0; k < 8; k++) s[k] = -FLT_MAX;
#pragma unroll 2
    for (int t = 0; t < 16; t++) {
        int j0 = jbase + t * 32;
        float scv[16];
        tile_scores(hHi, hMid, hLo, nsq, bN, j0, ln31, koff, rbase, i0w,
                    bi_h, bi_m, bi_l, scv);
        float va[8] = { scv[0], scv[1], scv[2], scv[3], scv[4], scv[5], scv[6], scv[7] };
        float vb[8] = { scv[8], scv[9], scv[10], scv[11], scv[12], scv[13], scv[14], scv[15] };
        sort8d(va); sort8d(vb);
        float mg[8];
#pragma unroll
        for (int k = 0; k < 8; k++) mg[k] = fmaxf(va[k], vb[7 - k]);  // top-8 of 16, bitonic
        bsort8d(mg);
#pragma unroll
        for (int k = 0; k < 8; k++) s[k] = fmaxf(s[k], mg[7 - k]);    // top-8 of (s ∪ mg), bitonic
        bsort8d(s);
    }
    // pair-merge: top-8 of union(lane, lane^32) as a multiset; theta = its min.
    float mv[8];
#pragma unroll
    for (int k = 0; k < 8; k++) mv[k] = fmaxf(s[k], __shfl_xor(s[7 - k], 32));
    float theta = mv[0];
#pragma unroll
    for (int k = 1; k < 8; k++) theta = fminf(theta, mv[k]);

    // ---- pass 2: id recovery via bitmask + ffs ----
    ushort* ldsw = &lists[0][0];
    int baseA = tid * 18, baseB = baseA + 8, trash = baseA + 16;
    int nA = 0, nB = 0;
#pragma unroll 2
    for (int t = 0; t < 16; t++) {
        int j0 = jbase + t * 32;
        float scv[16];
        tile_scores(hHi, hMid, hLo, nsq, bN, j0, ln31, koff, rbase, i0w,
                    bi_h, bi_m, bi_l, scv);
        unsigned gm = 0, em = 0;
#pragma unroll
        for (int rr = 0; rr < 16; rr++) {
            gm |= (scv[rr] >  theta) ? (1u << rr) : 0u;
            em |= (scv[rr] == theta) ? (1u << rr) : 0u;
        }
        unsigned m = gm | em;
        while (__any(m != 0u)) {
            if (m) {
                int rr = __ffs(m) - 1;
                m &= m - 1u;
                int r = (rr & 3) + ((rr >> 2) << 3) + rbase;
                int j = j0 + r;
                bool isGt = (gm >> rr) & 1u;
                bool cA = isGt && (nA < 8);   // <=7 by math; insurance
                bool cB = (!isGt) && (nB < 8);
                int ia = cA ? (baseA + nA) : (cB ? (baseB + nB) : trash);
                ldsw[ia] = (ushort)j;         // single predicated write
                nA += cA;
                nB += cB;
            }
        }
    }
    int pA = __shfl_xor(nA, 32);
    int pB = __shfl_xor(nB, 32);
    __syncthreads();
    // ---- assembly (per column, lane<32): A ids + smallest-j ties to fill 8 ----
    if (lane < 32) {
        int tp = tid + 32;
        int n = 0;
        for (int k = 0; k < nA && n < 8; k++) outl[tid][n++] = lists[tid][k];
        for (int k = 0; k < pA && n < 8; k++) outl[tid][n++] = lists[tp][k];
        int p0 = 0, p1 = 0;
        while (n < 8) {                  // two-pointer merge of j-ascending tie lists
            unsigned a = (p0 < nB) ? (unsigned)lists[tid][8 + p0] : 0xFFFFFFFFu;
            unsigned c = (p1 < pB) ? (unsigned)lists[tp][8 + p1] : 0xFFFFFFFFu;
            bool t0 = a < c;
            outl[tid][n++] = (ushort)(t0 ? a : c);
            p0 += t0 ? 1 : 0; p1 += t0 ? 0 : 1;
        }
        uint4 pk = *(const uint4*)&outl[tid][0];
        cand_i[(long)(b * NSL + sl) * NN + i] = pk;
    }
}

// --- merge 8 slice-lists + GAT + update-MLP + fire + 1x1->1 + sigmoid -------
// R13: 256-thread blocks (4 waves, each handling 16 nodes with the EXACT R10
// per-wave mapping — shfl_xor(16/32) merges are wave-local, unchanged).
// Weight staging amortized 4x (was 64 loads/thread at 64-thr blocks); block
// count 2048 -> 512. pshare becomes [64][17] indexed by (wave*16+ln15).
__launch_bounds__(256)
__global__ void k_gat2(const uint4* __restrict__ cand_i, const float* __restrict__ h,
                       const float* __restrict__ sq,
                       const float* __restrict__ xp, const float* __restrict__ asr,
                       const float* __restrict__ adt, const float* __restrict__ bg,
                       const float* __restrict__ fire, const float* __restrict__ Wu1,
                       const float* __restrict__ bu1, const float* __restrict__ Wu2,
                       const float* __restrict__ bu2, const float* __restrict__ Wo,
                       const float* __restrict__ bo, float* __restrict__ out_low) {
    __shared__ float sU1[128 * 16];
    __shared__ float sU2t[128 * 16];      // [hd][c] = Wu2[c][hd]
    __shared__ float sb1[128];
    __shared__ float pshare[64][17];
    int tid = threadIdx.x;
    int lane = tid & 63, w = tid >> 6;            // 4 waves per block
    for (int k = tid; k < 2048; k += 256) {       // stage MLP weights (amortized 4x)
        sU1[k] = Wu1[k];
        sU2t[(k & 127) * 16 + (k >> 7)] = Wu2[k];
    }
    if (tid < 128) sb1[tid] = bu1[tid];
    int ln15 = lane & 15, q = lane >> 4;
    int ns = w * 16 + ln15;                       // node slot within block (0..63)
    int t = blockIdx.x * 64 + ns;                 // node 0..32767 (== bN + i)
    int b = t >> 12, i = t & 4095;
    long bN = (long)b * NN;
    const float4* ip = (const float4*)&h[(bN + i) * 16];
    float4 r0 = ip[0], r1 = ip[1], r2 = ip[2], r3 = ip[3];
    float ni[16] = { r0.x,r0.y,r0.z,r0.w, r1.x,r1.y,r1.z,r1.w,
                     r2.x,r2.y,r2.z,r2.w, r3.x,r3.y,r3.z,r3.w };
    float fS[8]; int fI[8];
#pragma unroll
    for (int k = 0; k < 8; k++) { fS[k] = -FLT_MAX; fI[k] = 65535; }
#pragma unroll
    for (int ss = 0; ss < 2; ss++) {
        int sl = q * 2 + ss;
        uint4 pk = cand_i[(long)(b * NSL + sl) * NN + i];
        unsigned idx8[8] = { pk.x & 0xFFFF, pk.x >> 16, pk.y & 0xFFFF, pk.y >> 16,
                             pk.z & 0xFFFF, pk.z >> 16, pk.w & 0xFFFF, pk.w >> 16 };
#pragma unroll
        for (int k = 0; k < 8; k++) {
            int j = (int)idx8[k];
            const float4* np = (const float4*)&h[(bN + j) * 16];
            float4 a0 = np[0], a1 = np[1], a2 = np[2], a3 = np[3];
            float d = dot16m(ni, a0, a1, a2, a3, sq[bN + j]);
            bool bt = (d > fS[7]) || (d == fS[7] && j < fI[7]);
            if (bt) {
                fS[7] = d; fI[7] = j;
#pragma unroll
                for (int qq = 7; qq > 0; qq--) {
                    bool sw = (fS[qq] > fS[qq - 1]) || (fS[qq] == fS[qq - 1] && fI[qq] < fI[qq - 1]);
                    if (sw) {
                        float td = fS[qq]; fS[qq] = fS[qq - 1]; fS[qq - 1] = td;
                        int tj = fI[qq]; fI[qq] = fI[qq - 1]; fI[qq - 1] = tj;
                    }
                }
            }
        }
    }
    // level 1: merge quarter pairs (0<->1, 2<->3) — top-8 of 32, then re-sort
    float oS[8]; int oI[8];
#pragma unroll
    for (int k = 0; k < 8; k++) {
        oS[k] = __shfl_xor(fS[k], 16);
        oI[k] = __shfl_xor(fI[k], 16);
    }
    float mS[8]; int mI[8];
#pragma unroll
    for (int k = 0; k < 8; k++) {
        bool mine = (fS[k] > oS[7 - k]) || (fS[k] == oS[7 - k] && fI[k] < oI[7 - k]);
        mS[k] = mine ? fS[k] : oS[7 - k];
        mI[k] = mine ? fI[k] : oI[7 - k];
    }
    bsort8d_id(mS, mI);
    // level 2: merge across (01)<->(23) — top-8 of 64
#pragma unroll
    for (int k = 0; k < 8; k++) {
        oS[k] = __shfl_xor(mS[k], 32);
        oI[k] = __shfl_xor(mI[k], 32);
    }
    int nI[8];
#pragma unroll
    for (int k = 0; k < 8; k++) {
        bool mine = (mS[k] > oS[7 - k]) || (mS[k] == oS[7 - k] && mI[k] < oI[7 - k]);
        nI[k] = mine ? mI[k] : oI[7 - k];
    }
    if (q == 0) {
        int nbrs[9];
#pragma unroll
        for (int e = 0; e < 8; e++) nbrs[e] = nI[e];
        nbrs[8] = i;                                   // self-loop
        float adtv[4];
#pragma unroll
        for (int hh = 0; hh < 4; hh++) adtv[hh] = adt[(bN + i) * 4 + hh];
        float mx[4] = { -FLT_MAX, -FLT_MAX, -FLT_MAX, -FLT_MAX };
        float lg[9][4];
#pragma unroll
        for (int e = 0; e < 9; e++) {
            long nb = bN + nbrs[e];
#pragma unroll
            for (int hh = 0; hh < 4; hh++) {
                float l = asr[nb * 4 + hh] + adtv[hh];
                l = (l > 0.f) ? l : 0.2f * l;          // leaky_relu 0.2
                lg[e][hh] = l;
                mx[hh] = fmaxf(mx[hh], l);
            }
        }
        float sum[4] = { 0, 0, 0, 0 };
        float acc[16];
#pragma unroll
        for (int c = 0; c < 16; c++) acc[c] = 0.f;
#pragma unroll
        for (int e = 0; e < 9; e++) {
            long nb = bN + nbrs[e];
            const float4* xpn = (const float4*)&xp[nb * 16];
            float4 x0 = xpn[0], x1 = xpn[1], x2 = xpn[2], x3 = xpn[3];
            float xv[16] = { x0.x,x0.y,x0.z,x0.w, x1.x,x1.y,x1.z,x1.w,
                             x2.x,x2.y,x2.z,x2.w, x3.x,x3.y,x3.z,x3.w };
            float wv[4];
#pragma unroll
            for (int hh = 0; hh < 4; hh++) {
                float w2 = expf(lg[e][hh] - mx[hh]);
                sum[hh] += w2; wv[hh] = w2;
            }
#pragma unroll
            for (int hh = 0; hh < 4; hh++)
#pragma unroll
                for (int f = 0; f < 4; f++)
                    acc[hh * 4 + f] += wv[hh] * xv[hh * 4 + f];
        }
#pragma unroll
        for (int hh = 0; hh < 4; hh++) {
            float inv = 1.f / sum[hh];
#pragma unroll
            for (int f = 0; f < 4; f++) {
                float o = acc[hh * 4 + f] * inv + bg[hh * 4 + f];
                pshare[ns][hh * 4 + f] = fmaxf(o, 0.f);   // GAT relu -> LDS (p dead)
            }
        }
    }
    __syncthreads();
    // ---- fused update-MLP: all lanes; lane (ns, q) = node ns, hd quarter q
    float pv[16];
#pragma unroll
    for (int c = 0; c < 16; c++) pv[c] = pshare[ns][c];
    float u[16];
#pragma unroll
    for (int c = 0; c < 16; c++) u[c] = 0.f;
    int hd0 = q * 32;
    for (int hd = hd0; hd < hd0 + 32; hd++) {        // wave-uniform LDS addrs: broadcast
        const float4* r = (const float4*)&sU1[hd * 16];
        float4 w0 = r[0], w1 = r[1], w2 = r[2], w3 = r[3];
        float a = sb1[hd]
            + w0.x*pv[0] + w0.y*pv[1] + w0.z*pv[2] + w0.w*pv[3]
            + w1.x*pv[4] + w1.y*pv[5] + w1.z*pv[6] + w1.w*pv[7]
            + w2.x*pv[8] + w2.y*pv[9] + w2.z*pv[10]+ w2.w*pv[11]
            + w3.x*pv[12]+ w3.y*pv[13]+ w3.z*pv[14]+ w3.w*pv[15];
        a = fmaxf(a, 0.f);
        const float4* tt = (const float4*)&sU2t[hd * 16];
        float4 t0 = tt[0], t1 = tt[1], t2 = tt[2], t3 = tt[3];
        u[0] += t0.x*a; u[1] += t0.y*a; u[2] += t0.z*a; u[3] += t0.w*a;
        u[4] += t1.x*a; u[5] += t1.y*a; u[6] += t1.z*a; u[7] += t1.w*a;
        u[8] += t2.x*a; u[9] += t2.y*a; u[10]+= t2.z*a; u[11]+= t2.w*a;
        u[12]+= t3.x*a; u[13]+= t3.y*a; u[14]+= t3.z*a; u[15]+= t3.w*a;
    }
    // butterfly-reduce the 4 quarter-partials (fp32 reorder class)
#pragma unroll
    for (int c = 0; c < 16; c++) {
        u[c] += __shfl_xor(u[c], 16);
        u[c] += __shfl_xor(u[c], 32);
    }
    if (q == 0) {
        float mask = (fire[t] < 0.5f) ? 1.f : 0.f;
        float o = bo[0];
#pragma unroll
        for (int c = 0; c < 16; c++)
            o += Wo[c] * (ni[c] + mask * (u[c] + bu2[c]));   // ni == h[t]
        out_low[t] = 1.f / (1.f + expf(-o));
    }
}

// ---------------- bilinear upsample 64 -> 256 (half-pixel, clamp) -----------
// R13: 4 consecutive pixels/thread (identical per-pixel arithmetic, one
// float4 store); 512 blocks instead of 2048.
__launch_bounds__(256)
__global__ void k_up(const float* __restrict__ ol, float* __restrict__ out) {
    int idx = blockIdx.x * 256 + threadIdx.x;      // 0..131071 (4 pixels each)
    int b = idx >> 14, rem = idx & 16383;
    int oy = rem >> 6, ox0 = (rem & 63) * 4;
    float cy = (oy + 0.5f) * 0.25f - 0.5f;
    int iy0 = (int)floorf(cy); float fy = cy - (float)iy0;
    int y0 = min(max(iy0, 0), 63), y1 = min(max(iy0 + 1, 0), 63);
    const float* s = ol + b * NN;
    float res[4];
#pragma unroll
    for (int e = 0; e < 4; e++) {
        int ox = ox0 + e;
        float cx = (ox + 0.5f) * 0.25f - 0.5f;
        int ix0 = (int)floorf(cx); float fx = cx - (float)ix0;
        int x0 = min(max(ix0, 0), 63), x1 = min(max(ix0 + 1, 0), 63);
        res[e] = (1.f - fy) * ((1.f - fx) * s[y0 * 64 + x0] + fx * s[y0 * 64 + x1])
               + fy * ((1.f - fx) * s[y1 * 64 + x0] + fx * s[y1 * 64 + x1]);
    }
    *(float4*)&out[(long)idx * 4] = make_float4(res[0], res[1], res[2], res[3]);
}

extern "C" void kernel_launch(void* const* d_in, const int* in_sizes, int n_in,
                              void* d_out, int out_size, void* d_ws, size_t ws_size,
                              hipStream_t stream) {
    const float* x    = (const float*)d_in[0];
    const float* fire = (const float*)d_in[1];
    const float* W1   = (const float*)d_in[2];
    const float* b1   = (const float*)d_in[3];
    const float* g1   = (const float*)d_in[4];
    const float* be1  = (const float*)d_in[5];
    const float* m1   = (const float*)d_in[6];
    const float* v1   = (const float*)d_in[7];
    const float* W2   = (const float*)d_in[8];
    const float* b2   = (const float*)d_in[9];
    const float* g2   = (const float*)d_in[10];
    const float* be2  = (const float*)d_in[11];
    const float* m2   = (const float*)d_in[12];
    const float* v2   = (const float*)d_in[13];
    const float* Wg   = (const float*)d_in[14];
    const float* a_src= (const float*)d_in[15];
    const float* a_dst= (const float*)d_in[16];
    const float* bg   = (const float*)d_in[17];
    const float* Wu1  = (const float*)d_in[18];
    const float* bu1  = (const float*)d_in[19];
    const float* Wu2  = (const float*)d_in[20];
    const float* bu2  = (const float*)d_in[21];
    const float* Wo   = (const float*)d_in[22];
    const float* bo   = (const float*)d_in[23];

    float* ws  = (float*)d_ws;
    float* h1  = ws + OFF_H1;
    float* h   = ws + OFF_H;
    float* sq  = ws + OFF_SQ;
    float* xp  = ws + OFF_XP;
    float* asr = ws + OFF_ASR;
    float* adt = ws + OFF_ADT;
    float* ol  = ws + OFF_OL;
    // H1 region reuse (dead after conv2): cand_i 4 MB (NSL=8), bf16 splits,
    // nsq. Total 1,867,776 of 2,097,152 floats — no footprint growth.
    uint4*  cand_i = (uint4*)(ws + OFF_H1);
    ushort* hHi    = (ushort*)(ws + OFF_H1 + 1048576);
    ushort* hMid   = (ushort*)(ws + OFF_H1 + 1310720);
    ushort* hLo    = (ushort*)(ws + OFF_H1 + 1572864);
    float*  nsq    = ws + OFF_H1 + 1835008;

    k_dconv1<<<BATCH * 32, 512, 0, stream>>>(x, W1, b1, g1, be1, m1, v1, h1);
    k_conv2 <<<BATCH * 32, 512, 0, stream>>>(h1, W2, b2, g2, be2, m2, v2, Wg, a_src, a_dst,
                                             h, sq, xp, asr, adt);
    k_split <<<BATCH * NN / 256, 256, 0, stream>>>(h, sq, hHi, hMid, hLo, nsq);
    k_scan  <<<BATCH * 32 * NSL, 256, 0, stream>>>(hHi, hMid, hLo, nsq, cand_i);
    k_gat2  <<<BATCH * NN / 64, 256, 0, stream>>>(cand_i, h, sq, xp, asr, adt, bg,
                                                  fire, Wu1, bu1, Wu2, bu2, Wo, bo, ol);
    k_up    <<<(BATCH * HIGH * HIGH / 4) / 256, 256, 0, stream>>>(ol, (float*)d_out);
}